// Round 5
// baseline (491.397 us; speedup 1.0000x reference)
//
#include <hip/hip_runtime.h>

typedef __bf16 bf16;
typedef __attribute__((ext_vector_type(8))) __bf16 bf16x8;
typedef __attribute__((ext_vector_type(4))) float f32x4;

#define MEMFENCE asm volatile("" ::: "memory")

// async global->LDS, 16B per lane; LDS dest = wave-uniform base + lane*16
__device__ __forceinline__ void gload16(const bf16* g, bf16* l) {
    __builtin_amdgcn_global_load_lds(
        (const __attribute__((address_space(1))) void*)g,
        (__attribute__((address_space(3))) void*)l,
        16, 0, 0);
}

// ======== 128x128 4-wave bf16 NT GEMM, BK=32, double-buffered, ~3 blocks/CU (R5) =========
// m97-proportioned engine: the lever is BLOCK-level overlap (outstanding-DMA depth), not
// intra-block scheduling (R0/R1/R3/R4 all null at 2.8us/tile on the 256² 1-block/CU shape).
// LDS 32KB: buf p at p*16384 = [A 8KB][B 8KB]; each = 8 subtiles of [16r x 32c] (1KB).
// Per tile u: {stage(u+1, p^1): 4 gload16/thread} {8 ds_read_b128: a[4],b[4]} {16 MFMA}
// {vmcnt(0); barrier}.  Race-audit: reads of buf p are lgkm-forced before the consuming
// MFMAs (compiler), which precede the barrier; stage into buf p happens only after the
// NEXT iteration's barrier -> single barrier/tile is sufficient.  Prologue: stage(0)+
// vmcnt(0)+barrier.  Tail: last tile has nothing outstanding.
// st_16x32 swizzle (subtile-local, verified): read addr ^= phx; global source col = sce
// (inverse-swizzled).  D layout: col=lane&15, row=(lane>>4)*4+reg.
// EPI 0: bf16 C = alpha*acc
// EPI 1: bf16 C[ix] = aux3[ix] * (acc - aux1[zb*2048+row])      (dS = A*(dA-rowdot), in-place ok)
// EPI 2: f32  C = aux1[ix] + (float)aux3[ix] - alpha*acc        (out = V + AO - eps*scale*dQacc)
template<int EPI>
__global__ __launch_bounds__(256, 3)
void gemm2b(const bf16* __restrict__ A, const bf16* __restrict__ Bm,
            void* __restrict__ Cp, int Kdim, int lda, int ldb, int ldc,
            long sA, long sB, long sC, float alpha,
            const float* __restrict__ aux1, const bf16* __restrict__ aux3)
{
    __shared__ __align__(16) char smem[32768];

    // XCD-aware bijective swizzle (ntot % 8 == 0 for all launches)
    const int gx = gridDim.x, gy = gridDim.y;
    int lin = blockIdx.x + gx * (blockIdx.y + gy * blockIdx.z);
    const int q = (gx * gy * gridDim.z) >> 3;
    lin = (lin & 7) * q + (lin >> 3);
    const int bx = lin % gx;
    const int rem0 = lin / gx;
    const int by = rem0 % gy;
    const int bz = rem0 / gy;

    const int t0 = threadIdx.x;
    const int w = t0 >> 6, lane = t0 & 63;      // 4 waves, 2x2 grid; per-wave C = 64x64
    const int wm = w >> 1, wn = w & 1;
    const int m0 = by * 128, n0 = bx * 128;
    const long zb = bz;

    const bf16* Ab = A  + zb * sA + (size_t)m0 * lda;
    const bf16* Bb = Bm + zb * sB + (size_t)n0 * ldb;

    // staging lane coords (subtile-local, inverse-swizzled col)
    const int sr16 = lane >> 2;
    const int sce  = ((((lane & 3) << 4) ^ (((lane >> 5) & 1) << 5))) >> 1;
    const bf16* gA = Ab + (size_t)sr16 * lda + sce;
    const bf16* gB = Bb + (size_t)sr16 * ldb + sce;

    // fragment-read bases (16x16x32 layout)
    const int lr = lane & 15, lkq = lane >> 4;
    const int phx = ((lane >> 3) & 1) << 5;
    const int frag_base = (lr * 64 + lkq * 16) ^ phx;

    f32x4 acc[4][4] = {};
    const int NT = Kdim >> 5;                   // BK=32 tiles (16/32/64)

    // wave w stages subtiles {w, w+4} of A and of B (8 subtiles each)
    auto stage = [&](int u, int p) {
        char* L = smem + p * 16384;
        const size_t ku = (size_t)u * 32;
        gload16(gA + (size_t)(w    ) * 16 * lda + ku, (bf16*)(L + w * 1024));
        gload16(gA + (size_t)(w + 4) * 16 * lda + ku, (bf16*)(L + (w + 4) * 1024));
        gload16(gB + (size_t)(w    ) * 16 * ldb + ku, (bf16*)(L + 8192 + w * 1024));
        gload16(gB + (size_t)(w + 4) * 16 * ldb + ku, (bf16*)(L + 8192 + (w + 4) * 1024));
    };

    // ---- prologue ----
    stage(0, 0);
    asm volatile("s_waitcnt vmcnt(0)" ::: "memory");
    __builtin_amdgcn_s_barrier();
    MEMFENCE;

    for (int u = 0; u < NT; ++u) {
        const int p = u & 1;
        if (u + 1 < NT) stage(u + 1, p ^ 1);

        const char* aBuf = smem + p * 16384 + frag_base;
        const char* bBuf = aBuf + 8192;
        bf16x8 a[4], b[4];
        #pragma unroll
        for (int mf = 0; mf < 4; ++mf) a[mf] = *(const bf16x8*)(aBuf + (wm * 4 + mf) * 1024);
        #pragma unroll
        for (int nf = 0; nf < 4; ++nf) b[nf] = *(const bf16x8*)(bBuf + (wn * 4 + nf) * 1024);

        __builtin_amdgcn_s_setprio(1);
        #pragma unroll
        for (int mf = 0; mf < 4; ++mf)
            #pragma unroll
            for (int nf = 0; nf < 4; ++nf)
                acc[mf][nf] = __builtin_amdgcn_mfma_f32_16x16x32_bf16(a[mf], b[nf], acc[mf][nf], 0, 0, 0);
        __builtin_amdgcn_s_setprio(0);

        MEMFENCE;
        if (u + 1 < NT) asm volatile("s_waitcnt vmcnt(0)" ::: "memory");
        __builtin_amdgcn_s_barrier();
        MEMFENCE;
    }

    // ---- epilogue: D layout col=lane&15, row=(lane>>4)*4+reg ----
    const int rb  = m0 + wm * 64 + lkq * 4;
    const int cb0 = n0 + wn * 64 + lr;
    #pragma unroll
    for (int mf = 0; mf < 4; ++mf) {
        #pragma unroll
        for (int r = 0; r < 4; ++r) {
            const int rw = rb + mf * 16 + r;
            float rd = 0.f;
            if (EPI == 1) rd = aux1[zb * 2048 + rw];
            #pragma unroll
            for (int nf = 0; nf < 4; ++nf) {
                const int c = cb0 + nf * 16;
                const size_t ix = (size_t)rw * ldc + c;
                const float v = acc[mf][nf][r];
                if (EPI == 0) {
                    ((bf16*)Cp + zb * sC)[ix] = (bf16)(alpha * v);
                } else if (EPI == 1) {
                    bf16* Cb = (bf16*)Cp + zb * sC;
                    const bf16* Am = aux3 + zb * sC;
                    Cb[ix] = (bf16)((float)Am[ix] * (v - rd));
                } else {
                    float* C = (float*)Cp + zb * sC;
                    const float* Vv = aux1 + zb * sC;
                    const bf16* AOv = aux3 + zb * sC;
                    C[ix] = Vv[ix] + (float)AOv[ix] - alpha * v;
                }
            }
        }
    }
}

// ===== round-6 engine: 256 x (64*NF) quad-slot BK=32 cross-step =====
// EPI 0: bf16 C = alpha*acc
// EPI 3: bf16 C = silu'(acc + aux1[col]) * aux2[col];  H[ix] = (bf16)acc  (H via aux3, cast)
template<int EPI, int NF>
__global__ __launch_bounds__(512, 1)
void gemm_nc(const bf16* __restrict__ A, const bf16* __restrict__ Bm,
             void* __restrict__ Cp, int Kdim, int lda, int ldb, int ldc,
             long sA, long sB, long sC, float alpha,
             const float* __restrict__ aux1, const float* __restrict__ aux2,
             const bf16* __restrict__ aux3)
{
    constexpr int SB = NF * 4096;
    __shared__ __align__(16) char smem[65536 + 4 * SB];

    const int gx = gridDim.x, gy = gridDim.y;
    int lin = blockIdx.x + gx * (blockIdx.y + gy * blockIdx.z);
    const int q = (gx * gy * gridDim.z) >> 3;
    lin = (lin & 7) * q + (lin >> 3);
    const int bx = lin % gx;
    const int rem0 = lin / gx;
    const int by = rem0 % gy;
    const int bz = rem0 / gy;

    const int t0 = threadIdx.x;
    const int w = t0 >> 6, lane = t0 & 63;
    const int wm = w >> 2, wn = w & 3;
    const int m0 = by * 256, n0 = bx * (64 * NF);
    const long zb = bz;

    const bf16* Ab = A  + zb * sA + (size_t)m0 * lda;
    const bf16* Bb = Bm + zb * sB + (size_t)n0 * ldb;

    const int sr16 = lane >> 2;
    const int sce  = ((((lane & 3) << 4) ^ (((lane >> 5) & 1) << 5))) >> 1;
    const int stg0 = w * 2, stg1 = w * 2 + 1;
    const bf16* pA0 = Ab + (size_t)(stg0 * 16 + sr16) * lda + sce;
    const bf16* pA1 = Ab + (size_t)(stg1 * 16 + sr16) * lda + sce;
    const bf16* pB0 = Bb + (size_t)((NF == 4 ? stg0 : w) * 16 + sr16) * ldb + sce;
    const bf16* pB1 = Bb + (size_t)(stg1 * 16 + sr16) * ldb + sce;

    const int lr = lane & 15, lkq = lane >> 4;
    const int phx = ((lane >> 3) & 1) << 5;
    const int frag_base = lr * 64 + lkq * 16;

    f32x4 acc[8][NF] = {};
    const int NT = Kdim >> 5;

    auto issueSlot = [&](int p) {
        char* lA = smem + (p & 3) * 16384;
        char* lB = smem + 65536 + (p & 3) * SB;
        const int kt = p << 5;
        gload16(pA0 + kt, (bf16*)(lA + stg0 * 1024));
        gload16(pA1 + kt, (bf16*)(lA + stg1 * 1024));
        if (NF == 4) {
            gload16(pB0 + kt, (bf16*)(lB + stg0 * 1024));
            gload16(pB1 + kt, (bf16*)(lB + stg1 * 1024));
        } else {
            gload16(pB0 + kt, (bf16*)(lB + w * 1024));
        }
    };
    auto rdA = [&](const char* base, int sub) {
        return *(const bf16x8*)(base + (((sub << 10) + frag_base) ^ phx));
    };

    issueSlot(0); issueSlot(1); issueSlot(2);
    if (NF == 4) asm volatile("s_waitcnt vmcnt(4)" ::: "memory");
    else         asm volatile("s_waitcnt vmcnt(3)" ::: "memory");
    __builtin_amdgcn_s_barrier();
    MEMFENCE;

    bf16x8 alo[4], ahi[4], b0[NF], b1[NF];
    {
        const char* cA = smem;
        const char* cB = smem + 65536;
        #pragma unroll
        for (int mf = 0; mf < 4; ++mf) alo[mf] = rdA(cA, wm * 8 + mf);
        #pragma unroll
        for (int nf = 0; nf < NF; ++nf) b0[nf] = rdA(cB, wn * NF + nf);
    }

    auto stepBody = [&](int SL, int s, bf16x8 (&bA)[NF], bf16x8 (&bB)[NF]) {
        if (s + 3 < NT) issueSlot(s + 3);
        const char* cA = smem + SL * 16384;
        #pragma unroll
        for (int mf = 0; mf < 4; ++mf) ahi[mf] = rdA(cA, wm * 8 + 4 + mf);

        __builtin_amdgcn_s_setprio(1);
        #pragma unroll
        for (int mf = 0; mf < 4; ++mf)
            #pragma unroll
            for (int nf = 0; nf < NF; ++nf)
                acc[mf][nf] = __builtin_amdgcn_mfma_f32_16x16x32_bf16(alo[mf], bA[nf], acc[mf][nf], 0, 0, 0);
        __builtin_amdgcn_s_setprio(0);

        if (s + 1 < NT) {
            const int NS = (SL + 1) & 3;
            const char* nA = smem + NS * 16384;
            const char* nB = smem + 65536 + NS * SB;
            #pragma unroll
            for (int mf = 0; mf < 4; ++mf) alo[mf] = rdA(nA, wm * 8 + mf);
            #pragma unroll
            for (int nf = 0; nf < NF; ++nf) bB[nf] = rdA(nB, wn * NF + nf);
        }

        __builtin_amdgcn_s_setprio(1);
        #pragma unroll
        for (int mf = 0; mf < 4; ++mf)
            #pragma unroll
            for (int nf = 0; nf < NF; ++nf)
                acc[4 + mf][nf] = __builtin_amdgcn_mfma_f32_16x16x32_bf16(ahi[mf], bA[nf], acc[4 + mf][nf], 0, 0, 0);
        __builtin_amdgcn_s_setprio(0);

        MEMFENCE;
        if (s + 3 < NT) {
            if (NF == 4) asm volatile("s_waitcnt vmcnt(4)" ::: "memory");
            else         asm volatile("s_waitcnt vmcnt(3)" ::: "memory");
        } else {
            asm volatile("s_waitcnt vmcnt(0)" ::: "memory");
        }
        __builtin_amdgcn_s_barrier();
        MEMFENCE;
    };

    for (int s = 0; s < NT; s += 2) {
        stepBody(s & 3, s, b0, b1);
        stepBody((s + 1) & 3, s + 1, b1, b0);
    }

    const int rb  = m0 + wm * 128 + lkq * 4;
    const int cb0 = n0 + wn * (NF * 16) + lr;
    #pragma unroll
    for (int mf = 0; mf < 8; ++mf) {
        #pragma unroll
        for (int nf = 0; nf < NF; ++nf) {
            const int c = cb0 + nf * 16;
            #pragma unroll
            for (int r = 0; r < 4; ++r) {
                const int rw = rb + mf * 16 + r;
                const size_t ix = (size_t)rw * ldc + c;
                const float v = acc[mf][nf][r];
                if (EPI == 0) {
                    ((bf16*)Cp + zb * sC)[ix] = (bf16)(alpha * v);
                } else {   // EPI == 3: U + H
                    const float u = v + aux1[c];
                    const float sg = 1.f / (1.f + __expf(-u));
                    const float dd = sg * (1.f + u * (1.f - sg));
                    ((bf16*)Cp)[ix] = (bf16)(dd * aux2[c]);
                    ((bf16*)aux3)[ix] = (bf16)v;   // H = AO@W1 (pre-bias)
                }
            }
        }
    }
}

// ---------------- fp32 -> bf16 cast (DN) and/or transposed cast (DT) ----------------
template<bool DN, bool DT>
__global__ __launch_bounds__(256)
void transcast_k(const float* __restrict__ in, bf16* __restrict__ outN,
                 bf16* __restrict__ outT, int R, int C)
{
    __shared__ float ts[64][65];
    const int t = threadIdx.x;
    const int c0 = blockIdx.x * 64, r0 = blockIdx.y * 64;
    const size_t zoff = (size_t)blockIdx.z * R * C;

    const int rr = t >> 2, cc = (t & 3) * 16;
    float4 f[4];
    const float* src = in + zoff + (size_t)(r0 + rr) * C + c0 + cc;
    #pragma unroll
    for (int i = 0; i < 4; ++i) f[i] = *(const float4*)(src + 4 * i);

    if (DN) {
        bf16x8 h0, h1;
        #pragma unroll
        for (int i = 0; i < 2; ++i) {
            h0[i*4+0] = (bf16)f[i].x;   h0[i*4+1] = (bf16)f[i].y;
            h0[i*4+2] = (bf16)f[i].z;   h0[i*4+3] = (bf16)f[i].w;
            h1[i*4+0] = (bf16)f[i+2].x; h1[i*4+1] = (bf16)f[i+2].y;
            h1[i*4+2] = (bf16)f[i+2].z; h1[i*4+3] = (bf16)f[i+2].w;
        }
        bf16* dst = outN + zoff + (size_t)(r0 + rr) * C + c0 + cc;
        *(bf16x8*)dst = h0;
        *(bf16x8*)(dst + 8) = h1;
    }
    if (DT) {
        #pragma unroll
        for (int i = 0; i < 4; ++i) {
            ts[rr][cc + 4*i + 0] = f[i].x;
            ts[rr][cc + 4*i + 1] = f[i].y;
            ts[rr][cc + 4*i + 2] = f[i].z;
            ts[rr][cc + 4*i + 3] = f[i].w;
        }
        __syncthreads();
        const int ct = t >> 2, rr4 = (t & 3) * 16;
        bf16x8 o0, o1;
        #pragma unroll
        for (int i = 0; i < 8; ++i) o0[i] = (bf16)ts[rr4 + i][ct];
        #pragma unroll
        for (int i = 0; i < 8; ++i) o1[i] = (bf16)ts[rr4 + 8 + i][ct];
        bf16* dst = outT + zoff + (size_t)(c0 + ct) * R + r0 + rr4;
        *(bf16x8*)dst = o0;
        *(bf16x8*)(dst + 8) = o1;
    }
}

// ---------------- row softmax over 2048-wide rows ----------------
__global__ __launch_bounds__(256)
void softmax_k(const bf16* __restrict__ S, bf16* __restrict__ A)
{
    const size_t row = blockIdx.x;
    const int t = threadIdx.x;
    const int wid = t >> 6, lane = t & 63;
    __shared__ float r1[4], r2[4];

    bf16x8 v = *(const bf16x8*)(S + row * 2048 + t * 8);
    float f[8];
    float mx = -1e30f;
    #pragma unroll
    for (int i = 0; i < 8; ++i) { f[i] = (float)v[i]; mx = fmaxf(mx, f[i]); }
    #pragma unroll
    for (int o = 32; o; o >>= 1) mx = fmaxf(mx, __shfl_xor(mx, o, 64));
    if (!lane) r1[wid] = mx;
    __syncthreads();
    mx = fmaxf(fmaxf(r1[0], r1[1]), fmaxf(r1[2], r1[3]));

    float sum = 0.f;
    #pragma unroll
    for (int i = 0; i < 8; ++i) { f[i] = __expf(f[i] - mx); sum += f[i]; }
    #pragma unroll
    for (int o = 32; o; o >>= 1) sum += __shfl_xor(sum, o, 64);
    if (!lane) r2[wid] = sum;
    __syncthreads();
    sum = r2[0] + r2[1] + r2[2] + r2[3];

    const float inv = 1.f / sum;
    bf16x8 ov;
    #pragma unroll
    for (int i = 0; i < 8; ++i) ov[i] = (bf16)(f[i] * inv);
    *(bf16x8*)(A + row * 2048 + t * 8) = ov;
}

// ---------------- rowdot[r] = dot(U[r,:512], H[r,:512]) — FA-backward delta ----------------
__global__ __launch_bounds__(256)
void rowdot_k(const bf16* __restrict__ U, const bf16* __restrict__ H, float* __restrict__ rd)
{
    const int r = blockIdx.x * 4 + (threadIdx.x >> 6);
    const int lane = threadIdx.x & 63;
    bf16x8 uv = *(const bf16x8*)(U + (size_t)r * 512 + lane * 8);
    bf16x8 hv = *(const bf16x8*)(H + (size_t)r * 512 + lane * 8);
    float d = 0.f;
    #pragma unroll
    for (int i = 0; i < 8; ++i) d += (float)uv[i] * (float)hv[i];
    #pragma unroll
    for (int o = 32; o; o >>= 1) d += __shfl_xor(d, o, 64);
    if (!lane) rd[r] = d;
}

extern "C" void kernel_launch(void* const* d_in, const int* in_sizes, int n_in,
                              void* d_out, int out_size, void* d_ws, size_t ws_size,
                              hipStream_t stream)
{
    const float* Q  = (const float*)d_in[0];
    const float* Km = (const float*)d_in[1];
    const float* V  = (const float*)d_in[2];
    const float* W1 = (const float*)d_in[3];
    const float* b1 = (const float*)d_in[4];
    const float* W2 = (const float*)d_in[5];
    float* out = (float*)d_out;

    // ---- workspace layout (~236 MB, live-range packed) ----
    char* ws = (char*)d_ws;
    bf16* Amat = (bf16*)(ws);                    // R1: A, then dS (in-place)   67.1 MB
    bf16* AO   = (bf16*)(ws + 67108864);         // R2: Kb (pre-GEMM3), then attn_out bf16
    bf16* Kb   = AO;
    bf16* KbT  = (bf16*)(ws + 100663296);        // R3: K^T bf16
    bf16* Vb   = (bf16*)(ws + 134217728);        // R4: V bf16 -> H (after VW1)
    bf16* Hb   = Vb;
    bf16* VbT  = (bf16*)(ws + 167772160);        // R5: V^T bf16 -> U
    bf16* U    = VbT;
    bf16* Qb   = (bf16*)(ws + 201326592);        // R6: Q bf16 -> VW1 [2048][512]/batch
    bf16* VW1b = Qb;
    bf16* W1T  = (bf16*)(ws + 234881024);        // R7: W1^T bf16 [512][1024] (1 MB)
    float* rowdot = (float*)(ws + 235929600);    // R8: rowdot f32 [16384] (64 KB)
    bf16* S    = (bf16*)d_out;                   // S (dead after softmax; d_out reused for out)

    const long sQK = 2048L * 1024;
    const long sS  = 2048L * 2048;
    const long sVW = 2048L * 512;
    dim3 blk(256), blkG(512);

    // ---- prep: bf16 casts / transposes ----
    transcast_k<true,  false><<<dim3(16, 32, 8), blk, 0, stream>>>(Q,  Qb, nullptr, 2048, 1024);
    transcast_k<true,  true ><<<dim3(16, 32, 8), blk, 0, stream>>>(Km, Kb, KbT,     2048, 1024);
    transcast_k<true,  true ><<<dim3(16, 32, 8), blk, 0, stream>>>(V,  Vb, VbT,     2048, 1024);
    transcast_k<false, true ><<<dim3(8,  16, 1), blk, 0, stream>>>(W1, nullptr, W1T, 1024, 512);

    // 1) S = scale * Qb @ Kb^T
    gemm2b<0><<<dim3(16, 16, 8), blk, 0, stream>>>(
        Qb, Kb, S, 1024, 1024, 1024, 2048, sQK, sQK, sS, 0.03125f, nullptr, nullptr);

    // 1b) VW1 = V @ W1  (B = W1^T; overwrites Qb region — Qb dead after GEMM 1)
    gemm_nc<0, 2><<<dim3(4, 8, 8), blkG, 0, stream>>>(
        Vb, W1T, VW1b, 1024, 1024, 1024, 512, sQK, 0, sVW, 1.0f, nullptr, nullptr, nullptr);

    // 2) A = row-softmax(S)
    softmax_k<<<dim3(16384), blk, 0, stream>>>(S, Amat);

    // 3) attn_out = A @ V   (B = V^T [1024][2048]; overwrites Kb region with AO)
    gemm2b<0><<<dim3(8, 16, 8), blk, 0, stream>>>(
        Amat, VbT, AO, 2048, 2048, 2048, 1024, sS, sQK, sQK, 1.0f, nullptr, nullptr);

    // 4) U = silu'(AO @ W1 + b1) * w2 ; H = AO @ W1   (H into dead Vb region)
    gemm_nc<3, 2><<<dim3(4, 64, 1), blkG, 0, stream>>>(
        AO, W1T, U, 1024, 1024, 1024, 512, 0, 0, 0, 1.0f, b1, W2, Hb);

    // 5) rowdot[n] = dot(U[n], H[n])   (= rowsum(A .* dA), FA-backward identity)
    rowdot_k<<<dim3(4096), blk, 0, stream>>>(U, Hb, rowdot);

    // 6) dS = A .* (U @ VW1^T - rowdot)  — K=512 GEMM, epilogue-fused, in-place into Amat
    gemm2b<1><<<dim3(16, 16, 8), blk, 0, stream>>>(
        U, VW1b, Amat, 512, 512, 512, 2048, sVW, sVW, sS, 1.0f, rowdot, Amat);

    // 7) out = V + attn_out - (eps*scale) * dS @ K   (B = K^T [1024][2048])
    gemm2b<2><<<dim3(8, 16, 8), blk, 0, stream>>>(
        Amat, KbT, out, 2048, 2048, 2048, 1024, sS, sQK, sQK, 0.03f * 0.03125f, V, AO);
}

// Round 6
// 480.923 us; speedup vs baseline: 1.0218x; 1.0218x over previous
//
#include <hip/hip_runtime.h>

typedef __bf16 bf16;
typedef __attribute__((ext_vector_type(8))) __bf16 bf16x8;
typedef __attribute__((ext_vector_type(4))) float f32x4;

#define MEMFENCE asm volatile("" ::: "memory")

template<typename T>
__device__ __forceinline__ void stnt(T* p, T v) { __builtin_nontemporal_store(v, p); }
template<typename T>
__device__ __forceinline__ T ldnt(const T* p) { return __builtin_nontemporal_load(p); }

// async global->LDS, 16B per lane; LDS dest = wave-uniform base + lane*16
__device__ __forceinline__ void gload16(const bf16* g, bf16* l) {
    __builtin_amdgcn_global_load_lds(
        (const __attribute__((address_space(1))) void*)g,
        (__attribute__((address_space(3))) void*)l,
        16, 0, 0);
}

// ============ 256x256 8-wave bf16 NT GEMM, BK=64, 4-seg cross-fed pipeline (R6) ============
// R3 engine (best verified, 420us) + NON-TEMPORAL intermediate stores chain-wide.
// Theory: chained GEMMs read lines freshly written by the producer kernel -> dirty in remote
// XCD L2s -> cross-XCD probe/writeback halves effective staging bandwidth (measured ~5.7-8.7
// TB/s vs m201's 12.2 clean-L3).  nt stores stream producer output past local L2 so consumers
// read clean lines.
// LDS: A bufs {0,1,2} at a*32768 (96K, triple), B bufs {0,1} at 98304+p*32768 (64K, double).
// Quadrant order per tile u: (0,2)->(0,0)->(4,0)->(4,2).  Registers: a[4][2] al(u)->ah(u)->
// al(u+1); bh pre-read prev seg4; bl read seg1.  Barriers: 2/tile.
// RACE INVARIANT: every cross-wave LDS read sits after a {per-wave vmcnt confirming that
// data -> s_barrier} pair.  Single wait per tile at end of seg2 (W1):
//   steady (st2): queue [A(u+1)4, B(u+1)4, A(u+2)4] -> vmcnt(4) confirms A(u+1) AND B(u+1);
//   tail u=NTt-2: vmcnt(0).  Last tile: nothing outstanding.
// st_16x32 swizzle: phys = off ^ (((off>>9)&1)<<5); inverse-swizzled global source.
// EPI 0: bf16 C = alpha*acc
// EPI 1: bf16 C[ix] = aux3[ix] * (acc - aux1[zb*2048+row])      (dS = A*(dA-rowdot), in-place ok)
// EPI 2: f32  C = aux1[ix] + (float)aux3[ix] - alpha*acc        (out = V + AO - eps*scale*dQacc)
template<int EPI>
__global__ __launch_bounds__(512, 1)
void gemm8p(const bf16* __restrict__ A, const bf16* __restrict__ Bm,
            void* __restrict__ Cp, int Kdim, int lda, int ldb, int ldc,
            long sA, long sB, long sC, float alpha,
            const float* __restrict__ aux1, const bf16* __restrict__ aux3)
{
    __shared__ __align__(16) char smem[163840];

    // XCD-aware bijective swizzle (ntot % 8 == 0 for all launches)
    const int gx = gridDim.x, gy = gridDim.y;
    int lin = blockIdx.x + gx * (blockIdx.y + gy * blockIdx.z);
    const int q = (gx * gy * gridDim.z) >> 3;
    lin = (lin & 7) * q + (lin >> 3);
    const int bx = lin % gx;
    const int rem0 = lin / gx;
    const int by = rem0 % gy;
    const int bz = rem0 / gy;

    const int t0 = threadIdx.x;
    const int w = t0 >> 6, lane = t0 & 63;
    const int wm = w >> 2, wn = w & 3;          // 2 x 4 wave grid; per-wave C = 128 x 64
    const int m0 = by * 256, n0 = bx * 256;
    const long zb = bz;

    const bf16* Ab = A  + zb * sA + (size_t)m0 * lda;
    const bf16* Bb = Bm + zb * sB + (size_t)n0 * ldb;

    // staging lane coords: wave w stages subtiles {w, 8+w} of a 128-row half-tile
    const int sr16 = lane >> 2;
    const int sce  = ((((lane & 3) << 4) ^ (((lane >> 5) & 1) << 5))) >> 1; // inv-swizzled col
    const int r0s = (w >> 1) * 16 + sr16;
    const int c0s = (w & 1) * 32 + sce;
    const bf16* gA0 = Ab + (size_t)r0s * lda + c0s;
    const bf16* gA1 = Ab + (size_t)(128 + r0s) * lda + c0s;
    const bf16* gB0 = Bb + (size_t)r0s * ldb + c0s;
    const bf16* gB1 = Bb + (size_t)(128 + r0s) * ldb + c0s;
    const size_t a64 = (size_t)64 * lda, b64 = (size_t)64 * ldb;
    const int ldsW0 = w * 1024, ldsW1 = (8 + w) * 1024;

    // fragment-read bases (16x16x32 layout)
    const int lr = lane & 15, lkq = lane >> 4;
    const int phx = ((lane >> 3) & 1) << 5;
    const int frag_base = (lr * 64 + lkq * 16) ^ phx;
    const char* aR = smem + wm * 16384 + frag_base;                    // + aOff + sub*1024
    const char* bR = smem + 98304 + (wn >> 1) * 16384 + (wn & 1) * 8192 + frag_base; // + p*32768

    f32x4 acc[8][4] = {};
    const int NTt = Kdim >> 6;                  // K-tiles of 64 (8/16/32, always even)

    auto stgA = [&](int h, int u, int off) {
        char* L = smem + off + h * 16384;
        const bf16* g = h ? gA1 : gA0;
        gload16(g + (size_t)u * 64,        (bf16*)(L + ldsW0));
        gload16(g + a64 + (size_t)u * 64,  (bf16*)(L + ldsW1));
    };
    auto stgB = [&](int h, int u, int p) {
        char* L = smem + 98304 + p * 32768 + h * 16384;
        const bf16* g = h ? gB1 : gB0;
        gload16(g + (size_t)u * 64,        (bf16*)(L + ldsW0));
        gload16(g + b64 + (size_t)u * 64,  (bf16*)(L + ldsW1));
    };

    // ---- prologue: A(0),B(0),A(1),B(1); vmcnt(8) confirms A(0),B(0); barrier publishes ----
    stgA(0, 0, 0);     stgA(1, 0, 0);     stgB(0, 0, 0); stgB(1, 0, 0);
    stgA(0, 1, 32768); stgA(1, 1, 32768); stgB(0, 1, 1); stgB(1, 1, 1);
    asm volatile("s_waitcnt vmcnt(8)" ::: "memory");
    __builtin_amdgcn_s_barrier();
    MEMFENCE;

    bf16x8 a[4][2], bl[2][2], bh[2][2];
    // pre-read al(0) and bh(0)
    #pragma unroll
    for (int mf = 0; mf < 4; ++mf)
        #pragma unroll
        for (int ks = 0; ks < 2; ++ks)
            a[mf][ks] = *(const bf16x8*)(aR + (mf * 2 + ks) * 1024);
    #pragma unroll
    for (int nf = 0; nf < 2; ++nf)
        #pragma unroll
        for (int ks = 0; ks < 2; ++ks)
            bh[nf][ks] = *(const bf16x8*)(bR + ((2 + nf) * 2 + ks) * 1024);

#define QUADQ(MFB, NFB, AARR, BARR)                                                     \
    __builtin_amdgcn_s_setprio(1);                                                      \
    _Pragma("unroll")                                                                   \
    for (int ks = 0; ks < 2; ++ks)                                                      \
        _Pragma("unroll")                                                               \
        for (int mf = 0; mf < 4; ++mf)                                                  \
            _Pragma("unroll")                                                           \
            for (int nf = 0; nf < 2; ++nf)                                              \
                acc[(MFB) + mf][(NFB) + nf] = __builtin_amdgcn_mfma_f32_16x16x32_bf16(  \
                    AARR[mf][ks], BARR[nf][ks], acc[(MFB) + mf][(NFB) + nf], 0, 0, 0);  \
    __builtin_amdgcn_s_setprio(0);

    int aOff = 0, aOff1 = 32768, sOff = 65536;  // A(u), A(u+1), stage A(u+2)
    for (int u = 0; u < NTt; ++u) {
        const int p = u & 1;
        const char* aP  = aR + aOff;
        const char* aP1 = aR + aOff1;
        const char* bP  = bR + p * 32768;
        const char* bP1 = bR + (p ^ 1) * 32768;
        const bool st2 = (u + 2 < NTt), nx = (u + 1 < NTt);

        // ---- seg1: Q(0,2)=al*bh ; read bl(u) [4]; stage A0(u+2) ----
        if (st2) stgA(0, u + 2, sOff);
        #pragma unroll
        for (int nf = 0; nf < 2; ++nf)
            #pragma unroll
            for (int ks = 0; ks < 2; ++ks)
                bl[nf][ks] = *(const bf16x8*)(bP + (nf * 2 + ks) * 1024);
        QUADQ(0, 2, a, bh)

        // ---- seg2: Q(0,0)=al*bl ; a <- ah(u) [8]; stage A1(u+2); W1; barrier1 ----
        if (st2) stgA(1, u + 2, sOff);
        QUADQ(0, 0, a, bl)
        #pragma unroll
        for (int mf = 0; mf < 4; ++mf)
            #pragma unroll
            for (int ks = 0; ks < 2; ++ks)
                a[mf][ks] = *(const bf16x8*)(aP + ((4 + mf) * 2 + ks) * 1024);
        MEMFENCE;
        if (st2)     asm volatile("s_waitcnt vmcnt(4)" ::: "memory");  // A(u+1)+B(u+1)
        else if (nx) asm volatile("s_waitcnt vmcnt(0)" ::: "memory");  // tail: confirm both
        __builtin_amdgcn_s_barrier();
        MEMFENCE;

        // ---- seg3: Q(4,0)=ah*bl ; stage B0(u+2) ----
        if (st2) stgB(0, u + 2, p);
        QUADQ(4, 0, a, bl)

        // ---- seg4: Q(4,2)=ah*bh ; a <- al(u+1) [8]; bh <- bh(u+1) [4]; barrier2 ----
        if (st2) stgB(1, u + 2, p);
        QUADQ(4, 2, a, bh)
        if (nx) {
            #pragma unroll
            for (int mf = 0; mf < 4; ++mf)
                #pragma unroll
                for (int ks = 0; ks < 2; ++ks)
                    a[mf][ks] = *(const bf16x8*)(aP1 + (mf * 2 + ks) * 1024);
            #pragma unroll
            for (int nf = 0; nf < 2; ++nf)
                #pragma unroll
                for (int ks = 0; ks < 2; ++ks)
                    bh[nf][ks] = *(const bf16x8*)(bP1 + ((2 + nf) * 2 + ks) * 1024);
        }
        MEMFENCE;
        __builtin_amdgcn_s_barrier();
        MEMFENCE;

        const int tmp = aOff; aOff = aOff1; aOff1 = sOff; sOff = tmp;
    }
#undef QUADQ

    // ---- epilogue: D layout col=lane&15, row=(lane>>4)*4+reg; nt stores (clean lines) ----
    const int rb  = m0 + wm * 128 + lkq * 4;
    const int cb0 = n0 + wn * 64 + lr;
    #pragma unroll
    for (int mf = 0; mf < 8; ++mf) {
        #pragma unroll
        for (int r = 0; r < 4; ++r) {
            const int rw = rb + mf * 16 + r;
            float rd = 0.f;
            if (EPI == 1) rd = aux1[zb * 2048 + rw];
            #pragma unroll
            for (int nf = 0; nf < 4; ++nf) {
                const int c = cb0 + nf * 16;
                const size_t ix = (size_t)rw * ldc + c;
                const float v = acc[mf][nf][r];
                if (EPI == 0) {
                    stnt((bf16*)Cp + zb * sC + ix, (bf16)(alpha * v));
                } else if (EPI == 1) {
                    bf16* Cb = (bf16*)Cp + zb * sC;
                    const bf16* Am = aux3 + zb * sC;
                    stnt(Cb + ix, (bf16)((float)ldnt(Am + ix) * (v - rd)));
                } else {
                    float* C = (float*)Cp + zb * sC;
                    const float* Vv = aux1 + zb * sC;
                    const bf16* AOv = aux3 + zb * sC;
                    stnt(C + ix, ldnt(Vv + ix) + (float)ldnt(AOv + ix) - alpha * v);
                }
            }
        }
    }
}

// ===== round-6 engine: 256 x (64*NF) quad-slot BK=32 cross-step =====
// EPI 0: bf16 C = alpha*acc
// EPI 3: bf16 C = silu'(acc + aux1[col]) * aux2[col];  H[ix] = (bf16)acc  (H via aux3, cast)
template<int EPI, int NF>
__global__ __launch_bounds__(512, 1)
void gemm_nc(const bf16* __restrict__ A, const bf16* __restrict__ Bm,
             void* __restrict__ Cp, int Kdim, int lda, int ldb, int ldc,
             long sA, long sB, long sC, float alpha,
             const float* __restrict__ aux1, const float* __restrict__ aux2,
             const bf16* __restrict__ aux3)
{
    constexpr int SB = NF * 4096;
    __shared__ __align__(16) char smem[65536 + 4 * SB];

    const int gx = gridDim.x, gy = gridDim.y;
    int lin = blockIdx.x + gx * (blockIdx.y + gy * blockIdx.z);
    const int q = (gx * gy * gridDim.z) >> 3;
    lin = (lin & 7) * q + (lin >> 3);
    const int bx = lin % gx;
    const int rem0 = lin / gx;
    const int by = rem0 % gy;
    const int bz = rem0 / gy;

    const int t0 = threadIdx.x;
    const int w = t0 >> 6, lane = t0 & 63;
    const int wm = w >> 2, wn = w & 3;
    const int m0 = by * 256, n0 = bx * (64 * NF);
    const long zb = bz;

    const bf16* Ab = A  + zb * sA + (size_t)m0 * lda;
    const bf16* Bb = Bm + zb * sB + (size_t)n0 * ldb;

    const int sr16 = lane >> 2;
    const int sce  = ((((lane & 3) << 4) ^ (((lane >> 5) & 1) << 5))) >> 1;
    const int stg0 = w * 2, stg1 = w * 2 + 1;
    const bf16* pA0 = Ab + (size_t)(stg0 * 16 + sr16) * lda + sce;
    const bf16* pA1 = Ab + (size_t)(stg1 * 16 + sr16) * lda + sce;
    const bf16* pB0 = Bb + (size_t)((NF == 4 ? stg0 : w) * 16 + sr16) * ldb + sce;
    const bf16* pB1 = Bb + (size_t)(stg1 * 16 + sr16) * ldb + sce;

    const int lr = lane & 15, lkq = lane >> 4;
    const int phx = ((lane >> 3) & 1) << 5;
    const int frag_base = lr * 64 + lkq * 16;

    f32x4 acc[8][NF] = {};
    const int NT = Kdim >> 5;

    auto issueSlot = [&](int p) {
        char* lA = smem + (p & 3) * 16384;
        char* lB = smem + 65536 + (p & 3) * SB;
        const int kt = p << 5;
        gload16(pA0 + kt, (bf16*)(lA + stg0 * 1024));
        gload16(pA1 + kt, (bf16*)(lA + stg1 * 1024));
        if (NF == 4) {
            gload16(pB0 + kt, (bf16*)(lB + stg0 * 1024));
            gload16(pB1 + kt, (bf16*)(lB + stg1 * 1024));
        } else {
            gload16(pB0 + kt, (bf16*)(lB + w * 1024));
        }
    };
    auto rdA = [&](const char* base, int sub) {
        return *(const bf16x8*)(base + (((sub << 10) + frag_base) ^ phx));
    };

    issueSlot(0); issueSlot(1); issueSlot(2);
    if (NF == 4) asm volatile("s_waitcnt vmcnt(4)" ::: "memory");
    else         asm volatile("s_waitcnt vmcnt(3)" ::: "memory");
    __builtin_amdgcn_s_barrier();
    MEMFENCE;

    bf16x8 alo[4], ahi[4], b0[NF], b1[NF];
    {
        const char* cA = smem;
        const char* cB = smem + 65536;
        #pragma unroll
        for (int mf = 0; mf < 4; ++mf) alo[mf] = rdA(cA, wm * 8 + mf);
        #pragma unroll
        for (int nf = 0; nf < NF; ++nf) b0[nf] = rdA(cB, wn * NF + nf);
    }

    auto stepBody = [&](int SL, int s, bf16x8 (&bA)[NF], bf16x8 (&bB)[NF]) {
        if (s + 3 < NT) issueSlot(s + 3);
        const char* cA = smem + SL * 16384;
        #pragma unroll
        for (int mf = 0; mf < 4; ++mf) ahi[mf] = rdA(cA, wm * 8 + 4 + mf);

        __builtin_amdgcn_s_setprio(1);
        #pragma unroll
        for (int mf = 0; mf < 4; ++mf)
            #pragma unroll
            for (int nf = 0; nf < NF; ++nf)
                acc[mf][nf] = __builtin_amdgcn_mfma_f32_16x16x32_bf16(alo[mf], bA[nf], acc[mf][nf], 0, 0, 0);
        __builtin_amdgcn_s_setprio(0);

        if (s + 1 < NT) {
            const int NS = (SL + 1) & 3;
            const char* nA = smem + NS * 16384;
            const char* nB = smem + 65536 + NS * SB;
            #pragma unroll
            for (int mf = 0; mf < 4; ++mf) alo[mf] = rdA(nA, wm * 8 + mf);
            #pragma unroll
            for (int nf = 0; nf < NF; ++nf) bB[nf] = rdA(nB, wn * NF + nf);
        }

        __builtin_amdgcn_s_setprio(1);
        #pragma unroll
        for (int mf = 0; mf < 4; ++mf)
            #pragma unroll
            for (int nf = 0; nf < NF; ++nf)
                acc[4 + mf][nf] = __builtin_amdgcn_mfma_f32_16x16x32_bf16(ahi[mf], bA[nf], acc[4 + mf][nf], 0, 0, 0);
        __builtin_amdgcn_s_setprio(0);

        MEMFENCE;
        if (s + 3 < NT) {
            if (NF == 4) asm volatile("s_waitcnt vmcnt(4)" ::: "memory");
            else         asm volatile("s_waitcnt vmcnt(3)" ::: "memory");
        } else {
            asm volatile("s_waitcnt vmcnt(0)" ::: "memory");
        }
        __builtin_amdgcn_s_barrier();
        MEMFENCE;
    };

    for (int s = 0; s < NT; s += 2) {
        stepBody(s & 3, s, b0, b1);
        stepBody((s + 1) & 3, s + 1, b1, b0);
    }

    const int rb  = m0 + wm * 128 + lkq * 4;
    const int cb0 = n0 + wn * (NF * 16) + lr;
    #pragma unroll
    for (int mf = 0; mf < 8; ++mf) {
        #pragma unroll
        for (int nf = 0; nf < NF; ++nf) {
            const int c = cb0 + nf * 16;
            #pragma unroll
            for (int r = 0; r < 4; ++r) {
                const int rw = rb + mf * 16 + r;
                const size_t ix = (size_t)rw * ldc + c;
                const float v = acc[mf][nf][r];
                if (EPI == 0) {
                    stnt((bf16*)Cp + zb * sC + ix, (bf16)(alpha * v));
                } else {   // EPI == 3: U + H
                    const float u = v + aux1[c];
                    const float sg = 1.f / (1.f + __expf(-u));
                    const float dd = sg * (1.f + u * (1.f - sg));
                    stnt((bf16*)Cp + ix, (bf16)(dd * aux2[c]));
                    stnt((bf16*)aux3 + ix, (bf16)v);   // H = AO@W1 (pre-bias)
                }
            }
        }
    }
}

// ---------------- fp32 -> bf16 cast (DN) and/or transposed cast (DT) ----------------
template<bool DN, bool DT>
__global__ __launch_bounds__(256)
void transcast_k(const float* __restrict__ in, bf16* __restrict__ outN,
                 bf16* __restrict__ outT, int R, int C)
{
    __shared__ float ts[64][65];
    const int t = threadIdx.x;
    const int c0 = blockIdx.x * 64, r0 = blockIdx.y * 64;
    const size_t zoff = (size_t)blockIdx.z * R * C;

    const int rr = t >> 2, cc = (t & 3) * 16;
    float4 f[4];
    const float* src = in + zoff + (size_t)(r0 + rr) * C + c0 + cc;
    #pragma unroll
    for (int i = 0; i < 4; ++i) f[i] = *(const float4*)(src + 4 * i);

    if (DN) {
        bf16x8 h0, h1;
        #pragma unroll
        for (int i = 0; i < 2; ++i) {
            h0[i*4+0] = (bf16)f[i].x;   h0[i*4+1] = (bf16)f[i].y;
            h0[i*4+2] = (bf16)f[i].z;   h0[i*4+3] = (bf16)f[i].w;
            h1[i*4+0] = (bf16)f[i+2].x; h1[i*4+1] = (bf16)f[i+2].y;
            h1[i*4+2] = (bf16)f[i+2].z; h1[i*4+3] = (bf16)f[i+2].w;
        }
        bf16* dst = outN + zoff + (size_t)(r0 + rr) * C + c0 + cc;
        stnt((bf16x8*)dst, h0);
        stnt((bf16x8*)(dst + 8), h1);
    }
    if (DT) {
        #pragma unroll
        for (int i = 0; i < 4; ++i) {
            ts[rr][cc + 4*i + 0] = f[i].x;
            ts[rr][cc + 4*i + 1] = f[i].y;
            ts[rr][cc + 4*i + 2] = f[i].z;
            ts[rr][cc + 4*i + 3] = f[i].w;
        }
        __syncthreads();
        const int ct = t >> 2, rr4 = (t & 3) * 16;
        bf16x8 o0, o1;
        #pragma unroll
        for (int i = 0; i < 8; ++i) o0[i] = (bf16)ts[rr4 + i][ct];
        #pragma unroll
        for (int i = 0; i < 8; ++i) o1[i] = (bf16)ts[rr4 + 8 + i][ct];
        bf16* dst = outT + zoff + (size_t)(c0 + ct) * R + r0 + rr4;
        stnt((bf16x8*)dst, o0);
        stnt((bf16x8*)(dst + 8), o1);
    }
}

// ---------------- row softmax over 2048-wide rows ----------------
__global__ __launch_bounds__(256)
void softmax_k(const bf16* __restrict__ S, bf16* __restrict__ A)
{
    const size_t row = blockIdx.x;
    const int t = threadIdx.x;
    const int wid = t >> 6, lane = t & 63;
    __shared__ float r1[4], r2[4];

    bf16x8 v = ldnt((const bf16x8*)(S + row * 2048 + t * 8));
    float f[8];
    float mx = -1e30f;
    #pragma unroll
    for (int i = 0; i < 8; ++i) { f[i] = (float)v[i]; mx = fmaxf(mx, f[i]); }
    #pragma unroll
    for (int o = 32; o; o >>= 1) mx = fmaxf(mx, __shfl_xor(mx, o, 64));
    if (!lane) r1[wid] = mx;
    __syncthreads();
    mx = fmaxf(fmaxf(r1[0], r1[1]), fmaxf(r1[2], r1[3]));

    float sum = 0.f;
    #pragma unroll
    for (int i = 0; i < 8; ++i) { f[i] = __expf(f[i] - mx); sum += f[i]; }
    #pragma unroll
    for (int o = 32; o; o >>= 1) sum += __shfl_xor(sum, o, 64);
    if (!lane) r2[wid] = sum;
    __syncthreads();
    sum = r2[0] + r2[1] + r2[2] + r2[3];

    const float inv = 1.f / sum;
    bf16x8 ov;
    #pragma unroll
    for (int i = 0; i < 8; ++i) ov[i] = (bf16)(f[i] * inv);
    stnt((bf16x8*)(A + row * 2048 + t * 8), ov);
}

// ---------------- rowdot[r] = dot(U[r,:512], H[r,:512]) — FA-backward delta ----------------
__global__ __launch_bounds__(256)
void rowdot_k(const bf16* __restrict__ U, const bf16* __restrict__ H, float* __restrict__ rd)
{
    const int r = blockIdx.x * 4 + (threadIdx.x >> 6);
    const int lane = threadIdx.x & 63;
    bf16x8 uv = *(const bf16x8*)(U + (size_t)r * 512 + lane * 8);
    bf16x8 hv = *(const bf16x8*)(H + (size_t)r * 512 + lane * 8);
    float d = 0.f;
    #pragma unroll
    for (int i = 0; i < 8; ++i) d += (float)uv[i] * (float)hv[i];
    #pragma unroll
    for (int o = 32; o; o >>= 1) d += __shfl_xor(d, o, 64);
    if (!lane) rd[r] = d;
}

extern "C" void kernel_launch(void* const* d_in, const int* in_sizes, int n_in,
                              void* d_out, int out_size, void* d_ws, size_t ws_size,
                              hipStream_t stream)
{
    const float* Q  = (const float*)d_in[0];
    const float* Km = (const float*)d_in[1];
    const float* V  = (const float*)d_in[2];
    const float* W1 = (const float*)d_in[3];
    const float* b1 = (const float*)d_in[4];
    const float* W2 = (const float*)d_in[5];
    float* out = (float*)d_out;

    // ---- workspace layout (~236 MB, live-range packed) ----
    char* ws = (char*)d_ws;
    bf16* Amat = (bf16*)(ws);                    // R1: A, then dS (in-place)   67.1 MB
    bf16* AO   = (bf16*)(ws + 67108864);         // R2: Kb (pre-GEMM3), then attn_out bf16
    bf16* Kb   = AO;
    bf16* KbT  = (bf16*)(ws + 100663296);        // R3: K^T bf16
    bf16* Vb   = (bf16*)(ws + 134217728);        // R4: V bf16 -> H (after VW1)
    bf16* Hb   = Vb;
    bf16* VbT  = (bf16*)(ws + 167772160);        // R5: V^T bf16 -> U
    bf16* U    = VbT;
    bf16* Qb   = (bf16*)(ws + 201326592);        // R6: Q bf16 -> VW1 [2048][512]/batch
    bf16* VW1b = Qb;
    bf16* W1T  = (bf16*)(ws + 234881024);        // R7: W1^T bf16 [512][1024] (1 MB)
    float* rowdot = (float*)(ws + 235929600);    // R8: rowdot f32 [16384] (64 KB)
    bf16* S    = (bf16*)d_out;                   // S (dead after softmax; d_out reused for out)

    const long sQK = 2048L * 1024;
    const long sS  = 2048L * 2048;
    const long sVW = 2048L * 512;
    dim3 blk(256), blkG(512);

    // ---- prep: bf16 casts / transposes ----
    transcast_k<true,  false><<<dim3(16, 32, 8), blk, 0, stream>>>(Q,  Qb, nullptr, 2048, 1024);
    transcast_k<true,  true ><<<dim3(16, 32, 8), blk, 0, stream>>>(Km, Kb, KbT,     2048, 1024);
    transcast_k<true,  true ><<<dim3(16, 32, 8), blk, 0, stream>>>(V,  Vb, VbT,     2048, 1024);
    transcast_k<false, true ><<<dim3(8,  16, 1), blk, 0, stream>>>(W1, nullptr, W1T, 1024, 512);

    // 1) S = scale * Qb @ Kb^T
    gemm8p<0><<<dim3(8, 8, 8), blkG, 0, stream>>>(
        Qb, Kb, S, 1024, 1024, 1024, 2048, sQK, sQK, sS, 0.03125f, nullptr, nullptr);

    // 1b) VW1 = V @ W1  (B = W1^T; overwrites Qb region — Qb dead after GEMM 1)
    gemm_nc<0, 2><<<dim3(4, 8, 8), blkG, 0, stream>>>(
        Vb, W1T, VW1b, 1024, 1024, 1024, 512, sQK, 0, sVW, 1.0f, nullptr, nullptr, nullptr);

    // 2) A = row-softmax(S)
    softmax_k<<<dim3(16384), blk, 0, stream>>>(S, Amat);

    // 3) attn_out = A @ V   (B = V^T [1024][2048]; overwrites Kb region with AO)
    gemm8p<0><<<dim3(4, 8, 8), blkG, 0, stream>>>(
        Amat, VbT, AO, 2048, 2048, 2048, 1024, sS, sQK, sQK, 1.0f, nullptr, nullptr);

    // 4) U = silu'(AO @ W1 + b1) * w2 ; H = AO @ W1   (H into dead Vb region)
    gemm_nc<3, 2><<<dim3(4, 64, 1), blkG, 0, stream>>>(
        AO, W1T, U, 1024, 1024, 1024, 512, 0, 0, 0, 1.0f, b1, W2, Hb);

    // 5) rowdot[n] = dot(U[n], H[n])   (= rowsum(A .* dA), FA-backward identity)
    rowdot_k<<<dim3(4096), blk, 0, stream>>>(U, Hb, rowdot);

    // 6) dS = A .* (U @ VW1^T - rowdot)  — K=512 GEMM, epilogue-fused, in-place into Amat
    gemm8p<1><<<dim3(8, 8, 8), blkG, 0, stream>>>(
        U, VW1b, Amat, 512, 512, 512, 2048, sVW, sVW, sS, 1.0f, rowdot, Amat);

    // 7) out = V + attn_out - (eps*scale) * dS @ K   (B = K^T [1024][2048])
    gemm8p<2><<<dim3(4, 8, 8), blkG, 0, stream>>>(
        Amat, KbT, out, 2048, 2048, 2048, 1024, sS, sQK, sQK, 0.03f * 0.03125f, V, AO);
}

// Round 7
// 438.375 us; speedup vs baseline: 1.1210x; 1.0971x over previous
//
#include <hip/hip_runtime.h>

typedef __bf16 bf16;
typedef __attribute__((ext_vector_type(8))) __bf16 bf16x8;
typedef __attribute__((ext_vector_type(4))) float f32x4;

#define MEMFENCE asm volatile("" ::: "memory")

// async global->LDS, 16B per lane; LDS dest = wave-uniform base + lane*16
__device__ __forceinline__ void gload16(const bf16* g, bf16* l) {
    __builtin_amdgcn_global_load_lds(
        (const __attribute__((address_space(1))) void*)g,
        (__attribute__((address_space(3))) void*)l,
        16, 0, 0);
}

// ========== 256x256 16-wave bf16 NT GEMM, BK=64, double-buffered, 1024 threads (R7) ==========
// Supply model (validated R0/R5): per-CU staging supply ≈ 1.2-1.4 B/cyc per resident wave;
// per-tile time = staged-bytes / supply.  R0 (8 waves): 9.8 B/cyc -> 6700 cyc/tile.  This
// kernel keeps the 256² tile's optimal 128 B/MFMA demand but doubles resident waves to 16
// (1024 threads, 1 block/CU) -> predicted ~20 B/cyc -> ~3300 cyc/tile.
// LDS 128KB: buf p at p*65536 = [A 32KB][B 32KB]; each = 32 subtiles [16r x 32c] (1KB),
// slot s = m_sub*2 + ks at s*1024.  Wave w stages slots {w, 16+w} of A and of B (4 gload16).
// Per-wave C = 64x64 (wm=w>>2, wn=w&3): acc[4][4] = 64 VGPRs; __launch_bounds__(1024,4)
// caps regs at 128 so 16 waves/CU fit.
// Schedule per tile u (R5-verified single-barrier discipline): {stage(u+1, p^1)} {per ks:
// 4 b-reads, 4x(a-read + 4 MFMA)} {vmcnt(0) if prefetch issued} {barrier}.  Race audit:
// reads of buf p were staged at tile u-1 and confirmed by that tile's vmcnt(0)+barrier;
// stage into p^1 is WAR-safe (p^1 reads finished before previous barrier).
// st_16x32 swizzle (subtile-local): read addr ^= phx; global source col = sce (inverse).
// D layout: col=lane&15, row=(lane>>4)*4+reg.
// EPI 0: bf16 C = alpha*acc
// EPI 1: bf16 C[ix] = aux3[ix] * (acc - aux1[zb*2048+row])      (dS = A*(dA-rowdot), in-place ok)
// EPI 2: f32  C = aux1[ix] + (float)aux3[ix] - alpha*acc        (out = V + AO - eps*scale*dQacc)
template<int EPI>
__global__ __launch_bounds__(1024, 4)
void gemm16(const bf16* __restrict__ A, const bf16* __restrict__ Bm,
            void* __restrict__ Cp, int Kdim, int lda, int ldb, int ldc,
            long sA, long sB, long sC, float alpha,
            const float* __restrict__ aux1, const bf16* __restrict__ aux3)
{
    __shared__ __align__(16) char smem[131072];

    // XCD-aware bijective swizzle (ntot % 8 == 0 for all launches)
    const int gx = gridDim.x, gy = gridDim.y;
    int lin = blockIdx.x + gx * (blockIdx.y + gy * blockIdx.z);
    const int q = (gx * gy * gridDim.z) >> 3;
    lin = (lin & 7) * q + (lin >> 3);
    const int bx = lin % gx;
    const int rem0 = lin / gx;
    const int by = rem0 % gy;
    const int bz = rem0 / gy;

    const int t0 = threadIdx.x;
    const int w = t0 >> 6, lane = t0 & 63;      // 16 waves, 4x4 grid; per-wave C = 64x64
    const int wm = w >> 2, wn = w & 3;
    const int m0 = by * 256, n0 = bx * 256;
    const long zb = bz;

    const bf16* Ab = A  + zb * sA + (size_t)m0 * lda;
    const bf16* Bb = Bm + zb * sB + (size_t)n0 * ldb;

    // staging lane coords (subtile-local, inverse-swizzled col)
    const int sr16 = lane >> 2;
    const int sce  = ((((lane & 3) << 4) ^ (((lane >> 5) & 1) << 5))) >> 1;
    // wave w stages slots {w, 16+w}: slot s -> rows (s>>1)*16+sr16, cols (s&1)*32+sce
    const int rS0 = (w >> 1) * 16 + sr16;
    const int cS  = (w & 1) * 32 + sce;
    const bf16* gA0 = Ab + (size_t)rS0 * lda + cS;
    const bf16* gA1 = Ab + (size_t)(128 + rS0) * lda + cS;
    const bf16* gB0 = Bb + (size_t)rS0 * ldb + cS;
    const bf16* gB1 = Bb + (size_t)(128 + rS0) * ldb + cS;
    const int ldsS0 = w * 1024, ldsS1 = (16 + w) * 1024;

    // fragment-read bases (16x16x32 layout)
    const int lr = lane & 15, lkq = lane >> 4;
    const int phx = ((lane >> 3) & 1) << 5;
    const int frag_base = (lr * 64 + lkq * 16) ^ phx;

    f32x4 acc[4][4] = {};
    const int NT = Kdim >> 6;                   // BK=64 tiles (8/16/32)

    auto stage = [&](int u, int pp) {
        char* L = smem + pp * 65536;
        const size_t ku = (size_t)u * 64;
        gload16(gA0 + ku, (bf16*)(L + ldsS0));
        gload16(gA1 + ku, (bf16*)(L + ldsS1));
        gload16(gB0 + ku, (bf16*)(L + 32768 + ldsS0));
        gload16(gB1 + ku, (bf16*)(L + 32768 + ldsS1));
    };

    // ---- prologue ----
    stage(0, 0);
    asm volatile("s_waitcnt vmcnt(0)" ::: "memory");
    __builtin_amdgcn_s_barrier();
    MEMFENCE;

    for (int u = 0; u < NT; ++u) {
        const int p = u & 1;
        if (u + 1 < NT) stage(u + 1, p ^ 1);

        const char* aB = smem + p * 65536 + frag_base;
        const char* bB = aB + 32768;

        #pragma unroll
        for (int ks = 0; ks < 2; ++ks) {
            bf16x8 b[4];
            #pragma unroll
            for (int nf = 0; nf < 4; ++nf)
                b[nf] = *(const bf16x8*)(bB + ((wn * 4 + nf) * 2 + ks) * 1024);
            __builtin_amdgcn_s_setprio(1);
            #pragma unroll
            for (int mf = 0; mf < 4; ++mf) {
                const bf16x8 a = *(const bf16x8*)(aB + ((wm * 4 + mf) * 2 + ks) * 1024);
                #pragma unroll
                for (int nf = 0; nf < 4; ++nf)
                    acc[mf][nf] = __builtin_amdgcn_mfma_f32_16x16x32_bf16(a, b[nf], acc[mf][nf], 0, 0, 0);
            }
            __builtin_amdgcn_s_setprio(0);
        }

        MEMFENCE;
        if (u + 1 < NT) asm volatile("s_waitcnt vmcnt(0)" ::: "memory");
        __builtin_amdgcn_s_barrier();
        MEMFENCE;
    }

    // ---- epilogue: D layout col=lane&15, row=(lane>>4)*4+reg ----
    const int rb  = m0 + wm * 64 + lkq * 4;
    const int cb0 = n0 + wn * 64 + lr;
    #pragma unroll
    for (int mf = 0; mf < 4; ++mf) {
        #pragma unroll
        for (int r = 0; r < 4; ++r) {
            const int rw = rb + mf * 16 + r;
            float rd = 0.f;
            if (EPI == 1) rd = aux1[zb * 2048 + rw];
            #pragma unroll
            for (int nf = 0; nf < 4; ++nf) {
                const int c = cb0 + nf * 16;
                const size_t ix = (size_t)rw * ldc + c;
                const float v = acc[mf][nf][r];
                if (EPI == 0) {
                    ((bf16*)Cp + zb * sC)[ix] = (bf16)(alpha * v);
                } else if (EPI == 1) {
                    bf16* Cb = (bf16*)Cp + zb * sC;
                    const bf16* Am = aux3 + zb * sC;
                    Cb[ix] = (bf16)((float)Am[ix] * (v - rd));
                } else {
                    float* C = (float*)Cp + zb * sC;
                    const float* Vv = aux1 + zb * sC;
                    const bf16* AOv = aux3 + zb * sC;
                    C[ix] = Vv[ix] + (float)AOv[ix] - alpha * v;
                }
            }
        }
    }
}

// ===== round-6 engine: 256 x (64*NF) quad-slot BK=32 cross-step =====
// EPI 0: bf16 C = alpha*acc
// EPI 3: bf16 C = silu'(acc + aux1[col]) * aux2[col];  H[ix] = (bf16)acc  (H via aux3, cast)
template<int EPI, int NF>
__global__ __launch_bounds__(512, 1)
void gemm_nc(const bf16* __restrict__ A, const bf16* __restrict__ Bm,
             void* __restrict__ Cp, int Kdim, int lda, int ldb, int ldc,
             long sA, long sB, long sC, float alpha,
             const float* __restrict__ aux1, const float* __restrict__ aux2,
             const bf16* __restrict__ aux3)
{
    constexpr int SB = NF * 4096;
    __shared__ __align__(16) char smem[65536 + 4 * SB];

    const int gx = gridDim.x, gy = gridDim.y;
    int lin = blockIdx.x + gx * (blockIdx.y + gy * blockIdx.z);
    const int q = (gx * gy * gridDim.z) >> 3;
    lin = (lin & 7) * q + (lin >> 3);
    const int bx = lin % gx;
    const int rem0 = lin / gx;
    const int by = rem0 % gy;
    const int bz = rem0 / gy;

    const int t0 = threadIdx.x;
    const int w = t0 >> 6, lane = t0 & 63;
    const int wm = w >> 2, wn = w & 3;
    const int m0 = by * 256, n0 = bx * (64 * NF);
    const long zb = bz;

    const bf16* Ab = A  + zb * sA + (size_t)m0 * lda;
    const bf16* Bb = Bm + zb * sB + (size_t)n0 * ldb;

    const int sr16 = lane >> 2;
    const int sce  = ((((lane & 3) << 4) ^ (((lane >> 5) & 1) << 5))) >> 1;
    const int stg0 = w * 2, stg1 = w * 2 + 1;
    const bf16* pA0 = Ab + (size_t)(stg0 * 16 + sr16) * lda + sce;
    const bf16* pA1 = Ab + (size_t)(stg1 * 16 + sr16) * lda + sce;
    const bf16* pB0 = Bb + (size_t)((NF == 4 ? stg0 : w) * 16 + sr16) * ldb + sce;
    const bf16* pB1 = Bb + (size_t)(stg1 * 16 + sr16) * ldb + sce;

    const int lr = lane & 15, lkq = lane >> 4;
    const int phx = ((lane >> 3) & 1) << 5;
    const int frag_base = lr * 64 + lkq * 16;

    f32x4 acc[8][NF] = {};
    const int NT = Kdim >> 5;

    auto issueSlot = [&](int p) {
        char* lA = smem + (p & 3) * 16384;
        char* lB = smem + 65536 + (p & 3) * SB;
        const int kt = p << 5;
        gload16(pA0 + kt, (bf16*)(lA + stg0 * 1024));
        gload16(pA1 + kt, (bf16*)(lA + stg1 * 1024));
        if (NF == 4) {
            gload16(pB0 + kt, (bf16*)(lB + stg0 * 1024));
            gload16(pB1 + kt, (bf16*)(lB + stg1 * 1024));
        } else {
            gload16(pB0 + kt, (bf16*)(lB + w * 1024));
        }
    };
    auto rdA = [&](const char* base, int sub) {
        return *(const bf16x8*)(base + (((sub << 10) + frag_base) ^ phx));
    };

    issueSlot(0); issueSlot(1); issueSlot(2);
    if (NF == 4) asm volatile("s_waitcnt vmcnt(4)" ::: "memory");
    else         asm volatile("s_waitcnt vmcnt(3)" ::: "memory");
    __builtin_amdgcn_s_barrier();
    MEMFENCE;

    bf16x8 alo[4], ahi[4], b0[NF], b1[NF];
    {
        const char* cA = smem;
        const char* cB = smem + 65536;
        #pragma unroll
        for (int mf = 0; mf < 4; ++mf) alo[mf] = rdA(cA, wm * 8 + mf);
        #pragma unroll
        for (int nf = 0; nf < NF; ++nf) b0[nf] = rdA(cB, wn * NF + nf);
    }

    auto stepBody = [&](int SL, int s, bf16x8 (&bA)[NF], bf16x8 (&bB)[NF]) {
        if (s + 3 < NT) issueSlot(s + 3);
        const char* cA = smem + SL * 16384;
        #pragma unroll
        for (int mf = 0; mf < 4; ++mf) ahi[mf] = rdA(cA, wm * 8 + 4 + mf);

        __builtin_amdgcn_s_setprio(1);
        #pragma unroll
        for (int mf = 0; mf < 4; ++mf)
            #pragma unroll
            for (int nf = 0; nf < NF; ++nf)
                acc[mf][nf] = __builtin_amdgcn_mfma_f32_16x16x32_bf16(alo[mf], bA[nf], acc[mf][nf], 0, 0, 0);
        __builtin_amdgcn_s_setprio(0);

        if (s + 1 < NT) {
            const int NS = (SL + 1) & 3;
            const char* nA = smem + NS * 16384;
            const char* nB = smem + 65536 + NS * SB;
            #pragma unroll
            for (int mf = 0; mf < 4; ++mf) alo[mf] = rdA(nA, wm * 8 + mf);
            #pragma unroll
            for (int nf = 0; nf < NF; ++nf) bB[nf] = rdA(nB, wn * NF + nf);
        }

        __builtin_amdgcn_s_setprio(1);
        #pragma unroll
        for (int mf = 0; mf < 4; ++mf)
            #pragma unroll
            for (int nf = 0; nf < NF; ++nf)
                acc[4 + mf][nf] = __builtin_amdgcn_mfma_f32_16x16x32_bf16(ahi[mf], bA[nf], acc[4 + mf][nf], 0, 0, 0);
        __builtin_amdgcn_s_setprio(0);

        MEMFENCE;
        if (s + 3 < NT) {
            if (NF == 4) asm volatile("s_waitcnt vmcnt(4)" ::: "memory");
            else         asm volatile("s_waitcnt vmcnt(3)" ::: "memory");
        } else {
            asm volatile("s_waitcnt vmcnt(0)" ::: "memory");
        }
        __builtin_amdgcn_s_barrier();
        MEMFENCE;
    };

    for (int s = 0; s < NT; s += 2) {
        stepBody(s & 3, s, b0, b1);
        stepBody((s + 1) & 3, s + 1, b1, b0);
    }

    const int rb  = m0 + wm * 128 + lkq * 4;
    const int cb0 = n0 + wn * (NF * 16) + lr;
    #pragma unroll
    for (int mf = 0; mf < 8; ++mf) {
        #pragma unroll
        for (int nf = 0; nf < NF; ++nf) {
            const int c = cb0 + nf * 16;
            #pragma unroll
            for (int r = 0; r < 4; ++r) {
                const int rw = rb + mf * 16 + r;
                const size_t ix = (size_t)rw * ldc + c;
                const float v = acc[mf][nf][r];
                if (EPI == 0) {
                    ((bf16*)Cp + zb * sC)[ix] = (bf16)(alpha * v);
                } else {   // EPI == 3: U + H
                    const float u = v + aux1[c];
                    const float sg = 1.f / (1.f + __expf(-u));
                    const float dd = sg * (1.f + u * (1.f - sg));
                    ((bf16*)Cp)[ix] = (bf16)(dd * aux2[c]);
                    ((bf16*)aux3)[ix] = (bf16)v;   // H = AO@W1 (pre-bias)
                }
            }
        }
    }
}

// ---------------- fp32 -> bf16 cast (DN) and/or transposed cast (DT) ----------------
template<bool DN, bool DT>
__global__ __launch_bounds__(256)
void transcast_k(const float* __restrict__ in, bf16* __restrict__ outN,
                 bf16* __restrict__ outT, int R, int C)
{
    __shared__ float ts[64][65];
    const int t = threadIdx.x;
    const int c0 = blockIdx.x * 64, r0 = blockIdx.y * 64;
    const size_t zoff = (size_t)blockIdx.z * R * C;

    const int rr = t >> 2, cc = (t & 3) * 16;
    float4 f[4];
    const float* src = in + zoff + (size_t)(r0 + rr) * C + c0 + cc;
    #pragma unroll
    for (int i = 0; i < 4; ++i) f[i] = *(const float4*)(src + 4 * i);

    if (DN) {
        bf16x8 h0, h1;
        #pragma unroll
        for (int i = 0; i < 2; ++i) {
            h0[i*4+0] = (bf16)f[i].x;   h0[i*4+1] = (bf16)f[i].y;
            h0[i*4+2] = (bf16)f[i].z;   h0[i*4+3] = (bf16)f[i].w;
            h1[i*4+0] = (bf16)f[i+2].x; h1[i*4+1] = (bf16)f[i+2].y;
            h1[i*4+2] = (bf16)f[i+2].z; h1[i*4+3] = (bf16)f[i+2].w;
        }
        bf16* dst = outN + zoff + (size_t)(r0 + rr) * C + c0 + cc;
        *(bf16x8*)dst = h0;
        *(bf16x8*)(dst + 8) = h1;
    }
    if (DT) {
        #pragma unroll
        for (int i = 0; i < 4; ++i) {
            ts[rr][cc + 4*i + 0] = f[i].x;
            ts[rr][cc + 4*i + 1] = f[i].y;
            ts[rr][cc + 4*i + 2] = f[i].z;
            ts[rr][cc + 4*i + 3] = f[i].w;
        }
        __syncthreads();
        const int ct = t >> 2, rr4 = (t & 3) * 16;
        bf16x8 o0, o1;
        #pragma unroll
        for (int i = 0; i < 8; ++i) o0[i] = (bf16)ts[rr4 + i][ct];
        #pragma unroll
        for (int i = 0; i < 8; ++i) o1[i] = (bf16)ts[rr4 + 8 + i][ct];
        bf16* dst = outT + zoff + (size_t)(c0 + ct) * R + r0 + rr4;
        *(bf16x8*)dst = o0;
        *(bf16x8*)(dst + 8) = o1;
    }
}

// ---------------- row softmax over 2048-wide rows ----------------
__global__ __launch_bounds__(256)
void softmax_k(const bf16* __restrict__ S, bf16* __restrict__ A)
{
    const size_t row = blockIdx.x;
    const int t = threadIdx.x;
    const int wid = t >> 6, lane = t & 63;
    __shared__ float r1[4], r2[4];

    bf16x8 v = *(const bf16x8*)(S + row * 2048 + t * 8);
    float f[8];
    float mx = -1e30f;
    #pragma unroll
    for (int i = 0; i < 8; ++i) { f[i] = (float)v[i]; mx = fmaxf(mx, f[i]); }
    #pragma unroll
    for (int o = 32; o; o >>= 1) mx = fmaxf(mx, __shfl_xor(mx, o, 64));
    if (!lane) r1[wid] = mx;
    __syncthreads();
    mx = fmaxf(fmaxf(r1[0], r1[1]), fmaxf(r1[2], r1[3]));

    float sum = 0.f;
    #pragma unroll
    for (int i = 0; i < 8; ++i) { f[i] = __expf(f[i] - mx); sum += f[i]; }
    #pragma unroll
    for (int o = 32; o; o >>= 1) sum += __shfl_xor(sum, o, 64);
    if (!lane) r2[wid] = sum;
    __syncthreads();
    sum = r2[0] + r2[1] + r2[2] + r2[3];

    const float inv = 1.f / sum;
    bf16x8 ov;
    #pragma unroll
    for (int i = 0; i < 8; ++i) ov[i] = (bf16)(f[i] * inv);
    *(bf16x8*)(A + row * 2048 + t * 8) = ov;
}

// ---------------- rowdot[r] = dot(U[r,:512], H[r,:512]) — FA-backward delta ----------------
__global__ __launch_bounds__(256)
void rowdot_k(const bf16* __restrict__ U, const bf16* __restrict__ H, float* __restrict__ rd)
{
    const int r = blockIdx.x * 4 + (threadIdx.x >> 6);
    const int lane = threadIdx.x & 63;
    bf16x8 uv = *(const bf16x8*)(U + (size_t)r * 512 + lane * 8);
    bf16x8 hv = *(const bf16x8*)(H + (size_t)r * 512 + lane * 8);
    float d = 0.f;
    #pragma unroll
    for (int i = 0; i < 8; ++i) d += (float)uv[i] * (float)hv[i];
    #pragma unroll
    for (int o = 32; o; o >>= 1) d += __shfl_xor(d, o, 64);
    if (!lane) rd[r] = d;
}

extern "C" void kernel_launch(void* const* d_in, const int* in_sizes, int n_in,
                              void* d_out, int out_size, void* d_ws, size_t ws_size,
                              hipStream_t stream)
{
    const float* Q  = (const float*)d_in[0];
    const float* Km = (const float*)d_in[1];
    const float* V  = (const float*)d_in[2];
    const float* W1 = (const float*)d_in[3];
    const float* b1 = (const float*)d_in[4];
    const float* W2 = (const float*)d_in[5];
    float* out = (float*)d_out;

    // ---- workspace layout (~236 MB, live-range packed) ----
    char* ws = (char*)d_ws;
    bf16* Amat = (bf16*)(ws);                    // R1: A, then dS (in-place)   67.1 MB
    bf16* AO   = (bf16*)(ws + 67108864);         // R2: Kb (pre-GEMM3), then attn_out bf16
    bf16* Kb   = AO;
    bf16* KbT  = (bf16*)(ws + 100663296);        // R3: K^T bf16
    bf16* Vb   = (bf16*)(ws + 134217728);        // R4: V bf16 -> H (after VW1)
    bf16* Hb   = Vb;
    bf16* VbT  = (bf16*)(ws + 167772160);        // R5: V^T bf16 -> U
    bf16* U    = VbT;
    bf16* Qb   = (bf16*)(ws + 201326592);        // R6: Q bf16 -> VW1 [2048][512]/batch
    bf16* VW1b = Qb;
    bf16* W1T  = (bf16*)(ws + 234881024);        // R7: W1^T bf16 [512][1024] (1 MB)
    float* rowdot = (float*)(ws + 235929600);    // R8: rowdot f32 [16384] (64 KB)
    bf16* S    = (bf16*)d_out;                   // S (dead after softmax; d_out reused for out)

    const long sQK = 2048L * 1024;
    const long sS  = 2048L * 2048;
    const long sVW = 2048L * 512;
    dim3 blk(256), blkG(512), blkW(1024);

    // ---- prep: bf16 casts / transposes ----
    transcast_k<true,  false><<<dim3(16, 32, 8), blk, 0, stream>>>(Q,  Qb, nullptr, 2048, 1024);
    transcast_k<true,  true ><<<dim3(16, 32, 8), blk, 0, stream>>>(Km, Kb, KbT,     2048, 1024);
    transcast_k<true,  true ><<<dim3(16, 32, 8), blk, 0, stream>>>(V,  Vb, VbT,     2048, 1024);
    transcast_k<false, true ><<<dim3(8,  16, 1), blk, 0, stream>>>(W1, nullptr, W1T, 1024, 512);

    // 1) S = scale * Qb @ Kb^T
    gemm16<0><<<dim3(8, 8, 8), blkW, 0, stream>>>(
        Qb, Kb, S, 1024, 1024, 1024, 2048, sQK, sQK, sS, 0.03125f, nullptr, nullptr);

    // 1b) VW1 = V @ W1  (B = W1^T; overwrites Qb region — Qb dead after GEMM 1)
    gemm_nc<0, 2><<<dim3(4, 8, 8), blkG, 0, stream>>>(
        Vb, W1T, VW1b, 1024, 1024, 1024, 512, sQK, 0, sVW, 1.0f, nullptr, nullptr, nullptr);

    // 2) A = row-softmax(S)
    softmax_k<<<dim3(16384), blk, 0, stream>>>(S, Amat);

    // 3) attn_out = A @ V   (B = V^T [1024][2048]; overwrites Kb region with AO)
    gemm16<0><<<dim3(4, 8, 8), blkW, 0, stream>>>(
        Amat, VbT, AO, 2048, 2048, 2048, 1024, sS, sQK, sQK, 1.0f, nullptr, nullptr);

    // 4) U = silu'(AO @ W1 + b1) * w2 ; H = AO @ W1   (H into dead Vb region)
    gemm_nc<3, 2><<<dim3(4, 64, 1), blkG, 0, stream>>>(
        AO, W1T, U, 1024, 1024, 1024, 512, 0, 0, 0, 1.0f, b1, W2, Hb);

    // 5) rowdot[n] = dot(U[n], H[n])   (= rowsum(A .* dA), FA-backward identity)
    rowdot_k<<<dim3(4096), blk, 0, stream>>>(U, Hb, rowdot);

    // 6) dS = A .* (U @ VW1^T - rowdot)  — K=512 GEMM, epilogue-fused, in-place into Amat
    gemm16<1><<<dim3(8, 8, 8), blkW, 0, stream>>>(
        U, VW1b, Amat, 512, 512, 512, 2048, sVW, sVW, sS, 1.0f, rowdot, Amat);

    // 7) out = V + attn_out - (eps*scale) * dS @ K   (B = K^T [1024][2048])
    gemm16<2><<<dim3(4, 8, 8), blkW, 0, stream>>>(
        Amat, KbT, out, 2048, 2048, 2048, 1024, sS, sQK, sQK, 0.03f * 0.03125f, V, AO);
}

// Round 9
// 405.557 us; speedup vs baseline: 1.2117x; 1.0809x over previous
//
#include <hip/hip_runtime.h>

typedef __bf16 bf16;
typedef __attribute__((ext_vector_type(8))) __bf16 bf16x8;
typedef __attribute__((ext_vector_type(4))) float f32x4;

#define MEMFENCE asm volatile("" ::: "memory")

// async global->LDS, 16B per lane; LDS dest = wave-uniform base + lane*16
__device__ __forceinline__ void gload16(const bf16* g, bf16* l) {
    __builtin_amdgcn_global_load_lds(
        (const __attribute__((address_space(1))) void*)g,
        (__attribute__((address_space(3))) void*)l,
        16, 0, 0);
}

// ============ 256x256 8-wave bf16 NT GEMM, BK=64, 4-seg cross-fed pipeline (R3-verified) ============
// Per-block law (R0-R7): tile time ≈ 2085 cyc fixed + staged-bytes/14.2 B/cyc, invariant to
// intra-block scheduling -> engine kept byte-identical to the 420us R3 kernel.
// EPI 0: bf16 C = alpha*acc
// EPI 1: bf16 C[ix] = aux3[ix] * (acc - SUM4(aux1 slabs)[row])  (dS = A*(dA-rowdot))
// EPI 2: f32  C = aux1[ix] + (float)aux3[ix] - alpha*acc        (out = V + AO - eps*scale*dQacc)
template<int EPI>
__global__ __launch_bounds__(512, 1)
void gemm8p(const bf16* __restrict__ A, const bf16* __restrict__ Bm,
            void* __restrict__ Cp, int Kdim, int lda, int ldb, int ldc,
            long sA, long sB, long sC, float alpha,
            const float* __restrict__ aux1, const bf16* __restrict__ aux3)
{
    __shared__ __align__(16) char smem[163840];

    // XCD-aware bijective swizzle (ntot % 8 == 0 for all launches)
    const int gx = gridDim.x, gy = gridDim.y;
    int lin = blockIdx.x + gx * (blockIdx.y + gy * blockIdx.z);
    const int q = (gx * gy * gridDim.z) >> 3;
    lin = (lin & 7) * q + (lin >> 3);
    const int bx = lin % gx;
    const int rem0 = lin / gx;
    const int by = rem0 % gy;
    const int bz = rem0 / gy;

    const int t0 = threadIdx.x;
    const int w = t0 >> 6, lane = t0 & 63;
    const int wm = w >> 2, wn = w & 3;          // 2 x 4 wave grid; per-wave C = 128 x 64
    const int m0 = by * 256, n0 = bx * 256;
    const long zb = bz;

    const bf16* Ab = A  + zb * sA + (size_t)m0 * lda;
    const bf16* Bb = Bm + zb * sB + (size_t)n0 * ldb;

    // staging lane coords: wave w stages subtiles {w, 8+w} of a 128-row half-tile
    const int sr16 = lane >> 2;
    const int sce  = ((((lane & 3) << 4) ^ (((lane >> 5) & 1) << 5))) >> 1; // inv-swizzled col
    const int r0s = (w >> 1) * 16 + sr16;
    const int c0s = (w & 1) * 32 + sce;
    const bf16* gA0 = Ab + (size_t)r0s * lda + c0s;
    const bf16* gA1 = Ab + (size_t)(128 + r0s) * lda + c0s;
    const bf16* gB0 = Bb + (size_t)r0s * ldb + c0s;
    const bf16* gB1 = Bb + (size_t)(128 + r0s) * ldb + c0s;
    const size_t a64 = (size_t)64 * lda, b64 = (size_t)64 * ldb;
    const int ldsW0 = w * 1024, ldsW1 = (8 + w) * 1024;

    // fragment-read bases (16x16x32 layout)
    const int lr = lane & 15, lkq = lane >> 4;
    const int phx = ((lane >> 3) & 1) << 5;
    const int frag_base = (lr * 64 + lkq * 16) ^ phx;
    const char* aR = smem + wm * 16384 + frag_base;
    const char* bR = smem + 98304 + (wn >> 1) * 16384 + (wn & 1) * 8192 + frag_base;

    f32x4 acc[8][4] = {};
    const int NTt = Kdim >> 6;

    auto stgA = [&](int h, int u, int off) {
        char* L = smem + off + h * 16384;
        const bf16* g = h ? gA1 : gA0;
        gload16(g + (size_t)u * 64,        (bf16*)(L + ldsW0));
        gload16(g + a64 + (size_t)u * 64,  (bf16*)(L + ldsW1));
    };
    auto stgB = [&](int h, int u, int p) {
        char* L = smem + 98304 + p * 32768 + h * 16384;
        const bf16* g = h ? gB1 : gB0;
        gload16(g + (size_t)u * 64,        (bf16*)(L + ldsW0));
        gload16(g + b64 + (size_t)u * 64,  (bf16*)(L + ldsW1));
    };

    stgA(0, 0, 0);     stgA(1, 0, 0);     stgB(0, 0, 0); stgB(1, 0, 0);
    stgA(0, 1, 32768); stgA(1, 1, 32768); stgB(0, 1, 1); stgB(1, 1, 1);
    asm volatile("s_waitcnt vmcnt(8)" ::: "memory");
    __builtin_amdgcn_s_barrier();
    MEMFENCE;

    bf16x8 a[4][2], bl[2][2], bh[2][2];
    #pragma unroll
    for (int mf = 0; mf < 4; ++mf)
        #pragma unroll
        for (int ks = 0; ks < 2; ++ks)
            a[mf][ks] = *(const bf16x8*)(aR + (mf * 2 + ks) * 1024);
    #pragma unroll
    for (int nf = 0; nf < 2; ++nf)
        #pragma unroll
        for (int ks = 0; ks < 2; ++ks)
            bh[nf][ks] = *(const bf16x8*)(bR + ((2 + nf) * 2 + ks) * 1024);

#define QUADQ(MFB, NFB, AARR, BARR)                                                     \
    __builtin_amdgcn_s_setprio(1);                                                      \
    _Pragma("unroll")                                                                   \
    for (int ks = 0; ks < 2; ++ks)                                                      \
        _Pragma("unroll")                                                               \
        for (int mf = 0; mf < 4; ++mf)                                                  \
            _Pragma("unroll")                                                           \
            for (int nf = 0; nf < 2; ++nf)                                              \
                acc[(MFB) + mf][(NFB) + nf] = __builtin_amdgcn_mfma_f32_16x16x32_bf16(  \
                    AARR[mf][ks], BARR[nf][ks], acc[(MFB) + mf][(NFB) + nf], 0, 0, 0);  \
    __builtin_amdgcn_s_setprio(0);

    int aOff = 0, aOff1 = 32768, sOff = 65536;
    for (int u = 0; u < NTt; ++u) {
        const int p = u & 1;
        const char* aP  = aR + aOff;
        const char* aP1 = aR + aOff1;
        const char* bP  = bR + p * 32768;
        const char* bP1 = bR + (p ^ 1) * 32768;
        const bool st2 = (u + 2 < NTt), nx = (u + 1 < NTt);

        if (st2) stgA(0, u + 2, sOff);
        #pragma unroll
        for (int nf = 0; nf < 2; ++nf)
            #pragma unroll
            for (int ks = 0; ks < 2; ++ks)
                bl[nf][ks] = *(const bf16x8*)(bP + (nf * 2 + ks) * 1024);
        QUADQ(0, 2, a, bh)

        if (st2) stgA(1, u + 2, sOff);
        QUADQ(0, 0, a, bl)
        #pragma unroll
        for (int mf = 0; mf < 4; ++mf)
            #pragma unroll
            for (int ks = 0; ks < 2; ++ks)
                a[mf][ks] = *(const bf16x8*)(aP + ((4 + mf) * 2 + ks) * 1024);
        MEMFENCE;
        if (st2)     asm volatile("s_waitcnt vmcnt(4)" ::: "memory");
        else if (nx) asm volatile("s_waitcnt vmcnt(0)" ::: "memory");
        __builtin_amdgcn_s_barrier();
        MEMFENCE;

        if (st2) stgB(0, u + 2, p);
        QUADQ(4, 0, a, bl)

        if (st2) stgB(1, u + 2, p);
        QUADQ(4, 2, a, bh)
        if (nx) {
            #pragma unroll
            for (int mf = 0; mf < 4; ++mf)
                #pragma unroll
                for (int ks = 0; ks < 2; ++ks)
                    a[mf][ks] = *(const bf16x8*)(aP1 + (mf * 2 + ks) * 1024);
            #pragma unroll
            for (int nf = 0; nf < 2; ++nf)
                #pragma unroll
                for (int ks = 0; ks < 2; ++ks)
                    bh[nf][ks] = *(const bf16x8*)(bP1 + ((2 + nf) * 2 + ks) * 1024);
        }
        MEMFENCE;
        __builtin_amdgcn_s_barrier();
        MEMFENCE;

        const int tmp = aOff; aOff = aOff1; aOff1 = sOff; sOff = tmp;
    }
#undef QUADQ

    // ---- epilogue: D layout col=lane&15, row=(lane>>4)*4+reg ----
    const int rb  = m0 + wm * 128 + lkq * 4;
    const int cb0 = n0 + wn * 64 + lr;
    #pragma unroll
    for (int mf = 0; mf < 8; ++mf) {
        #pragma unroll
        for (int r = 0; r < 4; ++r) {
            const int rw = rb + mf * 16 + r;
            float rd = 0.f;
            if (EPI == 1) {
                const size_t gr = zb * 2048 + rw;   // 4 per-block-column slabs from GEMM4
                rd = aux1[gr] + aux1[16384 + gr] + aux1[32768 + gr] + aux1[49152 + gr];
            }
            #pragma unroll
            for (int nf = 0; nf < 4; ++nf) {
                const int c = cb0 + nf * 16;
                const size_t ix = (size_t)rw * ldc + c;
                const float v = acc[mf][nf][r];
                if (EPI == 0) {
                    ((bf16*)Cp + zb * sC)[ix] = (bf16)(alpha * v);
                } else if (EPI == 1) {
                    bf16* Cb = (bf16*)Cp + zb * sC;
                    const bf16* Am = aux3 + zb * sC;
                    Cb[ix] = (bf16)((float)Am[ix] * (v - rd));
                } else {
                    float* C = (float*)Cp + zb * sC;
                    const float* Vv = aux1 + zb * sC;
                    const bf16* AOv = aux3 + zb * sC;
                    C[ix] = Vv[ix] + (float)AOv[ix] - alpha * v;
                }
            }
        }
    }
}

// ===== 256 x (64*NF) quad-slot BK=32 cross-step (R3-verified engine) =====
// EPI 0: bf16 C = alpha*acc
// EPI 3: bf16 C = silu'(acc + aux1[col]) * aux2[col];  rowdot partial slab -> rds (H eliminated)
template<int EPI, int NF>
__global__ __launch_bounds__(512, 1)
void gemm_nc(const bf16* __restrict__ A, const bf16* __restrict__ Bm,
             void* __restrict__ Cp, int Kdim, int lda, int ldb, int ldc,
             long sA, long sB, long sC, float alpha,
             const float* __restrict__ aux1, const float* __restrict__ aux2,
             float* __restrict__ rds)
{
    constexpr int SB = NF * 4096;
    __shared__ __align__(16) char smem[65536 + 4 * SB];

    const int gx = gridDim.x, gy = gridDim.y;
    int lin = blockIdx.x + gx * (blockIdx.y + gy * blockIdx.z);
    const int q = (gx * gy * gridDim.z) >> 3;
    lin = (lin & 7) * q + (lin >> 3);
    const int bx = lin % gx;
    const int rem0 = lin / gx;
    const int by = rem0 % gy;
    const int bz = rem0 / gy;

    const int t0 = threadIdx.x;
    const int w = t0 >> 6, lane = t0 & 63;
    const int wm = w >> 2, wn = w & 3;
    const int m0 = by * 256, n0 = bx * (64 * NF);
    const long zb = bz;

    const bf16* Ab = A  + zb * sA + (size_t)m0 * lda;
    const bf16* Bb = Bm + zb * sB + (size_t)n0 * ldb;

    const int sr16 = lane >> 2;
    const int sce  = ((((lane & 3) << 4) ^ (((lane >> 5) & 1) << 5))) >> 1;
    const int stg0 = w * 2, stg1 = w * 2 + 1;
    const bf16* pA0 = Ab + (size_t)(stg0 * 16 + sr16) * lda + sce;
    const bf16* pA1 = Ab + (size_t)(stg1 * 16 + sr16) * lda + sce;
    const bf16* pB0 = Bb + (size_t)((NF == 4 ? stg0 : w) * 16 + sr16) * ldb + sce;
    const bf16* pB1 = Bb + (size_t)(stg1 * 16 + sr16) * ldb + sce;

    const int lr = lane & 15, lkq = lane >> 4;
    const int phx = ((lane >> 3) & 1) << 5;
    const int frag_base = lr * 64 + lkq * 16;

    f32x4 acc[8][NF] = {};
    const int NT = Kdim >> 5;

    auto issueSlot = [&](int p) {
        char* lA = smem + (p & 3) * 16384;
        char* lB = smem + 65536 + (p & 3) * SB;
        const int kt = p << 5;
        gload16(pA0 + kt, (bf16*)(lA + stg0 * 1024));
        gload16(pA1 + kt, (bf16*)(lA + stg1 * 1024));
        if (NF == 4) {
            gload16(pB0 + kt, (bf16*)(lB + stg0 * 1024));
            gload16(pB1 + kt, (bf16*)(lB + stg1 * 1024));
        } else {
            gload16(pB0 + kt, (bf16*)(lB + w * 1024));
        }
    };
    auto rdA = [&](const char* base, int sub) {
        return *(const bf16x8*)(base + (((sub << 10) + frag_base) ^ phx));
    };

    issueSlot(0); issueSlot(1); issueSlot(2);
    if (NF == 4) asm volatile("s_waitcnt vmcnt(4)" ::: "memory");
    else         asm volatile("s_waitcnt vmcnt(3)" ::: "memory");
    __builtin_amdgcn_s_barrier();
    MEMFENCE;

    bf16x8 alo[4], ahi[4], b0[NF], b1[NF];
    {
        const char* cA = smem;
        const char* cB = smem + 65536;
        #pragma unroll
        for (int mf = 0; mf < 4; ++mf) alo[mf] = rdA(cA, wm * 8 + mf);
        #pragma unroll
        for (int nf = 0; nf < NF; ++nf) b0[nf] = rdA(cB, wn * NF + nf);
    }

    auto stepBody = [&](int SL, int s, bf16x8 (&bA)[NF], bf16x8 (&bB)[NF]) {
        if (s + 3 < NT) issueSlot(s + 3);
        const char* cA = smem + SL * 16384;
        #pragma unroll
        for (int mf = 0; mf < 4; ++mf) ahi[mf] = rdA(cA, wm * 8 + 4 + mf);

        __builtin_amdgcn_s_setprio(1);
        #pragma unroll
        for (int mf = 0; mf < 4; ++mf)
            #pragma unroll
            for (int nf = 0; nf < NF; ++nf)
                acc[mf][nf] = __builtin_amdgcn_mfma_f32_16x16x32_bf16(alo[mf], bA[nf], acc[mf][nf], 0, 0, 0);
        __builtin_amdgcn_s_setprio(0);

        if (s + 1 < NT) {
            const int NS = (SL + 1) & 3;
            const char* nA = smem + NS * 16384;
            const char* nB = smem + 65536 + NS * SB;
            #pragma unroll
            for (int mf = 0; mf < 4; ++mf) alo[mf] = rdA(nA, wm * 8 + mf);
            #pragma unroll
            for (int nf = 0; nf < NF; ++nf) bB[nf] = rdA(nB, wn * NF + nf);
        }

        __builtin_amdgcn_s_setprio(1);
        #pragma unroll
        for (int mf = 0; mf < 4; ++mf)
            #pragma unroll
            for (int nf = 0; nf < NF; ++nf)
                acc[4 + mf][nf] = __builtin_amdgcn_mfma_f32_16x16x32_bf16(ahi[mf], bA[nf], acc[4 + mf][nf], 0, 0, 0);
        __builtin_amdgcn_s_setprio(0);

        MEMFENCE;
        if (s + 3 < NT) {
            if (NF == 4) asm volatile("s_waitcnt vmcnt(4)" ::: "memory");
            else         asm volatile("s_waitcnt vmcnt(3)" ::: "memory");
        } else {
            asm volatile("s_waitcnt vmcnt(0)" ::: "memory");
        }
        __builtin_amdgcn_s_barrier();
        MEMFENCE;
    };

    for (int s = 0; s < NT; s += 2) {
        stepBody(s & 3, s, b0, b1);
        stepBody((s + 1) & 3, s + 1, b1, b0);
    }

    const int rb  = m0 + wm * 128 + lkq * 4;
    const int cb0 = n0 + wn * (NF * 16) + lr;

    if (EPI == 0) {
        #pragma unroll
        for (int mf = 0; mf < 8; ++mf)
            #pragma unroll
            for (int nf = 0; nf < NF; ++nf) {
                const int c = cb0 + nf * 16;
                #pragma unroll
                for (int r = 0; r < 4; ++r) {
                    const int rw = rb + mf * 16 + r;
                    ((bf16*)Cp + zb * sC)[(size_t)rw * ldc + c] = (bf16)(alpha * acc[mf][nf][r]);
                }
            }
    } else {
        // EPI 3: U store + in-register rowdot partial (replaces H materialization + rowdot_k).
        // All waves are past the engine's final barrier -> LDS reuse for reduction is safe.
        float* smemF = (float*)smem;
        #pragma unroll
        for (int mf = 0; mf < 8; ++mf) {
            #pragma unroll
            for (int r = 0; r < 4; ++r) {
                const int rw = rb + mf * 16 + r;
                float pd = 0.f;
                #pragma unroll
                for (int nf = 0; nf < NF; ++nf) {
                    const int c = cb0 + nf * 16;
                    const float v = acc[mf][nf][r];
                    const float u = v + aux1[c];
                    const float sg = 1.f / (1.f + __expf(-u));
                    const float dd = sg * (1.f + u * (1.f - sg));
                    const float uval = dd * aux2[c];
                    ((bf16*)Cp)[(size_t)rw * ldc + c] = (bf16)uval;
                    pd += uval * v;                      // U[r,c] * H[r,c] (H = pre-bias acc)
                }
                #pragma unroll
                for (int o = 1; o < 16; o <<= 1) pd += __shfl_xor(pd, o, 64);
                if (lr == 0)
                    smemF[wn * 256 + wm * 128 + mf * 16 + lkq * 4 + r] = pd;
            }
        }
        __syncthreads();
        if (t0 < 256) {
            const float s4 = smemF[t0] + smemF[256 + t0] + smemF[512 + t0] + smemF[768 + t0];
            rds[(size_t)bx * 16384 + m0 + t0] = s4;   // slab per block-column bx
        }
    }
}

// ---------------- fp32 -> bf16 cast (DN) and/or transposed cast (DT) body ----------------
template<bool DN, bool DT>
__device__ __forceinline__ void transcast_body(
                 const float* __restrict__ in, bf16* __restrict__ outN,
                 bf16* __restrict__ outT, int R, int C, int bx, int by, int bz,
                 float (*ts)[65])
{
    const int t = threadIdx.x;
    const int c0 = bx * 64, r0 = by * 64;
    const size_t zoff = (size_t)bz * R * C;

    const int rr = t >> 2, cc = (t & 3) * 16;
    float4 f[4];
    const float* src = in + zoff + (size_t)(r0 + rr) * C + c0 + cc;
    #pragma unroll
    for (int i = 0; i < 4; ++i) f[i] = *(const float4*)(src + 4 * i);

    if (DN) {
        bf16x8 h0, h1;
        #pragma unroll
        for (int i = 0; i < 2; ++i) {
            h0[i*4+0] = (bf16)f[i].x;   h0[i*4+1] = (bf16)f[i].y;
            h0[i*4+2] = (bf16)f[i].z;   h0[i*4+3] = (bf16)f[i].w;
            h1[i*4+0] = (bf16)f[i+2].x; h1[i*4+1] = (bf16)f[i+2].y;
            h1[i*4+2] = (bf16)f[i+2].z; h1[i*4+3] = (bf16)f[i+2].w;
        }
        bf16* dst = outN + zoff + (size_t)(r0 + rr) * C + c0 + cc;
        *(bf16x8*)dst = h0;
        *(bf16x8*)(dst + 8) = h1;
    }
    if (DT) {
        #pragma unroll
        for (int i = 0; i < 4; ++i) {
            ts[rr][cc + 4*i + 0] = f[i].x;
            ts[rr][cc + 4*i + 1] = f[i].y;
            ts[rr][cc + 4*i + 2] = f[i].z;
            ts[rr][cc + 4*i + 3] = f[i].w;
        }
        __syncthreads();
        const int ct = t >> 2, rr4 = (t & 3) * 16;
        bf16x8 o0, o1;
        #pragma unroll
        for (int i = 0; i < 8; ++i) o0[i] = (bf16)ts[rr4 + i][ct];
        #pragma unroll
        for (int i = 0; i < 8; ++i) o1[i] = (bf16)ts[rr4 + 8 + i][ct];
        bf16* dst = outT + zoff + (size_t)(c0 + ct) * R + r0 + rr4;
        *(bf16x8*)dst = o0;
        *(bf16x8*)(dst + 8) = o1;
    }
}

// one launch for all input casts: z 0-7 Q, 8-15 K(+T), 16-23 V(+T), 24 W1^T
__global__ __launch_bounds__(256)
void trans_all(const float* __restrict__ Q, const float* __restrict__ Km,
               const float* __restrict__ V, const float* __restrict__ W1,
               bf16* __restrict__ Qb, bf16* __restrict__ Kb, bf16* __restrict__ KbT,
               bf16* __restrict__ Vb, bf16* __restrict__ VbT, bf16* __restrict__ W1T)
{
    __shared__ float ts[64][65];
    const int z = blockIdx.z;
    if (z < 8) {
        transcast_body<true, false>(Q, Qb, nullptr, 2048, 1024, blockIdx.x, blockIdx.y, z, ts);
    } else if (z < 16) {
        transcast_body<true, true>(Km, Kb, KbT, 2048, 1024, blockIdx.x, blockIdx.y, z - 8, ts);
    } else if (z < 24) {
        transcast_body<true, true>(V, Vb, VbT, 2048, 1024, blockIdx.x, blockIdx.y, z - 16, ts);
    } else {
        if (blockIdx.x < 8 && blockIdx.y < 16)
            transcast_body<false, true>(W1, nullptr, W1T, 1024, 512, blockIdx.x, blockIdx.y, 0, ts);
    }
}

// ---------------- row softmax over 2048-wide rows ----------------
__global__ __launch_bounds__(256)
void softmax_k(const bf16* __restrict__ S, bf16* __restrict__ A)
{
    const size_t row = blockIdx.x;
    const int t = threadIdx.x;
    const int wid = t >> 6, lane = t & 63;
    __shared__ float r1[4], r2[4];

    bf16x8 v = *(const bf16x8*)(S + row * 2048 + t * 8);
    float f[8];
    float mx = -1e30f;
    #pragma unroll
    for (int i = 0; i < 8; ++i) { f[i] = (float)v[i]; mx = fmaxf(mx, f[i]); }
    #pragma unroll
    for (int o = 32; o; o >>= 1) mx = fmaxf(mx, __shfl_xor(mx, o, 64));
    if (!lane) r1[wid] = mx;
    __syncthreads();
    mx = fmaxf(fmaxf(r1[0], r1[1]), fmaxf(r1[2], r1[3]));

    float sum = 0.f;
    #pragma unroll
    for (int i = 0; i < 8; ++i) { f[i] = __expf(f[i] - mx); sum += f[i]; }
    #pragma unroll
    for (int o = 32; o; o >>= 1) sum += __shfl_xor(sum, o, 64);
    if (!lane) r2[wid] = sum;
    __syncthreads();
    sum = r2[0] + r2[1] + r2[2] + r2[3];

    const float inv = 1.f / sum;
    bf16x8 ov;
    #pragma unroll
    for (int i = 0; i < 8; ++i) ov[i] = (bf16)(f[i] * inv);
    *(bf16x8*)(A + row * 2048 + t * 8) = ov;
}

extern "C" void kernel_launch(void* const* d_in, const int* in_sizes, int n_in,
                              void* d_out, int out_size, void* d_ws, size_t ws_size,
                              hipStream_t stream)
{
    const float* Q  = (const float*)d_in[0];
    const float* Km = (const float*)d_in[1];
    const float* V  = (const float*)d_in[2];
    const float* W1 = (const float*)d_in[3];
    const float* b1 = (const float*)d_in[4];
    const float* W2 = (const float*)d_in[5];
    float* out = (float*)d_out;

    // ---- workspace layout (~236 MB, live-range packed; all launches sequential) ----
    char* ws = (char*)d_ws;
    bf16* Amat = (bf16*)(ws);                    // R1: A, then dS (in-place)   67.1 MB
    bf16* AO   = (bf16*)(ws + 67108864);         // R2: Kb (pre-GEMM3), then attn_out bf16
    bf16* Kb   = AO;
    bf16* KbT  = (bf16*)(ws + 100663296);        // R3: K^T bf16
    bf16* Vb   = (bf16*)(ws + 134217728);        // R4: V bf16 (dead after VW1) -> rowdot slabs
    float* rdSlab = (float*)(ws + 134217728);    //     [4][16384] f32 (256 KB)
    bf16* VbT  = (bf16*)(ws + 167772160);        // R5: V^T bf16 -> U
    bf16* U    = VbT;
    bf16* Qb   = (bf16*)(ws + 201326592);        // R6: Q bf16 (dead after GEMM1) -> VW1
    bf16* VW1b = Qb;
    bf16* W1T  = (bf16*)(ws + 234881024);        // R7: W1^T bf16 [512][1024] (1 MB)
    bf16* S    = (bf16*)d_out;                   // S (dead after softmax; d_out reused for out)

    const long sQK = 2048L * 1024;
    const long sS  = 2048L * 2048;
    const long sVW = 2048L * 512;
    dim3 blk(256), blkG(512);

    // prep: all bf16 casts / transposes in one launch
    trans_all<<<dim3(16, 32, 25), blk, 0, stream>>>(Q, Km, V, W1, Qb, Kb, KbT, Vb, VbT, W1T);

    // 1) S = scale * Qb @ Kb^T
    gemm8p<0><<<dim3(8, 8, 8), blkG, 0, stream>>>(
        Qb, Kb, S, 1024, 1024, 1024, 2048, sQK, sQK, sS, 0.03125f, nullptr, nullptr);

    // 1b) VW1 = V @ W1  (B = W1^T; writes Qb region — Qb dead after GEMM 1, sequential ✓)
    gemm_nc<0, 2><<<dim3(4, 8, 8), blkG, 0, stream>>>(
        Vb, W1T, VW1b, 1024, 1024, 1024, 512, sQK, 0, sVW, 1.0f, nullptr, nullptr, nullptr);

    // 2) A = row-softmax(S)
    softmax_k<<<dim3(16384), blk, 0, stream>>>(S, Amat);

    // 3) attn_out = A @ V   (B = V^T [1024][2048]; overwrites Kb region with AO)
    gemm8p<0><<<dim3(4, 8, 8), blkG, 0, stream>>>(
        Amat, VbT, AO, 2048, 2048, 2048, 1024, sS, sQK, sQK, 1.0f, nullptr, nullptr);

    // 4) U = silu'(AO @ W1 + b1) * w2 ; rowdot partial slabs fused into epilogue (H eliminated)
    gemm_nc<3, 2><<<dim3(4, 64, 1), blkG, 0, stream>>>(
        AO, W1T, U, 1024, 1024, 1024, 512, 0, 0, 0, 1.0f, b1, W2, rdSlab);

    // 6) dS = A .* (U @ VW1^T - rowdot)  — K=512 GEMM, sums 4 rowdot slabs in epilogue
    gemm8p<1><<<dim3(8, 8, 8), blkG, 0, stream>>>(
        U, VW1b, Amat, 512, 512, 512, 2048, sVW, sVW, sS, 1.0f, rdSlab, Amat);

    // 7) out = V + attn_out - (eps*scale) * dS @ K   (B = K^T [1024][2048])
    gemm8p<2><<<dim3(4, 8, 8), blkG, 0, stream>>>(
        Amat, KbT, out, 2048, 2048, 2048, 1024, sS, sQK, sQK, 0.03f * 0.03125f, V, AO);
}

// Round 10
// 402.503 us; speedup vs baseline: 1.2209x; 1.0076x over previous
//
#include <hip/hip_runtime.h>

typedef __bf16 bf16;
typedef long i64;
typedef __attribute__((ext_vector_type(8))) __bf16 bf16x8;
typedef __attribute__((ext_vector_type(4))) float f32x4;
typedef __attribute__((ext_vector_type(4))) int i32x4;

#define MEMFENCE asm volatile("" ::: "memory")

__device__ __forceinline__ unsigned char tofp8(float x) {
    return (unsigned char)(__builtin_amdgcn_cvt_pk_fp8_f32(x, x, 0, false) & 0xff);
}

// async global->LDS, 16B per lane; LDS dest = wave-uniform base + lane*16
__device__ __forceinline__ void gload16(const void* g, void* l) {
    __builtin_amdgcn_global_load_lds(
        (const __attribute__((address_space(1))) void*)g,
        (__attribute__((address_space(3))) void*)l,
        16, 0, 0);
}

// ============ 256x256 8-wave NT GEMM, BK=64B-rows, 4-seg cross-fed pipeline ============
// R3-verified engine.  F8=0: bf16, K-tile=64 elems.  F8=1: fp8 e4m3, K-tile=128 elems —
// staging is BYTE-IDENTICAL (same gload16 addresses/LDS layout); only NTt, fragment reads
// (2x b64 per former b128, chunk-XOR swizzled for <=4-way banks) and MFMA opcode change.
// Per-block law (R0-R7): tile time ~ 2085 cyc + 64KB/14.2 B/cyc regardless of schedule ->
// fp8 halves K-tile count at constant per-tile cost.
// EPI 0: bf16 C = alpha*acc
// EPI 1 (F8): fp8 C[ix] = fp8( 64 * aux3[ix] * (acc*alpha - SUM4(aux1 slabs)[row]) )
//             (dS8 = 64*A*(dA-rowdot); alpha=1/16 unscales U8; in: U8=16U, VW18)
// EPI 2: f32  C = aux1[ix] + (float)aux3[ix] - alpha*acc        (out = V + AO - eps*scale/64 * dS8@K8)
template<int EPI, int F8>
__global__ __launch_bounds__(512, 1)
void gemm8p(const void* __restrict__ A, const void* __restrict__ Bm,
            void* __restrict__ Cp, int Kdim, int lda, int ldb, int ldc,
            long sA, long sB, long sC, float alpha,
            const float* __restrict__ aux1, const bf16* __restrict__ aux3)
{
    constexpr int ES = F8 ? 1 : 2;   // element size bytes
    __shared__ __align__(16) char smem[163840];

    // XCD-aware bijective swizzle (ntot % 8 == 0 for all launches)
    const int gx = gridDim.x, gy = gridDim.y;
    int lin = blockIdx.x + gx * (blockIdx.y + gy * blockIdx.z);
    const int q = (gx * gy * gridDim.z) >> 3;
    lin = (lin & 7) * q + (lin >> 3);
    const int bx = lin % gx;
    const int rem0 = lin / gx;
    const int by = rem0 % gy;
    const int bz = rem0 / gy;

    const int t0 = threadIdx.x;
    const int w = t0 >> 6, lane = t0 & 63;
    const int wm = w >> 2, wn = w & 3;          // 2 x 4 wave grid; per-wave C = 128 x 64
    const int m0 = by * 256, n0 = bx * 256;
    const long zb = bz;

    const char* Ab = (const char*)A + ((size_t)zb * sA + (size_t)m0 * lda) * ES;
    const char* Bb = (const char*)Bm + ((size_t)zb * sB + (size_t)n0 * ldb) * ES;

    // staging lane coords: wave w stages subtiles {w, 8+w} of a 128-row half-tile.
    // source col-byte within the 64-B k-row, inverse-swizzled:
    //  bf16: 16B-chunk XOR 32B on rows>=8 (st_16x32)
    //  fp8:  chunk ^ (row&3) ^ ((row>=8)<<1)  -> read-side 4-way-max banks
    const int sr16 = lane >> 2;
    const int sceB = F8 ? ((((lane & 3) ^ (sr16 & 3) ^ (((lane >> 5) & 1) << 1)) << 4))
                        : ((((lane & 3) << 4) ^ (((lane >> 5) & 1) << 5)));
    const int r0s = (w >> 1) * 16 + sr16;
    const int c0sB = (w & 1) * 64 + sceB;
    const char* gA0 = Ab + (size_t)r0s * lda * ES + c0sB;
    const char* gA1 = Ab + (size_t)(128 + r0s) * lda * ES + c0sB;
    const char* gB0 = Bb + (size_t)r0s * ldb * ES + c0sB;
    const char* gB1 = Bb + (size_t)(128 + r0s) * ldb * ES + c0sB;
    const size_t a64 = (size_t)64 * lda * ES, b64 = (size_t)64 * ldb * ES;
    const int ldsW0 = w * 1024, ldsW1 = (8 + w) * 1024;

    // fragment-read bases (16x16x32 layout; 64 B per k-row both modes)
    const int lr = lane & 15, lkq = lane >> 4;
    const int phx = ((lane >> 3) & 1) << 5;
    const int frag_base = F8 ? (lr * 64) : ((lr * 64 + lkq * 16) ^ phx);
    // fp8 b64 read offsets for k-step ks2 in {0,1}: chunk-XOR matching the staging source
    const int e0 = (((0 + (lkq >> 1)) ^ (lr & 3) ^ (((lr >> 3) & 1) << 1)) << 4) + ((lkq & 1) << 3);
    const int e1 = (((2 + (lkq >> 1)) ^ (lr & 3) ^ (((lr >> 3) & 1) << 1)) << 4) + ((lkq & 1) << 3);
    const char* aR = smem + wm * 16384 + frag_base;
    const char* bR = smem + 98304 + (wn >> 1) * 16384 + (wn & 1) * 8192 + frag_base;

    f32x4 acc[8][4] = {};
    const int NTt = Kdim >> (F8 ? 7 : 6);       // K-tiles (always even, >=2)

    auto stgA = [&](int h, int u, int off) {
        char* L = smem + off + h * 16384;
        const char* g = h ? gA1 : gA0;
        gload16(g + (size_t)u * 128,        L + ldsW0);
        gload16(g + a64 + (size_t)u * 128,  L + ldsW1);
    };
    auto stgB = [&](int h, int u, int p) {
        char* L = smem + 98304 + p * 32768 + h * 16384;
        const char* g = h ? gB1 : gB0;
        gload16(g + (size_t)u * 128,        L + ldsW0);
        gload16(g + b64 + (size_t)u * 128,  L + ldsW1);
    };

    // ---- prologue: A(0),B(0),A(1),B(1); vmcnt(8) confirms A(0),B(0); barrier publishes ----
    stgA(0, 0, 0);     stgA(1, 0, 0);     stgB(0, 0, 0); stgB(1, 0, 0);
    stgA(0, 1, 32768); stgA(1, 1, 32768); stgB(0, 1, 1); stgB(1, 1, 1);
    asm volatile("s_waitcnt vmcnt(8)" ::: "memory");
    __builtin_amdgcn_s_barrier();
    MEMFENCE;

    bf16x8 a[4][2], bl[2][2], bh[2][2];
    i64 a8[4][2][2], bl8[2][2][2], bh8[2][2][2];

#define RD8(DST, BASE, SUB)                                                \
    DST[0] = *(const i64*)((BASE) + (SUB) * 1024 + e0);                    \
    DST[1] = *(const i64*)((BASE) + (SUB) * 1024 + e1);

    // pre-read al(0) and bh(0)
    if constexpr (!F8) {
        #pragma unroll
        for (int mf = 0; mf < 4; ++mf)
            #pragma unroll
            for (int ks = 0; ks < 2; ++ks)
                a[mf][ks] = *(const bf16x8*)(aR + (mf * 2 + ks) * 1024);
        #pragma unroll
        for (int nf = 0; nf < 2; ++nf)
            #pragma unroll
            for (int ks = 0; ks < 2; ++ks)
                bh[nf][ks] = *(const bf16x8*)(bR + ((2 + nf) * 2 + ks) * 1024);
    } else {
        #pragma unroll
        for (int mf = 0; mf < 4; ++mf)
            #pragma unroll
            for (int ks = 0; ks < 2; ++ks) { RD8(a8[mf][ks], aR, mf * 2 + ks) }
        #pragma unroll
        for (int nf = 0; nf < 2; ++nf)
            #pragma unroll
            for (int ks = 0; ks < 2; ++ks) { RD8(bh8[nf][ks], bR, (2 + nf) * 2 + ks) }
    }

#define QUADQ(MFB, NFB, AARR, BARR)                                                     \
    __builtin_amdgcn_s_setprio(1);                                                      \
    _Pragma("unroll")                                                                   \
    for (int ks = 0; ks < 2; ++ks)                                                      \
        _Pragma("unroll")                                                               \
        for (int mf = 0; mf < 4; ++mf)                                                  \
            _Pragma("unroll")                                                           \
            for (int nf = 0; nf < 2; ++nf)                                              \
                acc[(MFB) + mf][(NFB) + nf] = __builtin_amdgcn_mfma_f32_16x16x32_bf16(  \
                    AARR[mf][ks], BARR[nf][ks], acc[(MFB) + mf][(NFB) + nf], 0, 0, 0);  \
    __builtin_amdgcn_s_setprio(0);

#define QUAD8(MFB, NFB, AARR, BARR)                                                     \
    __builtin_amdgcn_s_setprio(1);                                                      \
    _Pragma("unroll")                                                                   \
    for (int ks = 0; ks < 2; ++ks)                                                      \
        _Pragma("unroll")                                                               \
        for (int k2 = 0; k2 < 2; ++k2)                                                  \
            _Pragma("unroll")                                                           \
            for (int mf = 0; mf < 4; ++mf)                                              \
                _Pragma("unroll")                                                       \
                for (int nf = 0; nf < 2; ++nf)                                          \
                    acc[(MFB) + mf][(NFB) + nf] =                                       \
                        __builtin_amdgcn_mfma_f32_16x16x32_fp8_fp8(                     \
                            AARR[mf][ks][k2], BARR[nf][ks][k2],                         \
                            acc[(MFB) + mf][(NFB) + nf], 0, 0, 0);                      \
    __builtin_amdgcn_s_setprio(0);

    int aOff = 0, aOff1 = 32768, sOff = 65536;  // A(u), A(u+1), stage A(u+2)
    for (int u = 0; u < NTt; ++u) {
        const int p = u & 1;
        const char* aP  = aR + aOff;
        const char* aP1 = aR + aOff1;
        const char* bP  = bR + p * 32768;
        const char* bP1 = bR + (p ^ 1) * 32768;
        const bool st2 = (u + 2 < NTt), nx = (u + 1 < NTt);

        // ---- seg1: Q(0,2)=al*bh ; read bl(u); stage A0(u+2) ----
        if (st2) stgA(0, u + 2, sOff);
        if constexpr (!F8) {
            #pragma unroll
            for (int nf = 0; nf < 2; ++nf)
                #pragma unroll
                for (int ks = 0; ks < 2; ++ks)
                    bl[nf][ks] = *(const bf16x8*)(bP + (nf * 2 + ks) * 1024);
            QUADQ(0, 2, a, bh)
        } else {
            #pragma unroll
            for (int nf = 0; nf < 2; ++nf)
                #pragma unroll
                for (int ks = 0; ks < 2; ++ks) { RD8(bl8[nf][ks], bP, nf * 2 + ks) }
            QUAD8(0, 2, a8, bh8)
        }

        // ---- seg2: Q(0,0)=al*bl ; a <- ah(u); stage A1(u+2); W1; barrier1 ----
        if (st2) stgA(1, u + 2, sOff);
        if constexpr (!F8) {
            QUADQ(0, 0, a, bl)
            #pragma unroll
            for (int mf = 0; mf < 4; ++mf)
                #pragma unroll
                for (int ks = 0; ks < 2; ++ks)
                    a[mf][ks] = *(const bf16x8*)(aP + ((4 + mf) * 2 + ks) * 1024);
        } else {
            QUAD8(0, 0, a8, bl8)
            #pragma unroll
            for (int mf = 0; mf < 4; ++mf)
                #pragma unroll
                for (int ks = 0; ks < 2; ++ks) { RD8(a8[mf][ks], aP, (4 + mf) * 2 + ks) }
        }
        MEMFENCE;
        if (st2)     asm volatile("s_waitcnt vmcnt(4)" ::: "memory");  // A(u+1)+B(u+1)
        else if (nx) asm volatile("s_waitcnt vmcnt(0)" ::: "memory");  // tail: confirm both
        __builtin_amdgcn_s_barrier();
        MEMFENCE;

        // ---- seg3: Q(4,0)=ah*bl ; stage B0(u+2) ----
        if (st2) stgB(0, u + 2, p);
        if constexpr (!F8) { QUADQ(4, 0, a, bl) } else { QUAD8(4, 0, a8, bl8) }

        // ---- seg4: Q(4,2)=ah*bh ; a <- al(u+1); bh <- bh(u+1); barrier2 ----
        if (st2) stgB(1, u + 2, p);
        if constexpr (!F8) {
            QUADQ(4, 2, a, bh)
            if (nx) {
                #pragma unroll
                for (int mf = 0; mf < 4; ++mf)
                    #pragma unroll
                    for (int ks = 0; ks < 2; ++ks)
                        a[mf][ks] = *(const bf16x8*)(aP1 + (mf * 2 + ks) * 1024);
                #pragma unroll
                for (int nf = 0; nf < 2; ++nf)
                    #pragma unroll
                    for (int ks = 0; ks < 2; ++ks)
                        bh[nf][ks] = *(const bf16x8*)(bP1 + ((2 + nf) * 2 + ks) * 1024);
            }
        } else {
            QUAD8(4, 2, a8, bh8)
            if (nx) {
                #pragma unroll
                for (int mf = 0; mf < 4; ++mf)
                    #pragma unroll
                    for (int ks = 0; ks < 2; ++ks) { RD8(a8[mf][ks], aP1, mf * 2 + ks) }
                #pragma unroll
                for (int nf = 0; nf < 2; ++nf)
                    #pragma unroll
                    for (int ks = 0; ks < 2; ++ks) { RD8(bh8[nf][ks], bP1, (2 + nf) * 2 + ks) }
            }
        }
        MEMFENCE;
        __builtin_amdgcn_s_barrier();
        MEMFENCE;

        const int tmp = aOff; aOff = aOff1; aOff1 = sOff; sOff = tmp;
    }
#undef QUADQ
#undef QUAD8
#undef RD8

    // ---- epilogue: D layout col=lane&15, row=(lane>>4)*4+reg ----
    const int rb  = m0 + wm * 128 + lkq * 4;
    const int cb0 = n0 + wn * 64 + lr;
    #pragma unroll
    for (int mf = 0; mf < 8; ++mf) {
        #pragma unroll
        for (int r = 0; r < 4; ++r) {
            const int rw = rb + mf * 16 + r;
            float rd = 0.f;
            if (EPI == 1) {
                const size_t gr = zb * 2048 + rw;   // 4 per-block-column slabs from GEMM4
                rd = aux1[gr] + aux1[16384 + gr] + aux1[32768 + gr] + aux1[49152 + gr];
            }
            #pragma unroll
            for (int nf = 0; nf < 4; ++nf) {
                const int c = cb0 + nf * 16;
                const size_t ix = (size_t)rw * ldc + c;
                const float v = acc[mf][nf][r];
                if (EPI == 0) {
                    ((bf16*)Cp + zb * sC)[ix] = (bf16)(alpha * v);
                } else if (EPI == 1) {
                    // dS8 = fp8(64 * A * (v/16 - rd));  aux3 = Amat (bf16, same index)
                    const bf16* Am = aux3 + zb * sC;
                    const float t = (float)Am[ix] * (v * alpha - rd) * 64.f;
                    ((unsigned char*)Cp + zb * sC)[ix] = tofp8(t);
                } else {
                    float* C = (float*)Cp + zb * sC;
                    const float* Vv = aux1 + zb * sC;
                    const bf16* AOv = aux3 + zb * sC;
                    C[ix] = Vv[ix] + (float)AOv[ix] - alpha * v;
                }
            }
        }
    }
}

// ===== 256 x (64*NF) quad-slot BK=32 cross-step (R3-verified engine, bf16) =====
// EPI 0: bf16 C = alpha*acc
// EPI 3: bf16->fp8 U8 = fp8(16 * silu'(acc+aux1[col])*aux2[col]); rowdot slab -> rds
// EPI 4: fp8  C = fp8(alpha*acc)                                   (VW18)
template<int EPI, int NF>
__global__ __launch_bounds__(512, 1)
void gemm_nc(const bf16* __restrict__ A, const bf16* __restrict__ Bm,
             void* __restrict__ Cp, int Kdim, int lda, int ldb, int ldc,
             long sA, long sB, long sC, float alpha,
             const float* __restrict__ aux1, const float* __restrict__ aux2,
             float* __restrict__ rds)
{
    constexpr int SB = NF * 4096;
    __shared__ __align__(16) char smem[65536 + 4 * SB];

    const int gx = gridDim.x, gy = gridDim.y;
    int lin = blockIdx.x + gx * (blockIdx.y + gy * blockIdx.z);
    const int q = (gx * gy * gridDim.z) >> 3;
    lin = (lin & 7) * q + (lin >> 3);
    const int bx = lin % gx;
    const int rem0 = lin / gx;
    const int by = rem0 % gy;
    const int bz = rem0 / gy;

    const int t0 = threadIdx.x;
    const int w = t0 >> 6, lane = t0 & 63;
    const int wm = w >> 2, wn = w & 3;
    const int m0 = by * 256, n0 = bx * (64 * NF);
    const long zb = bz;

    const bf16* Ab = A  + zb * sA + (size_t)m0 * lda;
    const bf16* Bb = Bm + zb * sB + (size_t)n0 * ldb;

    const int sr16 = lane >> 2;
    const int sce  = ((((lane & 3) << 4) ^ (((lane >> 5) & 1) << 5))) >> 1;
    const int stg0 = w * 2, stg1 = w * 2 + 1;
    const bf16* pA0 = Ab + (size_t)(stg0 * 16 + sr16) * lda + sce;
    const bf16* pA1 = Ab + (size_t)(stg1 * 16 + sr16) * lda + sce;
    const bf16* pB0 = Bb + (size_t)((NF == 4 ? stg0 : w) * 16 + sr16) * ldb + sce;
    const bf16* pB1 = Bb + (size_t)(stg1 * 16 + sr16) * ldb + sce;

    const int lr = lane & 15, lkq = lane >> 4;
    const int phx = ((lane >> 3) & 1) << 5;
    const int frag_base = lr * 64 + lkq * 16;

    f32x4 acc[8][NF] = {};
    const int NT = Kdim >> 5;

    auto issueSlot = [&](int p) {
        char* lA = smem + (p & 3) * 16384;
        char* lB = smem + 65536 + (p & 3) * SB;
        const int kt = p << 5;
        gload16(pA0 + kt, lA + stg0 * 1024);
        gload16(pA1 + kt, lA + stg1 * 1024);
        if (NF == 4) {
            gload16(pB0 + kt, lB + stg0 * 1024);
            gload16(pB1 + kt, lB + stg1 * 1024);
        } else {
            gload16(pB0 + kt, lB + w * 1024);
        }
    };
    auto rdA = [&](const char* base, int sub) {
        return *(const bf16x8*)(base + (((sub << 10) + frag_base) ^ phx));
    };

    issueSlot(0); issueSlot(1); issueSlot(2);
    if (NF == 4) asm volatile("s_waitcnt vmcnt(4)" ::: "memory");
    else         asm volatile("s_waitcnt vmcnt(3)" ::: "memory");
    __builtin_amdgcn_s_barrier();
    MEMFENCE;

    bf16x8 alo[4], ahi[4], b0[NF], b1[NF];
    {
        const char* cA = smem;
        const char* cB = smem + 65536;
        #pragma unroll
        for (int mf = 0; mf < 4; ++mf) alo[mf] = rdA(cA, wm * 8 + mf);
        #pragma unroll
        for (int nf = 0; nf < NF; ++nf) b0[nf] = rdA(cB, wn * NF + nf);
    }

    auto stepBody = [&](int SL, int s, bf16x8 (&bA)[NF], bf16x8 (&bB)[NF]) {
        if (s + 3 < NT) issueSlot(s + 3);
        const char* cA = smem + SL * 16384;
        #pragma unroll
        for (int mf = 0; mf < 4; ++mf) ahi[mf] = rdA(cA, wm * 8 + 4 + mf);

        __builtin_amdgcn_s_setprio(1);
        #pragma unroll
        for (int mf = 0; mf < 4; ++mf)
            #pragma unroll
            for (int nf = 0; nf < NF; ++nf)
                acc[mf][nf] = __builtin_amdgcn_mfma_f32_16x16x32_bf16(alo[mf], bA[nf], acc[mf][nf], 0, 0, 0);
        __builtin_amdgcn_s_setprio(0);

        if (s + 1 < NT) {
            const int NS = (SL + 1) & 3;
            const char* nA = smem + NS * 16384;
            const char* nB = smem + 65536 + NS * SB;
            #pragma unroll
            for (int mf = 0; mf < 4; ++mf) alo[mf] = rdA(nA, wm * 8 + mf);
            #pragma unroll
            for (int nf = 0; nf < NF; ++nf) bB[nf] = rdA(nB, wn * NF + nf);
        }

        __builtin_amdgcn_s_setprio(1);
        #pragma unroll
        for (int mf = 0; mf < 4; ++mf)
            #pragma unroll
            for (int nf = 0; nf < NF; ++nf)
                acc[4 + mf][nf] = __builtin_amdgcn_mfma_f32_16x16x32_bf16(ahi[mf], bA[nf], acc[4 + mf][nf], 0, 0, 0);
        __builtin_amdgcn_s_setprio(0);

        MEMFENCE;
        if (s + 3 < NT) {
            if (NF == 4) asm volatile("s_waitcnt vmcnt(4)" ::: "memory");
            else         asm volatile("s_waitcnt vmcnt(3)" ::: "memory");
        } else {
            asm volatile("s_waitcnt vmcnt(0)" ::: "memory");
        }
        __builtin_amdgcn_s_barrier();
        MEMFENCE;
    };

    for (int s = 0; s < NT; s += 2) {
        stepBody(s & 3, s, b0, b1);
        stepBody((s + 1) & 3, s + 1, b1, b0);
    }

    const int rb  = m0 + wm * 128 + lkq * 4;
    const int cb0 = n0 + wn * (NF * 16) + lr;

    if (EPI == 0 || EPI == 4) {
        #pragma unroll
        for (int mf = 0; mf < 8; ++mf)
            #pragma unroll
            for (int nf = 0; nf < NF; ++nf) {
                const int c = cb0 + nf * 16;
                #pragma unroll
                for (int r = 0; r < 4; ++r) {
                    const int rw = rb + mf * 16 + r;
                    const size_t ix = (size_t)rw * ldc + c;
                    if (EPI == 0)
                        ((bf16*)Cp + zb * sC)[ix] = (bf16)(alpha * acc[mf][nf][r]);
                    else
                        ((unsigned char*)Cp + zb * sC)[ix] = tofp8(alpha * acc[mf][nf][r]);
                }
            }
    } else {
        // EPI 3: U8 = fp8(16*U) store + in-register rowdot partial (raw units).
        float* smemF = (float*)smem;
        #pragma unroll
        for (int mf = 0; mf < 8; ++mf) {
            #pragma unroll
            for (int r = 0; r < 4; ++r) {
                const int rw = rb + mf * 16 + r;
                float pd = 0.f;
                #pragma unroll
                for (int nf = 0; nf < NF; ++nf) {
                    const int c = cb0 + nf * 16;
                    const float v = acc[mf][nf][r];
                    const float u = v + aux1[c];
                    const float sg = 1.f / (1.f + __expf(-u));
                    const float dd = sg * (1.f + u * (1.f - sg));
                    const float uval = dd * aux2[c];
                    ((unsigned char*)Cp)[(size_t)rw * ldc + c] = tofp8(uval * 16.f);
                    pd += uval * v;                      // U[r,c] * H[r,c] (raw)
                }
                #pragma unroll
                for (int o = 1; o < 16; o <<= 1) pd += __shfl_xor(pd, o, 64);
                if (lr == 0)
                    smemF[wn * 256 + wm * 128 + mf * 16 + lkq * 4 + r] = pd;
            }
        }
        __syncthreads();
        if (t0 < 256) {
            const float s4 = smemF[t0] + smemF[256 + t0] + smemF[512 + t0] + smemF[768 + t0];
            rds[(size_t)bx * 16384 + m0 + t0] = s4;   // slab per block-column bx
        }
    }
}

// ---------------- fp32 -> bf16 cast (DN) and/or transposed cast (TM) body ----------------
// TM: 0 = none, 1 = bf16 transpose, 2 = fp8 transpose
template<bool DN, int TM>
__device__ __forceinline__ void transcast_body(
                 const float* __restrict__ in, bf16* __restrict__ outN,
                 void* __restrict__ outT, int R, int C, int bx, int by, int bz,
                 float (*ts)[65])
{
    const int t = threadIdx.x;
    const int c0 = bx * 64, r0 = by * 64;
    const size_t zoff = (size_t)bz * R * C;

    const int rr = t >> 2, cc = (t & 3) * 16;
    float4 f[4];
    const float* src = in + zoff + (size_t)(r0 + rr) * C + c0 + cc;
    #pragma unroll
    for (int i = 0; i < 4; ++i) f[i] = *(const float4*)(src + 4 * i);

    if (DN) {
        bf16x8 h0, h1;
        #pragma unroll
        for (int i = 0; i < 2; ++i) {
            h0[i*4+0] = (bf16)f[i].x;   h0[i*4+1] = (bf16)f[i].y;
            h0[i*4+2] = (bf16)f[i].z;   h0[i*4+3] = (bf16)f[i].w;
            h1[i*4+0] = (bf16)f[i+2].x; h1[i*4+1] = (bf16)f[i+2].y;
            h1[i*4+2] = (bf16)f[i+2].z; h1[i*4+3] = (bf16)f[i+2].w;
        }
        bf16* dst = outN + zoff + (size_t)(r0 + rr) * C + c0 + cc;
        *(bf16x8*)dst = h0;
        *(bf16x8*)(dst + 8) = h1;
    }
    if (TM) {
        #pragma unroll
        for (int i = 0; i < 4; ++i) {
            ts[rr][cc + 4*i + 0] = f[i].x;
            ts[rr][cc + 4*i + 1] = f[i].y;
            ts[rr][cc + 4*i + 2] = f[i].z;
            ts[rr][cc + 4*i + 3] = f[i].w;
        }
        __syncthreads();
        const int ct = t >> 2, rr4 = (t & 3) * 16;
        if (TM == 1) {
            bf16x8 o0, o1;
            #pragma unroll
            for (int i = 0; i < 8; ++i) o0[i] = (bf16)ts[rr4 + i][ct];
            #pragma unroll
            for (int i = 0; i < 8; ++i) o1[i] = (bf16)ts[rr4 + 8 + i][ct];
            bf16* dst = (bf16*)outT + zoff + (size_t)(c0 + ct) * R + r0 + rr4;
            *(bf16x8*)dst = o0;
            *(bf16x8*)(dst + 8) = o1;
        } else {
            // fp8 transpose: 16 rows -> 16 bytes
            i32x4 o;
            #pragma unroll
            for (int g = 0; g < 4; ++g) {
                int v = __builtin_amdgcn_cvt_pk_fp8_f32(ts[rr4 + 4*g + 0][ct], ts[rr4 + 4*g + 1][ct], 0, false);
                v = __builtin_amdgcn_cvt_pk_fp8_f32(ts[rr4 + 4*g + 2][ct], ts[rr4 + 4*g + 3][ct], v, true);
                o[g] = v;
            }
            unsigned char* dst = (unsigned char*)outT + zoff + (size_t)(c0 + ct) * R + r0 + rr4;
            *(i32x4*)dst = o;
        }
    }
}

// one launch for all input casts: z 0-7 Q, 8-15 K (bf16 N + fp8 T), 16-23 V (bf16 N+T), 24 W1^T
__global__ __launch_bounds__(256)
void trans_all(const float* __restrict__ Q, const float* __restrict__ Km,
               const float* __restrict__ V, const float* __restrict__ W1,
               bf16* __restrict__ Qb, bf16* __restrict__ Kb, unsigned char* __restrict__ KbT8,
               bf16* __restrict__ Vb, bf16* __restrict__ VbT, bf16* __restrict__ W1T)
{
    __shared__ float ts[64][65];
    const int z = blockIdx.z;
    if (z < 8) {
        transcast_body<true, 0>(Q, Qb, nullptr, 2048, 1024, blockIdx.x, blockIdx.y, z, ts);
    } else if (z < 16) {
        transcast_body<true, 2>(Km, Kb, KbT8, 2048, 1024, blockIdx.x, blockIdx.y, z - 8, ts);
    } else if (z < 24) {
        transcast_body<true, 1>(V, Vb, VbT, 2048, 1024, blockIdx.x, blockIdx.y, z - 16, ts);
    } else {
        if (blockIdx.x < 8 && blockIdx.y < 16)
            transcast_body<false, 1>(W1, nullptr, W1T, 1024, 512, blockIdx.x, blockIdx.y, 0, ts);
    }
}

// ---------------- row softmax over 2048-wide rows ----------------
__global__ __launch_bounds__(256)
void softmax_k(const bf16* __restrict__ S, bf16* __restrict__ A)
{
    const size_t row = blockIdx.x;
    const int t = threadIdx.x;
    const int wid = t >> 6, lane = t & 63;
    __shared__ float r1[4], r2[4];

    bf16x8 v = *(const bf16x8*)(S + row * 2048 + t * 8);
    float f[8];
    float mx = -1e30f;
    #pragma unroll
    for (int i = 0; i < 8; ++i) { f[i] = (float)v[i]; mx = fmaxf(mx, f[i]); }
    #pragma unroll
    for (int o = 32; o; o >>= 1) mx = fmaxf(mx, __shfl_xor(mx, o, 64));
    if (!lane) r1[wid] = mx;
    __syncthreads();
    mx = fmaxf(fmaxf(r1[0], r1[1]), fmaxf(r1[2], r1[3]));

    float sum = 0.f;
    #pragma unroll
    for (int i = 0; i < 8; ++i) { f[i] = __expf(f[i] - mx); sum += f[i]; }
    #pragma unroll
    for (int o = 32; o; o >>= 1) sum += __shfl_xor(sum, o, 64);
    if (!lane) r2[wid] = sum;
    __syncthreads();
    sum = r2[0] + r2[1] + r2[2] + r2[3];

    const float inv = 1.f / sum;
    bf16x8 ov;
    #pragma unroll
    for (int i = 0; i < 8; ++i) ov[i] = (bf16)(f[i] * inv);
    *(bf16x8*)(A + row * 2048 + t * 8) = ov;
}

extern "C" void kernel_launch(void* const* d_in, const int* in_sizes, int n_in,
                              void* d_out, int out_size, void* d_ws, size_t ws_size,
                              hipStream_t stream)
{
    const float* Q  = (const float*)d_in[0];
    const float* Km = (const float*)d_in[1];
    const float* V  = (const float*)d_in[2];
    const float* W1 = (const float*)d_in[3];
    const float* b1 = (const float*)d_in[4];
    const float* W2 = (const float*)d_in[5];
    float* out = (float*)d_out;

    // ---- workspace layout (~236 MB, live-range packed; all launches sequential) ----
    char* ws = (char*)d_ws;
    bf16* Amat = (bf16*)(ws);                            // R1: softmax A (bf16, live to G6)
    bf16* AO   = (bf16*)(ws + 67108864);                 // R2: Kb, then attn_out bf16
    bf16* Kb   = AO;
    unsigned char* KbT8 = (unsigned char*)(ws + 100663296);  // R3: K^T fp8 (16.8 MB)
    float* rdSlab = (float*)(ws + 117440512);            // R3 tail: rowdot slabs [4][16384] f32
    bf16* Vb   = (bf16*)(ws + 134217728);                // R4: V bf16 (dead after VW1)
    unsigned char* dS8 = (unsigned char*)(ws + 134217728);   // R4 reuse: dS fp8 (G6->G7)
    bf16* VbT  = (bf16*)(ws + 167772160);                // R5: V^T bf16 (dead after G3)
    unsigned char* U8 = (unsigned char*)(ws + 167772160);    // R5 reuse: U fp8 = 16*U (G4->G6)
    bf16* Qb   = (bf16*)(ws + 201326592);                // R6: Q bf16 (dead after G1)
    unsigned char* VW18 = (unsigned char*)(ws + 201326592);  // R6 reuse: VW1 fp8 (VW1->G6)
    bf16* W1T  = (bf16*)(ws + 234881024);                // R7: W1^T bf16 (1 MB)
    bf16* S    = (bf16*)d_out;                           // S (dead after softmax)

    const long sQK = 2048L * 1024;
    const long sS  = 2048L * 2048;
    const long sVW = 2048L * 512;
    dim3 blk(256), blkG(512);

    // prep: all bf16/fp8 casts / transposes in one launch
    trans_all<<<dim3(16, 32, 25), blk, 0, stream>>>(Q, Km, V, W1, Qb, Kb, KbT8, Vb, VbT, W1T);

    // 1) S = scale * Qb @ Kb^T                               (bf16)
    gemm8p<0, 0><<<dim3(8, 8, 8), blkG, 0, stream>>>(
        Qb, Kb, S, 1024, 1024, 1024, 2048, sQK, sQK, sS, 0.03125f, nullptr, nullptr);

    // 1b) VW18 = fp8(V @ W1)  (writes Qb region — dead after GEMM 1)
    gemm_nc<4, 2><<<dim3(4, 8, 8), blkG, 0, stream>>>(
        Vb, W1T, VW18, 1024, 1024, 1024, 512, sQK, 0, sVW, 1.0f, nullptr, nullptr, nullptr);

    // 2) A = row-softmax(S)
    softmax_k<<<dim3(16384), blk, 0, stream>>>(S, Amat);

    // 3) attn_out = A @ V   (B = V^T; bf16)
    gemm8p<0, 0><<<dim3(4, 8, 8), blkG, 0, stream>>>(
        Amat, VbT, AO, 2048, 2048, 2048, 1024, sS, sQK, sQK, 1.0f, nullptr, nullptr);

    // 4) U8 = fp8(16 * silu'(AO@W1+b1)*w2); rowdot slabs fused (H eliminated)
    gemm_nc<3, 2><<<dim3(4, 64, 1), blkG, 0, stream>>>(
        AO, W1T, U8, 1024, 1024, 1024, 512, 0, 0, 0, 1.0f, b1, W2, rdSlab);

    // 6) dS8 = fp8(64 * A .* (U8@VW18^T / 16 - rowdot))   — fp8 GEMM, K=512
    gemm8p<1, 1><<<dim3(8, 8, 8), blkG, 0, stream>>>(
        U8, VW18, dS8, 512, 512, 512, 2048, 1048576, 1048576, 4194304, 0.0625f, rdSlab, Amat);

    // 7) out = V + attn_out - (eps*scale/64) * dS8 @ K     — fp8 GEMM, K=2048
    gemm8p<2, 1><<<dim3(4, 8, 8), blkG, 0, stream>>>(
        dS8, KbT8, out, 2048, 2048, 2048, 1024, 4194304, 2097152, 2097152,
        0.03f * 0.03125f / 64.f, V, AO);
}

// Round 11
// 382.674 us; speedup vs baseline: 1.2841x; 1.0518x over previous
//
#include <hip/hip_runtime.h>

typedef __bf16 bf16;
typedef long i64;
typedef __attribute__((ext_vector_type(2))) long i64x2;
typedef __attribute__((ext_vector_type(2))) int i32x2;
typedef __attribute__((ext_vector_type(8))) __bf16 bf16x8;
typedef __attribute__((ext_vector_type(4))) float f32x4;
typedef __attribute__((ext_vector_type(4))) int i32x4;

#define MEMFENCE asm volatile("" ::: "memory")

__device__ __forceinline__ unsigned char tofp8(float x) {
    return (unsigned char)(__builtin_amdgcn_cvt_pk_fp8_f32(x, x, 0, false) & 0xff);
}
// k-permutation within 64-blocks: element e=k2*32+lkq*8+b -> byte lkq*16+k2*8+b.
// Makes fp8 fragment reads byte-identical to the verified bf16 b128 pattern.
__device__ __forceinline__ int pcol(int c) {
    return (c & ~63) | (((c >> 3) & 3) << 4) | (((c >> 5) & 1) << 3) | (c & 7);
}

// async global->LDS, 16B per lane; LDS dest = wave-uniform base + lane*16
__device__ __forceinline__ void gload16(const void* g, void* l) {
    __builtin_amdgcn_global_load_lds(
        (const __attribute__((address_space(1))) void*)g,
        (__attribute__((address_space(3))) void*)l,
        16, 0, 0);
}

// ============ 256x256 8-wave NT GEMM, BK=64B-rows, 4-seg cross-fed pipeline ============
// R3-verified engine.  F8=0: bf16, K-tile=64 elems.  F8=1: fp8 e4m3 with k-PERMUTED operands
// (producers write pcol(k)) -> staging swizzle AND b128 fragment reads are byte-identical to
// bf16 (same addresses, same bank profile); each 16B read = 2 i64 halves -> 2 fp8 MFMAs.
// This removes R10's 4-way b64 conflicts that ate the fp8 gain.
// EPI 0: bf16 C = alpha*acc
// EPI 1 (F8): fp8 C[rw*ldc+pcol(c)] = fp8( 64 * aux3[ix] * (acc*alpha - SUM4(aux1 slabs)[row]) )
// EPI 2: f32  C = aux1[ix] + (float)aux3[ix] - alpha*acc        (out = V + AO - eps*scale/64 * dS8@K8)
template<int EPI, int F8>
__global__ __launch_bounds__(512, 1)
void gemm8p(const void* __restrict__ A, const void* __restrict__ Bm,
            void* __restrict__ Cp, int Kdim, int lda, int ldb, int ldc,
            long sA, long sB, long sC, float alpha,
            const float* __restrict__ aux1, const bf16* __restrict__ aux3)
{
    constexpr int ES = F8 ? 1 : 2;   // element size bytes
    __shared__ __align__(16) char smem[163840];

    // XCD-aware bijective swizzle (ntot % 8 == 0 for all launches)
    const int gx = gridDim.x, gy = gridDim.y;
    int lin = blockIdx.x + gx * (blockIdx.y + gy * blockIdx.z);
    const int q = (gx * gy * gridDim.z) >> 3;
    lin = (lin & 7) * q + (lin >> 3);
    const int bx = lin % gx;
    const int rem0 = lin / gx;
    const int by = rem0 % gy;
    const int bz = rem0 / gy;

    const int t0 = threadIdx.x;
    const int w = t0 >> 6, lane = t0 & 63;
    const int wm = w >> 2, wn = w & 3;          // 2 x 4 wave grid; per-wave C = 128 x 64
    const int m0 = by * 256, n0 = bx * 256;
    const long zb = bz;

    const char* Ab = (const char*)A + ((size_t)zb * sA + (size_t)m0 * lda) * ES;
    const char* Bb = (const char*)Bm + ((size_t)zb * sB + (size_t)n0 * ldb) * ES;

    // staging lane coords: wave w stages subtiles {w, 8+w} of a 128-row half-tile.
    // source col-byte within the 64-B k-half, inverse st_16x32 swizzle (both modes identical)
    const int sr16 = lane >> 2;
    const int sceB = (((lane & 3) << 4) ^ (((lane >> 5) & 1) << 5));
    const int r0s = (w >> 1) * 16 + sr16;
    const int c0sB = (w & 1) * 64 + sceB;
    const char* gA0 = Ab + (size_t)r0s * lda * ES + c0sB;
    const char* gA1 = Ab + (size_t)(128 + r0s) * lda * ES + c0sB;
    const char* gB0 = Bb + (size_t)r0s * ldb * ES + c0sB;
    const char* gB1 = Bb + (size_t)(128 + r0s) * ldb * ES + c0sB;
    const size_t a64 = (size_t)64 * lda * ES, b64 = (size_t)64 * ldb * ES;
    const int ldsW0 = w * 1024, ldsW1 = (8 + w) * 1024;

    // fragment-read bases (identical byte addresses both modes)
    const int lr = lane & 15, lkq = lane >> 4;
    const int phx = ((lane >> 3) & 1) << 5;
    const int frag_base = (lr * 64 + lkq * 16) ^ phx;
    const char* aR = smem + wm * 16384 + frag_base;
    const char* bR = smem + 98304 + (wn >> 1) * 16384 + (wn & 1) * 8192 + frag_base;

    f32x4 acc[8][4] = {};
    const int NTt = Kdim >> (F8 ? 7 : 6);       // K-tiles (always even, >=2)

    auto stgA = [&](int h, int u, int off) {
        char* L = smem + off + h * 16384;
        const char* g = h ? gA1 : gA0;
        gload16(g + (size_t)u * 128,        L + ldsW0);
        gload16(g + a64 + (size_t)u * 128,  L + ldsW1);
    };
    auto stgB = [&](int h, int u, int p) {
        char* L = smem + 98304 + p * 32768 + h * 16384;
        const char* g = h ? gB1 : gB0;
        gload16(g + (size_t)u * 128,        L + ldsW0);
        gload16(g + b64 + (size_t)u * 128,  L + ldsW1);
    };

    // ---- prologue: A(0),B(0),A(1),B(1); vmcnt(8) confirms A(0),B(0); barrier publishes ----
    stgA(0, 0, 0);     stgA(1, 0, 0);     stgB(0, 0, 0); stgB(1, 0, 0);
    stgA(0, 1, 32768); stgA(1, 1, 32768); stgB(0, 1, 1); stgB(1, 1, 1);
    asm volatile("s_waitcnt vmcnt(8)" ::: "memory");
    __builtin_amdgcn_s_barrier();
    MEMFENCE;

    bf16x8 a[4][2], bl[2][2], bh[2][2];
    i64x2 a8[4][2], bl8[2][2], bh8[2][2];

#define RD8(DST, BASE, SUB)  DST = *(const i64x2*)((BASE) + (SUB) * 1024);

    // pre-read al(0) and bh(0)
    if constexpr (!F8) {
        #pragma unroll
        for (int mf = 0; mf < 4; ++mf)
            #pragma unroll
            for (int ks = 0; ks < 2; ++ks)
                a[mf][ks] = *(const bf16x8*)(aR + (mf * 2 + ks) * 1024);
        #pragma unroll
        for (int nf = 0; nf < 2; ++nf)
            #pragma unroll
            for (int ks = 0; ks < 2; ++ks)
                bh[nf][ks] = *(const bf16x8*)(bR + ((2 + nf) * 2 + ks) * 1024);
    } else {
        #pragma unroll
        for (int mf = 0; mf < 4; ++mf)
            #pragma unroll
            for (int ks = 0; ks < 2; ++ks) { RD8(a8[mf][ks], aR, mf * 2 + ks) }
        #pragma unroll
        for (int nf = 0; nf < 2; ++nf)
            #pragma unroll
            for (int ks = 0; ks < 2; ++ks) { RD8(bh8[nf][ks], bR, (2 + nf) * 2 + ks) }
    }

#define QUADQ(MFB, NFB, AARR, BARR)                                                     \
    __builtin_amdgcn_s_setprio(1);                                                      \
    _Pragma("unroll")                                                                   \
    for (int ks = 0; ks < 2; ++ks)                                                      \
        _Pragma("unroll")                                                               \
        for (int mf = 0; mf < 4; ++mf)                                                  \
            _Pragma("unroll")                                                           \
            for (int nf = 0; nf < 2; ++nf)                                              \
                acc[(MFB) + mf][(NFB) + nf] = __builtin_amdgcn_mfma_f32_16x16x32_bf16(  \
                    AARR[mf][ks], BARR[nf][ks], acc[(MFB) + mf][(NFB) + nf], 0, 0, 0);  \
    __builtin_amdgcn_s_setprio(0);

#define QUAD8(MFB, NFB, AARR, BARR)                                                     \
    __builtin_amdgcn_s_setprio(1);                                                      \
    _Pragma("unroll")                                                                   \
    for (int ks = 0; ks < 2; ++ks)                                                      \
        _Pragma("unroll")                                                               \
        for (int k2 = 0; k2 < 2; ++k2)                                                  \
            _Pragma("unroll")                                                           \
            for (int mf = 0; mf < 4; ++mf)                                              \
                _Pragma("unroll")                                                       \
                for (int nf = 0; nf < 2; ++nf)                                          \
                    acc[(MFB) + mf][(NFB) + nf] =                                       \
                        __builtin_amdgcn_mfma_f32_16x16x32_fp8_fp8(                     \
                            AARR[mf][ks][k2], BARR[nf][ks][k2],                         \
                            acc[(MFB) + mf][(NFB) + nf], 0, 0, 0);                      \
    __builtin_amdgcn_s_setprio(0);

    int aOff = 0, aOff1 = 32768, sOff = 65536;  // A(u), A(u+1), stage A(u+2)
    for (int u = 0; u < NTt; ++u) {
        const int p = u & 1;
        const char* aP  = aR + aOff;
        const char* aP1 = aR + aOff1;
        const char* bP  = bR + p * 32768;
        const char* bP1 = bR + (p ^ 1) * 32768;
        const bool st2 = (u + 2 < NTt), nx = (u + 1 < NTt);

        // ---- seg1: Q(0,2)=al*bh ; read bl(u); stage A0(u+2) ----
        if (st2) stgA(0, u + 2, sOff);
        if constexpr (!F8) {
            #pragma unroll
            for (int nf = 0; nf < 2; ++nf)
                #pragma unroll
                for (int ks = 0; ks < 2; ++ks)
                    bl[nf][ks] = *(const bf16x8*)(bP + (nf * 2 + ks) * 1024);
            QUADQ(0, 2, a, bh)
        } else {
            #pragma unroll
            for (int nf = 0; nf < 2; ++nf)
                #pragma unroll
                for (int ks = 0; ks < 2; ++ks) { RD8(bl8[nf][ks], bP, nf * 2 + ks) }
            QUAD8(0, 2, a8, bh8)
        }

        // ---- seg2: Q(0,0)=al*bl ; a <- ah(u); stage A1(u+2); W1; barrier1 ----
        if (st2) stgA(1, u + 2, sOff);
        if constexpr (!F8) {
            QUADQ(0, 0, a, bl)
            #pragma unroll
            for (int mf = 0; mf < 4; ++mf)
                #pragma unroll
                for (int ks = 0; ks < 2; ++ks)
                    a[mf][ks] = *(const bf16x8*)(aP + ((4 + mf) * 2 + ks) * 1024);
        } else {
            QUAD8(0, 0, a8, bl8)
            #pragma unroll
            for (int mf = 0; mf < 4; ++mf)
                #pragma unroll
                for (int ks = 0; ks < 2; ++ks) { RD8(a8[mf][ks], aP, (4 + mf) * 2 + ks) }
        }
        MEMFENCE;
        if (st2)     asm volatile("s_waitcnt vmcnt(4)" ::: "memory");  // A(u+1)+B(u+1)
        else if (nx) asm volatile("s_waitcnt vmcnt(0)" ::: "memory");  // tail: confirm both
        __builtin_amdgcn_s_barrier();
        MEMFENCE;

        // ---- seg3: Q(4,0)=ah*bl ; stage B0(u+2) ----
        if (st2) stgB(0, u + 2, p);
        if constexpr (!F8) { QUADQ(4, 0, a, bl) } else { QUAD8(4, 0, a8, bl8) }

        // ---- seg4: Q(4,2)=ah*bh ; a <- al(u+1); bh <- bh(u+1); barrier2 ----
        if (st2) stgB(1, u + 2, p);
        if constexpr (!F8) {
            QUADQ(4, 2, a, bh)
            if (nx) {
                #pragma unroll
                for (int mf = 0; mf < 4; ++mf)
                    #pragma unroll
                    for (int ks = 0; ks < 2; ++ks)
                        a[mf][ks] = *(const bf16x8*)(aP1 + (mf * 2 + ks) * 1024);
                #pragma unroll
                for (int nf = 0; nf < 2; ++nf)
                    #pragma unroll
                    for (int ks = 0; ks < 2; ++ks)
                        bh[nf][ks] = *(const bf16x8*)(bP1 + ((2 + nf) * 2 + ks) * 1024);
            }
        } else {
            QUAD8(4, 2, a8, bh8)
            if (nx) {
                #pragma unroll
                for (int mf = 0; mf < 4; ++mf)
                    #pragma unroll
                    for (int ks = 0; ks < 2; ++ks) { RD8(a8[mf][ks], aP1, mf * 2 + ks) }
                #pragma unroll
                for (int nf = 0; nf < 2; ++nf)
                    #pragma unroll
                    for (int ks = 0; ks < 2; ++ks) { RD8(bh8[nf][ks], bP1, (2 + nf) * 2 + ks) }
            }
        }
        MEMFENCE;
        __builtin_amdgcn_s_barrier();
        MEMFENCE;

        const int tmp = aOff; aOff = aOff1; aOff1 = sOff; sOff = tmp;
    }
#undef QUADQ
#undef QUAD8
#undef RD8

    // ---- epilogue: D layout col=lane&15, row=(lane>>4)*4+reg ----
    const int rb  = m0 + wm * 128 + lkq * 4;
    const int cb0 = n0 + wn * 64 + lr;
    #pragma unroll
    for (int mf = 0; mf < 8; ++mf) {
        #pragma unroll
        for (int r = 0; r < 4; ++r) {
            const int rw = rb + mf * 16 + r;
            float rd = 0.f;
            if (EPI == 1) {
                const size_t gr = zb * 2048 + rw;   // 4 per-block-column slabs from GEMM4
                rd = aux1[gr] + aux1[16384 + gr] + aux1[32768 + gr] + aux1[49152 + gr];
            }
            #pragma unroll
            for (int nf = 0; nf < 4; ++nf) {
                const int c = cb0 + nf * 16;
                const size_t ix = (size_t)rw * ldc + c;
                const float v = acc[mf][nf][r];
                if (EPI == 0) {
                    ((bf16*)Cp + zb * sC)[ix] = (bf16)(alpha * v);
                } else if (EPI == 1) {
                    // dS8 = fp8(64 * A * (v/16 - rd)); Amat read unpermuted; store k-permuted
                    const bf16* Am = aux3 + zb * sC;
                    const float t = (float)Am[ix] * (v * alpha - rd) * 64.f;
                    ((unsigned char*)Cp + zb * sC)[(size_t)rw * ldc + pcol(c)] = tofp8(t);
                } else {
                    float* C = (float*)Cp + zb * sC;
                    const float* Vv = aux1 + zb * sC;
                    const bf16* AOv = aux3 + zb * sC;
                    C[ix] = Vv[ix] + (float)AOv[ix] - alpha * v;
                }
            }
        }
    }
}

// ===== 256 x (64*NF) quad-slot BK=32 cross-step (R3-verified engine, bf16) =====
// EPI 0: bf16 C = alpha*acc
// EPI 3: fp8 U8[rw*ldc+pcol(c)] = fp8(16 * silu'(acc+aux1[col])*aux2[col]); rowdot slab -> rds
// EPI 4: fp8 C[rw*ldc+pcol(c)] = fp8(alpha*acc)                              (VW18)
template<int EPI, int NF>
__global__ __launch_bounds__(512, 1)
void gemm_nc(const bf16* __restrict__ A, const bf16* __restrict__ Bm,
             void* __restrict__ Cp, int Kdim, int lda, int ldb, int ldc,
             long sA, long sB, long sC, float alpha,
             const float* __restrict__ aux1, const float* __restrict__ aux2,
             float* __restrict__ rds)
{
    constexpr int SB = NF * 4096;
    __shared__ __align__(16) char smem[65536 + 4 * SB];

    const int gx = gridDim.x, gy = gridDim.y;
    int lin = blockIdx.x + gx * (blockIdx.y + gy * blockIdx.z);
    const int q = (gx * gy * gridDim.z) >> 3;
    lin = (lin & 7) * q + (lin >> 3);
    const int bx = lin % gx;
    const int rem0 = lin / gx;
    const int by = rem0 % gy;
    const int bz = rem0 / gy;

    const int t0 = threadIdx.x;
    const int w = t0 >> 6, lane = t0 & 63;
    const int wm = w >> 2, wn = w & 3;
    const int m0 = by * 256, n0 = bx * (64 * NF);
    const long zb = bz;

    const bf16* Ab = A  + zb * sA + (size_t)m0 * lda;
    const bf16* Bb = Bm + zb * sB + (size_t)n0 * ldb;

    const int sr16 = lane >> 2;
    const int sce  = ((((lane & 3) << 4) ^ (((lane >> 5) & 1) << 5))) >> 1;
    const int stg0 = w * 2, stg1 = w * 2 + 1;
    const bf16* pA0 = Ab + (size_t)(stg0 * 16 + sr16) * lda + sce;
    const bf16* pA1 = Ab + (size_t)(stg1 * 16 + sr16) * lda + sce;
    const bf16* pB0 = Bb + (size_t)((NF == 4 ? stg0 : w) * 16 + sr16) * ldb + sce;
    const bf16* pB1 = Bb + (size_t)(stg1 * 16 + sr16) * ldb + sce;

    const int lr = lane & 15, lkq = lane >> 4;
    const int phx = ((lane >> 3) & 1) << 5;
    const int frag_base = lr * 64 + lkq * 16;

    f32x4 acc[8][NF] = {};
    const int NT = Kdim >> 5;

    auto issueSlot = [&](int p) {
        char* lA = smem + (p & 3) * 16384;
        char* lB = smem + 65536 + (p & 3) * SB;
        const int kt = p << 5;
        gload16(pA0 + kt, lA + stg0 * 1024);
        gload16(pA1 + kt, lA + stg1 * 1024);
        if (NF == 4) {
            gload16(pB0 + kt, lB + stg0 * 1024);
            gload16(pB1 + kt, lB + stg1 * 1024);
        } else {
            gload16(pB0 + kt, lB + w * 1024);
        }
    };
    auto rdA = [&](const char* base, int sub) {
        return *(const bf16x8*)(base + (((sub << 10) + frag_base) ^ phx));
    };

    issueSlot(0); issueSlot(1); issueSlot(2);
    if (NF == 4) asm volatile("s_waitcnt vmcnt(4)" ::: "memory");
    else         asm volatile("s_waitcnt vmcnt(3)" ::: "memory");
    __builtin_amdgcn_s_barrier();
    MEMFENCE;

    bf16x8 alo[4], ahi[4], b0[NF], b1[NF];
    {
        const char* cA = smem;
        const char* cB = smem + 65536;
        #pragma unroll
        for (int mf = 0; mf < 4; ++mf) alo[mf] = rdA(cA, wm * 8 + mf);
        #pragma unroll
        for (int nf = 0; nf < NF; ++nf) b0[nf] = rdA(cB, wn * NF + nf);
    }

    auto stepBody = [&](int SL, int s, bf16x8 (&bA)[NF], bf16x8 (&bB)[NF]) {
        if (s + 3 < NT) issueSlot(s + 3);
        const char* cA = smem + SL * 16384;
        #pragma unroll
        for (int mf = 0; mf < 4; ++mf) ahi[mf] = rdA(cA, wm * 8 + 4 + mf);

        __builtin_amdgcn_s_setprio(1);
        #pragma unroll
        for (int mf = 0; mf < 4; ++mf)
            #pragma unroll
            for (int nf = 0; nf < NF; ++nf)
                acc[mf][nf] = __builtin_amdgcn_mfma_f32_16x16x32_bf16(alo[mf], bA[nf], acc[mf][nf], 0, 0, 0);
        __builtin_amdgcn_s_setprio(0);

        if (s + 1 < NT) {
            const int NS = (SL + 1) & 3;
            const char* nA = smem + NS * 16384;
            const char* nB = smem + 65536 + NS * SB;
            #pragma unroll
            for (int mf = 0; mf < 4; ++mf) alo[mf] = rdA(nA, wm * 8 + mf);
            #pragma unroll
            for (int nf = 0; nf < NF; ++nf) bB[nf] = rdA(nB, wn * NF + nf);
        }

        __builtin_amdgcn_s_setprio(1);
        #pragma unroll
        for (int mf = 0; mf < 4; ++mf)
            #pragma unroll
            for (int nf = 0; nf < NF; ++nf)
                acc[4 + mf][nf] = __builtin_amdgcn_mfma_f32_16x16x32_bf16(ahi[mf], bA[nf], acc[4 + mf][nf], 0, 0, 0);
        __builtin_amdgcn_s_setprio(0);

        MEMFENCE;
        if (s + 3 < NT) {
            if (NF == 4) asm volatile("s_waitcnt vmcnt(4)" ::: "memory");
            else         asm volatile("s_waitcnt vmcnt(3)" ::: "memory");
        } else {
            asm volatile("s_waitcnt vmcnt(0)" ::: "memory");
        }
        __builtin_amdgcn_s_barrier();
        MEMFENCE;
    };

    for (int s = 0; s < NT; s += 2) {
        stepBody(s & 3, s, b0, b1);
        stepBody((s + 1) & 3, s + 1, b1, b0);
    }

    const int rb  = m0 + wm * 128 + lkq * 4;
    const int cb0 = n0 + wn * (NF * 16) + lr;

    if (EPI == 0 || EPI == 4) {
        #pragma unroll
        for (int mf = 0; mf < 8; ++mf)
            #pragma unroll
            for (int nf = 0; nf < NF; ++nf) {
                const int c = cb0 + nf * 16;
                #pragma unroll
                for (int r = 0; r < 4; ++r) {
                    const int rw = rb + mf * 16 + r;
                    if (EPI == 0)
                        ((bf16*)Cp + zb * sC)[(size_t)rw * ldc + c] = (bf16)(alpha * acc[mf][nf][r]);
                    else
                        ((unsigned char*)Cp + zb * sC)[(size_t)rw * ldc + pcol(c)] = tofp8(alpha * acc[mf][nf][r]);
                }
            }
    } else {
        // EPI 3: U8 = fp8(16*U) store (k-permuted) + in-register rowdot partial (raw units).
        float* smemF = (float*)smem;
        #pragma unroll
        for (int mf = 0; mf < 8; ++mf) {
            #pragma unroll
            for (int r = 0; r < 4; ++r) {
                const int rw = rb + mf * 16 + r;
                float pd = 0.f;
                #pragma unroll
                for (int nf = 0; nf < NF; ++nf) {
                    const int c = cb0 + nf * 16;
                    const float v = acc[mf][nf][r];
                    const float u = v + aux1[c];
                    const float sg = 1.f / (1.f + __expf(-u));
                    const float dd = sg * (1.f + u * (1.f - sg));
                    const float uval = dd * aux2[c];
                    ((unsigned char*)Cp)[(size_t)rw * ldc + pcol(c)] = tofp8(uval * 16.f);
                    pd += uval * v;                      // U[r,c] * H[r,c] (raw)
                }
                #pragma unroll
                for (int o = 1; o < 16; o <<= 1) pd += __shfl_xor(pd, o, 64);
                if (lr == 0)
                    smemF[wn * 256 + wm * 128 + mf * 16 + lkq * 4 + r] = pd;
            }
        }
        __syncthreads();
        if (t0 < 256) {
            const float s4 = smemF[t0] + smemF[256 + t0] + smemF[512 + t0] + smemF[768 + t0];
            rds[(size_t)bx * 16384 + m0 + t0] = s4;   // slab per block-column bx
        }
    }
}

// ---------------- fp32 -> bf16 cast (DN) and/or transposed cast (TM) body ----------------
// TM: 0 = none, 1 = bf16 transpose, 2 = fp8 transpose with k-permuted rows (64-blocks)
template<bool DN, int TM>
__device__ __forceinline__ void transcast_body(
                 const float* __restrict__ in, bf16* __restrict__ outN,
                 void* __restrict__ outT, int R, int C, int bx, int by, int bz,
                 float (*ts)[65])
{
    const int t = threadIdx.x;
    const int c0 = bx * 64, r0 = by * 64;
    const size_t zoff = (size_t)bz * R * C;

    const int rr = t >> 2, cc = (t & 3) * 16;
    float4 f[4];
    const float* src = in + zoff + (size_t)(r0 + rr) * C + c0 + cc;
    #pragma unroll
    for (int i = 0; i < 4; ++i) f[i] = *(const float4*)(src + 4 * i);

    if (DN) {
        bf16x8 h0, h1;
        #pragma unroll
        for (int i = 0; i < 2; ++i) {
            h0[i*4+0] = (bf16)f[i].x;   h0[i*4+1] = (bf16)f[i].y;
            h0[i*4+2] = (bf16)f[i].z;   h0[i*4+3] = (bf16)f[i].w;
            h1[i*4+0] = (bf16)f[i+2].x; h1[i*4+1] = (bf16)f[i+2].y;
            h1[i*4+2] = (bf16)f[i+2].z; h1[i*4+3] = (bf16)f[i+2].w;
        }
        bf16* dst = outN + zoff + (size_t)(r0 + rr) * C + c0 + cc;
        *(bf16x8*)dst = h0;
        *(bf16x8*)(dst + 8) = h1;
    }
    if (TM) {
        #pragma unroll
        for (int i = 0; i < 4; ++i) {
            ts[rr][cc + 4*i + 0] = f[i].x;
            ts[rr][cc + 4*i + 1] = f[i].y;
            ts[rr][cc + 4*i + 2] = f[i].z;
            ts[rr][cc + 4*i + 3] = f[i].w;
        }
        __syncthreads();
        const int ct = t >> 2, rr4 = (t & 3) * 16;
        if (TM == 1) {
            bf16x8 o0, o1;
            #pragma unroll
            for (int i = 0; i < 8; ++i) o0[i] = (bf16)ts[rr4 + i][ct];
            #pragma unroll
            for (int i = 0; i < 8; ++i) o1[i] = (bf16)ts[rr4 + 8 + i][ct];
            bf16* dst = (bf16*)outT + zoff + (size_t)(c0 + ct) * R + r0 + rr4;
            *(bf16x8*)dst = o0;
            *(bf16x8*)(dst + 8) = o1;
        } else {
            // fp8 transpose: 16 rows -> 16 bytes, split into two 8B runs at permuted offsets.
            // rows (r0+rr4+e): within 64-block, bytes [rr4,rr4+8) -> plo, [rr4+8,+16) -> plo+16
            i32x4 o;
            #pragma unroll
            for (int g = 0; g < 4; ++g) {
                int v = __builtin_amdgcn_cvt_pk_fp8_f32(ts[rr4 + 4*g + 0][ct], ts[rr4 + 4*g + 1][ct], 0, false);
                v = __builtin_amdgcn_cvt_pk_fp8_f32(ts[rr4 + 4*g + 2][ct], ts[rr4 + 4*g + 3][ct], v, true);
                o[g] = v;
            }
            const int plo = ((rr4 & 31) << 1) + ((rr4 >> 5) << 3);   // 0,32,8,40
            unsigned char* dstb = (unsigned char*)outT + zoff + (size_t)(c0 + ct) * R + r0;
            i32x2 lo; lo[0] = o[0]; lo[1] = o[1];
            i32x2 hi; hi[0] = o[2]; hi[1] = o[3];
            *(i32x2*)(dstb + plo) = lo;
            *(i32x2*)(dstb + plo + 16) = hi;
        }
    }
}

// one launch for all input casts: z 0-7 Q, 8-15 K (bf16 N + fp8 T), 16-23 V (bf16 N+T), 24 W1^T
__global__ __launch_bounds__(256)
void trans_all(const float* __restrict__ Q, const float* __restrict__ Km,
               const float* __restrict__ V, const float* __restrict__ W1,
               bf16* __restrict__ Qb, bf16* __restrict__ Kb, unsigned char* __restrict__ KbT8,
               bf16* __restrict__ Vb, bf16* __restrict__ VbT, bf16* __restrict__ W1T)
{
    __shared__ float ts[64][65];
    const int z = blockIdx.z;
    if (z < 8) {
        transcast_body<true, 0>(Q, Qb, nullptr, 2048, 1024, blockIdx.x, blockIdx.y, z, ts);
    } else if (z < 16) {
        transcast_body<true, 2>(Km, Kb, KbT8, 2048, 1024, blockIdx.x, blockIdx.y, z - 8, ts);
    } else if (z < 24) {
        transcast_body<true, 1>(V, Vb, VbT, 2048, 1024, blockIdx.x, blockIdx.y, z - 16, ts);
    } else {
        if (blockIdx.x < 8 && blockIdx.y < 16)
            transcast_body<false, 1>(W1, nullptr, W1T, 1024, 512, blockIdx.x, blockIdx.y, 0, ts);
    }
}

// ---------------- row softmax over 2048-wide rows ----------------
__global__ __launch_bounds__(256)
void softmax_k(const bf16* __restrict__ S, bf16* __restrict__ A)
{
    const size_t row = blockIdx.x;
    const int t = threadIdx.x;
    const int wid = t >> 6, lane = t & 63;
    __shared__ float r1[4], r2[4];

    bf16x8 v = *(const bf16x8*)(S + row * 2048 + t * 8);
    float f[8];
    float mx = -1e30f;
    #pragma unroll
    for (int i = 0; i < 8; ++i) { f[i] = (float)v[i]; mx = fmaxf(mx, f[i]); }
    #pragma unroll
    for (int o = 32; o; o >>= 1) mx = fmaxf(mx, __shfl_xor(mx, o, 64));
    if (!lane) r1[wid] = mx;
    __syncthreads();
    mx = fmaxf(fmaxf(r1[0], r1[1]), fmaxf(r1[2], r1[3]));

    float sum = 0.f;
    #pragma unroll
    for (int i = 0; i < 8; ++i) { f[i] = __expf(f[i] - mx); sum += f[i]; }
    #pragma unroll
    for (int o = 32; o; o >>= 1) sum += __shfl_xor(sum, o, 64);
    if (!lane) r2[wid] = sum;
    __syncthreads();
    sum = r2[0] + r2[1] + r2[2] + r2[3];

    const float inv = 1.f / sum;
    bf16x8 ov;
    #pragma unroll
    for (int i = 0; i < 8; ++i) ov[i] = (bf16)(f[i] * inv);
    *(bf16x8*)(A + row * 2048 + t * 8) = ov;
}

extern "C" void kernel_launch(void* const* d_in, const int* in_sizes, int n_in,
                              void* d_out, int out_size, void* d_ws, size_t ws_size,
                              hipStream_t stream)
{
    const float* Q  = (const float*)d_in[0];
    const float* Km = (const float*)d_in[1];
    const float* V  = (const float*)d_in[2];
    const float* W1 = (const float*)d_in[3];
    const float* b1 = (const float*)d_in[4];
    const float* W2 = (const float*)d_in[5];
    float* out = (float*)d_out;

    // ---- workspace layout (~236 MB, live-range packed; all launches sequential) ----
    char* ws = (char*)d_ws;
    bf16* Amat = (bf16*)(ws);                            // R1: softmax A (bf16, live to G6)
    bf16* AO   = (bf16*)(ws + 67108864);                 // R2: Kb, then attn_out bf16
    bf16* Kb   = AO;
    unsigned char* KbT8 = (unsigned char*)(ws + 100663296);  // R3: K^T fp8 k-permuted (16.8 MB)
    float* rdSlab = (float*)(ws + 117440512);            // R3 tail: rowdot slabs [4][16384] f32
    bf16* Vb   = (bf16*)(ws + 134217728);                // R4: V bf16 (dead after VW1)
    unsigned char* dS8 = (unsigned char*)(ws + 134217728);   // R4 reuse: dS fp8 k-perm (G6->G7)
    bf16* VbT  = (bf16*)(ws + 167772160);                // R5: V^T bf16 (dead after G3)
    unsigned char* U8 = (unsigned char*)(ws + 167772160);    // R5 reuse: U fp8 = 16*U k-perm
    bf16* Qb   = (bf16*)(ws + 201326592);                // R6: Q bf16 (dead after G1)
    unsigned char* VW18 = (unsigned char*)(ws + 201326592);  // R6 reuse: VW1 fp8 k-perm
    bf16* W1T  = (bf16*)(ws + 234881024);                // R7: W1^T bf16 (1 MB)
    bf16* S    = (bf16*)d_out;                           // S (dead after softmax)

    const long sQK = 2048L * 1024;
    const long sS  = 2048L * 2048;
    const long sVW = 2048L * 512;
    dim3 blk(256), blkG(512);

    // prep: all bf16/fp8 casts / transposes in one launch
    trans_all<<<dim3(16, 32, 25), blk, 0, stream>>>(Q, Km, V, W1, Qb, Kb, KbT8, Vb, VbT, W1T);

    // 1) S = scale * Qb @ Kb^T                               (bf16)
    gemm8p<0, 0><<<dim3(8, 8, 8), blkG, 0, stream>>>(
        Qb, Kb, S, 1024, 1024, 1024, 2048, sQK, sQK, sS, 0.03125f, nullptr, nullptr);

    // 1b) VW18 = fp8(V @ W1)  (writes Qb region — dead after GEMM 1)
    gemm_nc<4, 2><<<dim3(4, 8, 8), blkG, 0, stream>>>(
        Vb, W1T, VW18, 1024, 1024, 1024, 512, sQK, 0, sVW, 1.0f, nullptr, nullptr, nullptr);

    // 2) A = row-softmax(S)
    softmax_k<<<dim3(16384), blk, 0, stream>>>(S, Amat);

    // 3) attn_out = A @ V   (B = V^T; bf16)
    gemm8p<0, 0><<<dim3(4, 8, 8), blkG, 0, stream>>>(
        Amat, VbT, AO, 2048, 2048, 2048, 1024, sS, sQK, sQK, 1.0f, nullptr, nullptr);

    // 4) U8 = fp8(16 * silu'(AO@W1+b1)*w2); rowdot slabs fused (H eliminated)
    gemm_nc<3, 2><<<dim3(4, 64, 1), blkG, 0, stream>>>(
        AO, W1T, U8, 1024, 1024, 1024, 512, 0, 0, 0, 1.0f, b1, W2, rdSlab);

    // 6) dS8 = fp8(64 * A .* (U8@VW18^T / 16 - rowdot))   — fp8 GEMM, K=512
    gemm8p<1, 1><<<dim3(8, 8, 8), blkG, 0, stream>>>(
        U8, VW18, dS8, 512, 512, 512, 2048, 1048576, 1048576, 4194304, 0.0625f, rdSlab, Amat);

    // 7) out = V + attn_out - (eps*scale/64) * dS8 @ K     — fp8 GEMM, K=2048
    gemm8p<2, 1><<<dim3(4, 8, 8), blkG, 0, stream>>>(
        dS8, KbT8, out, 2048, 2048, 2048, 1024, 4194304, 2097152, 2097152,
        0.03f * 0.03125f / 64.f, V, AO);
}

// Round 12
// 378.971 us; speedup vs baseline: 1.2967x; 1.0098x over previous
//
#include <hip/hip_runtime.h>

typedef __bf16 bf16;
typedef long i64;
typedef __attribute__((ext_vector_type(2))) long i64x2;
typedef __attribute__((ext_vector_type(2))) int i32x2;
typedef __attribute__((ext_vector_type(4))) __bf16 bf16x4;
typedef __attribute__((ext_vector_type(8))) __bf16 bf16x8;
typedef __attribute__((ext_vector_type(4))) float f32x4;
typedef __attribute__((ext_vector_type(4))) int i32x4;

#define MEMFENCE asm volatile("" ::: "memory")

__device__ __forceinline__ unsigned char tofp8(float x) {
    return (unsigned char)(__builtin_amdgcn_cvt_pk_fp8_f32(x, x, 0, false) & 0xff);
}
// k-permutation within 64-blocks: element e=k2*32+lkq*8+b -> byte lkq*16+k2*8+b.
// Makes fp8 fragment reads byte-identical to the verified bf16 b128 pattern.
__device__ __forceinline__ int pcol(int c) {
    return (c & ~63) | (((c >> 3) & 3) << 4) | (((c >> 5) & 1) << 3) | (c & 7);
}

// async global->LDS, 16B per lane; LDS dest = wave-uniform base + lane*16
__device__ __forceinline__ void gload16(const void* g, void* l) {
    __builtin_amdgcn_global_load_lds(
        (const __attribute__((address_space(1))) void*)g,
        (__attribute__((address_space(3))) void*)l,
        16, 0, 0);
}

// ============ 256x256 8-wave NT GEMM, BK=64B-rows, 4-seg cross-fed pipeline ============
// R3-verified engine.  F8=0: bf16, K-tile=64 elems.  F8=1: fp8 e4m3 with k-PERMUTED operands
// (producers write pcol(k)) -> staging swizzle AND b128 fragment reads are byte-identical to
// bf16 (same addresses, same bank profile); each 16B read = 2 i64 halves -> 2 fp8 MFMAs.
// EPI 0: bf16 C = alpha*acc
// EPI 1 (F8): fp8 C[rw*ldc+pcol(c)] = fp8( 64 * aux3[ix] * (acc*alpha - SUM4(aux1 slabs)[row]) )
// EPI 2: f32  C = aux1[ix] + (float)aux3[ix] - alpha*acc        (out = V + AO - eps*scale/64 * dS8@K8)
template<int EPI, int F8>
__global__ __launch_bounds__(512, 1)
void gemm8p(const void* __restrict__ A, const void* __restrict__ Bm,
            void* __restrict__ Cp, int Kdim, int lda, int ldb, int ldc,
            long sA, long sB, long sC, float alpha,
            const float* __restrict__ aux1, const bf16* __restrict__ aux3)
{
    constexpr int ES = F8 ? 1 : 2;   // element size bytes
    __shared__ __align__(16) char smem[163840];

    // XCD-aware bijective swizzle (ntot % 8 == 0 for all launches)
    const int gx = gridDim.x, gy = gridDim.y;
    int lin = blockIdx.x + gx * (blockIdx.y + gy * blockIdx.z);
    const int q = (gx * gy * gridDim.z) >> 3;
    lin = (lin & 7) * q + (lin >> 3);
    const int bx = lin % gx;
    const int rem0 = lin / gx;
    const int by = rem0 % gy;
    const int bz = rem0 / gy;

    const int t0 = threadIdx.x;
    const int w = t0 >> 6, lane = t0 & 63;
    const int wm = w >> 2, wn = w & 3;          // 2 x 4 wave grid; per-wave C = 128 x 64
    const int m0 = by * 256, n0 = bx * 256;
    const long zb = bz;

    const char* Ab = (const char*)A + ((size_t)zb * sA + (size_t)m0 * lda) * ES;
    const char* Bb = (const char*)Bm + ((size_t)zb * sB + (size_t)n0 * ldb) * ES;

    // staging lane coords: wave w stages subtiles {w, 8+w} of a 128-row half-tile.
    // source col-byte within the 64-B k-half, inverse st_16x32 swizzle (both modes identical)
    const int sr16 = lane >> 2;
    const int sceB = (((lane & 3) << 4) ^ (((lane >> 5) & 1) << 5));
    const int r0s = (w >> 1) * 16 + sr16;
    const int c0sB = (w & 1) * 64 + sceB;
    const char* gA0 = Ab + (size_t)r0s * lda * ES + c0sB;
    const char* gA1 = Ab + (size_t)(128 + r0s) * lda * ES + c0sB;
    const char* gB0 = Bb + (size_t)r0s * ldb * ES + c0sB;
    const char* gB1 = Bb + (size_t)(128 + r0s) * ldb * ES + c0sB;
    const size_t a64 = (size_t)64 * lda * ES, b64 = (size_t)64 * ldb * ES;
    const int ldsW0 = w * 1024, ldsW1 = (8 + w) * 1024;

    // fragment-read bases (identical byte addresses both modes)
    const int lr = lane & 15, lkq = lane >> 4;
    const int phx = ((lane >> 3) & 1) << 5;
    const int frag_base = (lr * 64 + lkq * 16) ^ phx;
    const char* aR = smem + wm * 16384 + frag_base;
    const char* bR = smem + 98304 + (wn >> 1) * 16384 + (wn & 1) * 8192 + frag_base;

    f32x4 acc[8][4] = {};
    const int NTt = Kdim >> (F8 ? 7 : 6);       // K-tiles (always even, >=2)

    auto stgA = [&](int h, int u, int off) {
        char* L = smem + off + h * 16384;
        const char* g = h ? gA1 : gA0;
        gload16(g + (size_t)u * 128,        L + ldsW0);
        gload16(g + a64 + (size_t)u * 128,  L + ldsW1);
    };
    auto stgB = [&](int h, int u, int p) {
        char* L = smem + 98304 + p * 32768 + h * 16384;
        const char* g = h ? gB1 : gB0;
        gload16(g + (size_t)u * 128,        L + ldsW0);
        gload16(g + b64 + (size_t)u * 128,  L + ldsW1);
    };

    // ---- prologue: A(0),B(0),A(1),B(1); vmcnt(8) confirms A(0),B(0); barrier publishes ----
    stgA(0, 0, 0);     stgA(1, 0, 0);     stgB(0, 0, 0); stgB(1, 0, 0);
    stgA(0, 1, 32768); stgA(1, 1, 32768); stgB(0, 1, 1); stgB(1, 1, 1);
    asm volatile("s_waitcnt vmcnt(8)" ::: "memory");
    __builtin_amdgcn_s_barrier();
    MEMFENCE;

    bf16x8 a[4][2], bl[2][2], bh[2][2];
    i64x2 a8[4][2], bl8[2][2], bh8[2][2];

#define RD8(DST, BASE, SUB)  DST = *(const i64x2*)((BASE) + (SUB) * 1024);

    // pre-read al(0) and bh(0)
    if constexpr (!F8) {
        #pragma unroll
        for (int mf = 0; mf < 4; ++mf)
            #pragma unroll
            for (int ks = 0; ks < 2; ++ks)
                a[mf][ks] = *(const bf16x8*)(aR + (mf * 2 + ks) * 1024);
        #pragma unroll
        for (int nf = 0; nf < 2; ++nf)
            #pragma unroll
            for (int ks = 0; ks < 2; ++ks)
                bh[nf][ks] = *(const bf16x8*)(bR + ((2 + nf) * 2 + ks) * 1024);
    } else {
        #pragma unroll
        for (int mf = 0; mf < 4; ++mf)
            #pragma unroll
            for (int ks = 0; ks < 2; ++ks) { RD8(a8[mf][ks], aR, mf * 2 + ks) }
        #pragma unroll
        for (int nf = 0; nf < 2; ++nf)
            #pragma unroll
            for (int ks = 0; ks < 2; ++ks) { RD8(bh8[nf][ks], bR, (2 + nf) * 2 + ks) }
    }

#define QUADQ(MFB, NFB, AARR, BARR)                                                     \
    __builtin_amdgcn_s_setprio(1);                                                      \
    _Pragma("unroll")                                                                   \
    for (int ks = 0; ks < 2; ++ks)                                                      \
        _Pragma("unroll")                                                               \
        for (int mf = 0; mf < 4; ++mf)                                                  \
            _Pragma("unroll")                                                           \
            for (int nf = 0; nf < 2; ++nf)                                              \
                acc[(MFB) + mf][(NFB) + nf] = __builtin_amdgcn_mfma_f32_16x16x32_bf16(  \
                    AARR[mf][ks], BARR[nf][ks], acc[(MFB) + mf][(NFB) + nf], 0, 0, 0);  \
    __builtin_amdgcn_s_setprio(0);

#define QUAD8(MFB, NFB, AARR, BARR)                                                     \
    __builtin_amdgcn_s_setprio(1);                                                      \
    _Pragma("unroll")                                                                   \
    for (int ks = 0; ks < 2; ++ks)                                                      \
        _Pragma("unroll")                                                               \
        for (int k2 = 0; k2 < 2; ++k2)                                                  \
            _Pragma("unroll")                                                           \
            for (int mf = 0; mf < 4; ++mf)                                              \
                _Pragma("unroll")                                                       \
                for (int nf = 0; nf < 2; ++nf)                                          \
                    acc[(MFB) + mf][(NFB) + nf] =                                       \
                        __builtin_amdgcn_mfma_f32_16x16x32_fp8_fp8(                     \
                            AARR[mf][ks][k2], BARR[nf][ks][k2],                         \
                            acc[(MFB) + mf][(NFB) + nf], 0, 0, 0);                      \
    __builtin_amdgcn_s_setprio(0);

    int aOff = 0, aOff1 = 32768, sOff = 65536;  // A(u), A(u+1), stage A(u+2)
    for (int u = 0; u < NTt; ++u) {
        const int p = u & 1;
        const char* aP  = aR + aOff;
        const char* aP1 = aR + aOff1;
        const char* bP  = bR + p * 32768;
        const char* bP1 = bR + (p ^ 1) * 32768;
        const bool st2 = (u + 2 < NTt), nx = (u + 1 < NTt);

        // ---- seg1: Q(0,2)=al*bh ; read bl(u); stage A0(u+2) ----
        if (st2) stgA(0, u + 2, sOff);
        if constexpr (!F8) {
            #pragma unroll
            for (int nf = 0; nf < 2; ++nf)
                #pragma unroll
                for (int ks = 0; ks < 2; ++ks)
                    bl[nf][ks] = *(const bf16x8*)(bP + (nf * 2 + ks) * 1024);
            QUADQ(0, 2, a, bh)
        } else {
            #pragma unroll
            for (int nf = 0; nf < 2; ++nf)
                #pragma unroll
                for (int ks = 0; ks < 2; ++ks) { RD8(bl8[nf][ks], bP, nf * 2 + ks) }
            QUAD8(0, 2, a8, bh8)
        }

        // ---- seg2: Q(0,0)=al*bl ; a <- ah(u); stage A1(u+2); W1; barrier1 ----
        if (st2) stgA(1, u + 2, sOff);
        if constexpr (!F8) {
            QUADQ(0, 0, a, bl)
            #pragma unroll
            for (int mf = 0; mf < 4; ++mf)
                #pragma unroll
                for (int ks = 0; ks < 2; ++ks)
                    a[mf][ks] = *(const bf16x8*)(aP + ((4 + mf) * 2 + ks) * 1024);
        } else {
            QUAD8(0, 0, a8, bl8)
            #pragma unroll
            for (int mf = 0; mf < 4; ++mf)
                #pragma unroll
                for (int ks = 0; ks < 2; ++ks) { RD8(a8[mf][ks], aP, (4 + mf) * 2 + ks) }
        }
        MEMFENCE;
        if (st2)     asm volatile("s_waitcnt vmcnt(4)" ::: "memory");  // A(u+1)+B(u+1)
        else if (nx) asm volatile("s_waitcnt vmcnt(0)" ::: "memory");  // tail: confirm both
        __builtin_amdgcn_s_barrier();
        MEMFENCE;

        // ---- seg3: Q(4,0)=ah*bl ; stage B0(u+2) ----
        if (st2) stgB(0, u + 2, p);
        if constexpr (!F8) { QUADQ(4, 0, a, bl) } else { QUAD8(4, 0, a8, bl8) }

        // ---- seg4: Q(4,2)=ah*bh ; a <- al(u+1); bh <- bh(u+1); barrier2 ----
        if (st2) stgB(1, u + 2, p);
        if constexpr (!F8) {
            QUADQ(4, 2, a, bh)
            if (nx) {
                #pragma unroll
                for (int mf = 0; mf < 4; ++mf)
                    #pragma unroll
                    for (int ks = 0; ks < 2; ++ks)
                        a[mf][ks] = *(const bf16x8*)(aP1 + (mf * 2 + ks) * 1024);
                #pragma unroll
                for (int nf = 0; nf < 2; ++nf)
                    #pragma unroll
                    for (int ks = 0; ks < 2; ++ks)
                        bh[nf][ks] = *(const bf16x8*)(bP1 + ((2 + nf) * 2 + ks) * 1024);
            }
        } else {
            QUAD8(4, 2, a8, bh8)
            if (nx) {
                #pragma unroll
                for (int mf = 0; mf < 4; ++mf)
                    #pragma unroll
                    for (int ks = 0; ks < 2; ++ks) { RD8(a8[mf][ks], aP1, mf * 2 + ks) }
                #pragma unroll
                for (int nf = 0; nf < 2; ++nf)
                    #pragma unroll
                    for (int ks = 0; ks < 2; ++ks) { RD8(bh8[nf][ks], bP1, (2 + nf) * 2 + ks) }
            }
        }
        MEMFENCE;
        __builtin_amdgcn_s_barrier();
        MEMFENCE;

        const int tmp = aOff; aOff = aOff1; aOff1 = sOff; sOff = tmp;
    }
#undef QUADQ
#undef QUAD8
#undef RD8

    // ---- epilogue: D layout col=lane&15, row=(lane>>4)*4+reg ----
    const int rb  = m0 + wm * 128 + lkq * 4;
    const int cb0 = n0 + wn * 64 + lr;
    #pragma unroll
    for (int mf = 0; mf < 8; ++mf) {
        #pragma unroll
        for (int r = 0; r < 4; ++r) {
            const int rw = rb + mf * 16 + r;
            float rd = 0.f;
            if (EPI == 1) {
                const size_t gr = zb * 2048 + rw;   // 4 per-block-column slabs from GEMM4
                rd = aux1[gr] + aux1[16384 + gr] + aux1[32768 + gr] + aux1[49152 + gr];
            }
            #pragma unroll
            for (int nf = 0; nf < 4; ++nf) {
                const int c = cb0 + nf * 16;
                const size_t ix = (size_t)rw * ldc + c;
                const float v = acc[mf][nf][r];
                if (EPI == 0) {
                    ((bf16*)Cp + zb * sC)[ix] = (bf16)(alpha * v);
                } else if (EPI == 1) {
                    // dS8 = fp8(64 * A * (v/16 - rd)); Amat read unpermuted; store k-permuted
                    const bf16* Am = aux3 + zb * sC;
                    const float t = (float)Am[ix] * (v * alpha - rd) * 64.f;
                    ((unsigned char*)Cp + zb * sC)[(size_t)rw * ldc + pcol(c)] = tofp8(t);
                } else {
                    float* C = (float*)Cp + zb * sC;
                    const float* Vv = aux1 + zb * sC;
                    const bf16* AOv = aux3 + zb * sC;
                    C[ix] = Vv[ix] + (float)AOv[ix] - alpha * v;
                }
            }
        }
    }
}

// ===== 256 x (64*NF) quad-slot BK=32 cross-step (R3-verified engine, bf16) =====
// EPI 0: bf16 C = alpha*acc
// EPI 3: fp8 U8[rw*ldc+pcol(c)] = fp8(16 * silu'(acc+aux1[col])*aux2[col]); rowdot slab -> rds
// EPI 4: fp8 C[rw*ldc+pcol(c)] = fp8(alpha*acc)                              (VW18)
template<int EPI, int NF>
__global__ __launch_bounds__(512, 1)
void gemm_nc(const bf16* __restrict__ A, const bf16* __restrict__ Bm,
             void* __restrict__ Cp, int Kdim, int lda, int ldb, int ldc,
             long sA, long sB, long sC, float alpha,
             const float* __restrict__ aux1, const float* __restrict__ aux2,
             float* __restrict__ rds)
{
    constexpr int SB = NF * 4096;
    __shared__ __align__(16) char smem[65536 + 4 * SB];

    const int gx = gridDim.x, gy = gridDim.y;
    int lin = blockIdx.x + gx * (blockIdx.y + gy * blockIdx.z);
    const int q = (gx * gy * gridDim.z) >> 3;
    lin = (lin & 7) * q + (lin >> 3);
    const int bx = lin % gx;
    const int rem0 = lin / gx;
    const int by = rem0 % gy;
    const int bz = rem0 / gy;

    const int t0 = threadIdx.x;
    const int w = t0 >> 6, lane = t0 & 63;
    const int wm = w >> 2, wn = w & 3;
    const int m0 = by * 256, n0 = bx * (64 * NF);
    const long zb = bz;

    const bf16* Ab = A  + zb * sA + (size_t)m0 * lda;
    const bf16* Bb = Bm + zb * sB + (size_t)n0 * ldb;

    const int sr16 = lane >> 2;
    const int sce  = ((((lane & 3) << 4) ^ (((lane >> 5) & 1) << 5))) >> 1;
    const int stg0 = w * 2, stg1 = w * 2 + 1;
    const bf16* pA0 = Ab + (size_t)(stg0 * 16 + sr16) * lda + sce;
    const bf16* pA1 = Ab + (size_t)(stg1 * 16 + sr16) * lda + sce;
    const bf16* pB0 = Bb + (size_t)((NF == 4 ? stg0 : w) * 16 + sr16) * ldb + sce;
    const bf16* pB1 = Bb + (size_t)(stg1 * 16 + sr16) * ldb + sce;

    const int lr = lane & 15, lkq = lane >> 4;
    const int phx = ((lane >> 3) & 1) << 5;
    const int frag_base = lr * 64 + lkq * 16;

    f32x4 acc[8][NF] = {};
    const int NT = Kdim >> 5;

    auto issueSlot = [&](int p) {
        char* lA = smem + (p & 3) * 16384;
        char* lB = smem + 65536 + (p & 3) * SB;
        const int kt = p << 5;
        gload16(pA0 + kt, lA + stg0 * 1024);
        gload16(pA1 + kt, lA + stg1 * 1024);
        if (NF == 4) {
            gload16(pB0 + kt, lB + stg0 * 1024);
            gload16(pB1 + kt, lB + stg1 * 1024);
        } else {
            gload16(pB0 + kt, lB + w * 1024);
        }
    };
    auto rdA = [&](const char* base, int sub) {
        return *(const bf16x8*)(base + (((sub << 10) + frag_base) ^ phx));
    };

    issueSlot(0); issueSlot(1); issueSlot(2);
    if (NF == 4) asm volatile("s_waitcnt vmcnt(4)" ::: "memory");
    else         asm volatile("s_waitcnt vmcnt(3)" ::: "memory");
    __builtin_amdgcn_s_barrier();
    MEMFENCE;

    bf16x8 alo[4], ahi[4], b0[NF], b1[NF];
    {
        const char* cA = smem;
        const char* cB = smem + 65536;
        #pragma unroll
        for (int mf = 0; mf < 4; ++mf) alo[mf] = rdA(cA, wm * 8 + mf);
        #pragma unroll
        for (int nf = 0; nf < NF; ++nf) b0[nf] = rdA(cB, wn * NF + nf);
    }

    auto stepBody = [&](int SL, int s, bf16x8 (&bA)[NF], bf16x8 (&bB)[NF]) {
        if (s + 3 < NT) issueSlot(s + 3);
        const char* cA = smem + SL * 16384;
        #pragma unroll
        for (int mf = 0; mf < 4; ++mf) ahi[mf] = rdA(cA, wm * 8 + 4 + mf);

        __builtin_amdgcn_s_setprio(1);
        #pragma unroll
        for (int mf = 0; mf < 4; ++mf)
            #pragma unroll
            for (int nf = 0; nf < NF; ++nf)
                acc[mf][nf] = __builtin_amdgcn_mfma_f32_16x16x32_bf16(alo[mf], bA[nf], acc[mf][nf], 0, 0, 0);
        __builtin_amdgcn_s_setprio(0);

        if (s + 1 < NT) {
            const int NS = (SL + 1) & 3;
            const char* nA = smem + NS * 16384;
            const char* nB = smem + 65536 + NS * SB;
            #pragma unroll
            for (int mf = 0; mf < 4; ++mf) alo[mf] = rdA(nA, wm * 8 + mf);
            #pragma unroll
            for (int nf = 0; nf < NF; ++nf) bB[nf] = rdA(nB, wn * NF + nf);
        }

        __builtin_amdgcn_s_setprio(1);
        #pragma unroll
        for (int mf = 0; mf < 4; ++mf)
            #pragma unroll
            for (int nf = 0; nf < NF; ++nf)
                acc[4 + mf][nf] = __builtin_amdgcn_mfma_f32_16x16x32_bf16(ahi[mf], bA[nf], acc[4 + mf][nf], 0, 0, 0);
        __builtin_amdgcn_s_setprio(0);

        MEMFENCE;
        if (s + 3 < NT) {
            if (NF == 4) asm volatile("s_waitcnt vmcnt(4)" ::: "memory");
            else         asm volatile("s_waitcnt vmcnt(3)" ::: "memory");
        } else {
            asm volatile("s_waitcnt vmcnt(0)" ::: "memory");
        }
        __builtin_amdgcn_s_barrier();
        MEMFENCE;
    };

    for (int s = 0; s < NT; s += 2) {
        stepBody(s & 3, s, b0, b1);
        stepBody((s + 1) & 3, s + 1, b1, b0);
    }

    const int rb  = m0 + wm * 128 + lkq * 4;
    const int cb0 = n0 + wn * (NF * 16) + lr;

    if (EPI == 0 || EPI == 4) {
        #pragma unroll
        for (int mf = 0; mf < 8; ++mf)
            #pragma unroll
            for (int nf = 0; nf < NF; ++nf) {
                const int c = cb0 + nf * 16;
                #pragma unroll
                for (int r = 0; r < 4; ++r) {
                    const int rw = rb + mf * 16 + r;
                    if (EPI == 0)
                        ((bf16*)Cp + zb * sC)[(size_t)rw * ldc + c] = (bf16)(alpha * acc[mf][nf][r]);
                    else
                        ((unsigned char*)Cp + zb * sC)[(size_t)rw * ldc + pcol(c)] = tofp8(alpha * acc[mf][nf][r]);
                }
            }
    } else {
        // EPI 3: U8 = fp8(16*U) store (k-permuted) + in-register rowdot partial (raw units).
        float* smemF = (float*)smem;
        #pragma unroll
        for (int mf = 0; mf < 8; ++mf) {
            #pragma unroll
            for (int r = 0; r < 4; ++r) {
                const int rw = rb + mf * 16 + r;
                float pd = 0.f;
                #pragma unroll
                for (int nf = 0; nf < NF; ++nf) {
                    const int c = cb0 + nf * 16;
                    const float v = acc[mf][nf][r];
                    const float u = v + aux1[c];
                    const float sg = 1.f / (1.f + __expf(-u));
                    const float dd = sg * (1.f + u * (1.f - sg));
                    const float uval = dd * aux2[c];
                    ((unsigned char*)Cp)[(size_t)rw * ldc + pcol(c)] = tofp8(uval * 16.f);
                    pd += uval * v;                      // U[r,c] * H[r,c] (raw)
                }
                #pragma unroll
                for (int o = 1; o < 16; o <<= 1) pd += __shfl_xor(pd, o, 64);
                if (lr == 0)
                    smemF[wn * 256 + wm * 128 + mf * 16 + lkq * 4 + r] = pd;
            }
        }
        __syncthreads();
        if (t0 < 256) {
            const float s4 = smemF[t0] + smemF[256 + t0] + smemF[512 + t0] + smemF[768 + t0];
            rds[(size_t)bx * 16384 + m0 + t0] = s4;   // slab per block-column bx
        }
    }
}

// ---------------- fp32 -> bf16 cast (DN) and/or transposed cast (TM) body ----------------
// TM: 0 = none, 1 = bf16 transpose, 2 = fp8 transpose with k-permuted rows (64-blocks)
// R12: fully-coalesced lane mapping — every global load/store instruction is contiguous.
template<bool DN, int TM>
__device__ __forceinline__ void transcast_body(
                 const float* __restrict__ in, bf16* __restrict__ outN,
                 void* __restrict__ outT, int R, int C, int bx, int by, int bz,
                 float (*ts)[65])
{
    const int t = threadIdx.x;
    const int c0 = bx * 64, r0 = by * 64;
    const size_t zoff = (size_t)bz * R * C;

    // loads: lane t reads rows (t>>4)+16i, cols (t&15)*4..+3  -> 1KB contiguous per instr
    const int col4 = (t & 15) * 4;
    const int rowb = t >> 4;
    float4 f[4];
    const float* src = in + zoff + (size_t)r0 * C + c0 + col4;
    #pragma unroll
    for (int i = 0; i < 4; ++i)
        f[i] = *(const float4*)(src + (size_t)(rowb + 16 * i) * C);

    if (DN) {
        bf16* dstN = outN + zoff + (size_t)r0 * C + c0 + col4;
        #pragma unroll
        for (int i = 0; i < 4; ++i) {
            bf16x4 h;
            h[0] = (bf16)f[i].x; h[1] = (bf16)f[i].y;
            h[2] = (bf16)f[i].z; h[3] = (bf16)f[i].w;
            *(bf16x4*)(dstN + (size_t)(rowb + 16 * i) * C) = h;   // 512B contiguous/instr
        }
    }
    if (TM) {
        #pragma unroll
        for (int i = 0; i < 4; ++i) {
            ts[rowb + 16*i][col4 + 0] = f[i].x;
            ts[rowb + 16*i][col4 + 1] = f[i].y;
            ts[rowb + 16*i][col4 + 2] = f[i].z;
            ts[rowb + 16*i][col4 + 3] = f[i].w;
        }
        __syncthreads();
        if (TM == 1) {
            // 8 lanes per column: each instr writes 32 cols x 128B-contiguous chunks
            #pragma unroll
            for (int h = 0; h < 2; ++h) {
                const int ct = (t >> 3) + h * 32;
                const int rr8 = (t & 7) * 8;
                bf16x8 o;
                #pragma unroll
                for (int i = 0; i < 8; ++i) o[i] = (bf16)ts[rr8 + i][ct];
                *(bf16x8*)((bf16*)outT + zoff + (size_t)(c0 + ct) * R + r0 + rr8) = o;
            }
        } else {
            // fp8 transpose, k-permuted: lane t covers 16B chunk lkq of column ct.
            // byte lkq*16 + k2*8 + b  <-  element row k2*32 + lkq*8 + b  (= consumer pcol)
            const int ct = t >> 2, lkq = t & 3;
            i32x4 o;
            #pragma unroll
            for (int k2 = 0; k2 < 2; ++k2)
                #pragma unroll
                for (int g = 0; g < 2; ++g) {
                    const int rbase = k2 * 32 + lkq * 8 + g * 4;
                    int v = __builtin_amdgcn_cvt_pk_fp8_f32(ts[rbase + 0][ct], ts[rbase + 1][ct], 0, false);
                    v = __builtin_amdgcn_cvt_pk_fp8_f32(ts[rbase + 2][ct], ts[rbase + 3][ct], v, true);
                    o[k2 * 2 + g] = v;
                }
            unsigned char* dst = (unsigned char*)outT + zoff + (size_t)(c0 + ct) * R + r0 + lkq * 16;
            *(i32x4*)dst = o;   // 64 cols x 64B fully covered in one instr
        }
    }
}

// one launch for all input casts: z 0-7 Q, 8-15 K (bf16 N + fp8 T), 16-23 V (bf16 N+T), 24 W1^T
__global__ __launch_bounds__(256)
void trans_all(const float* __restrict__ Q, const float* __restrict__ Km,
               const float* __restrict__ V, const float* __restrict__ W1,
               bf16* __restrict__ Qb, bf16* __restrict__ Kb, unsigned char* __restrict__ KbT8,
               bf16* __restrict__ Vb, bf16* __restrict__ VbT, bf16* __restrict__ W1T)
{
    __shared__ float ts[64][65];
    const int z = blockIdx.z;
    if (z < 8) {
        transcast_body<true, 0>(Q, Qb, nullptr, 2048, 1024, blockIdx.x, blockIdx.y, z, ts);
    } else if (z < 16) {
        transcast_body<true, 2>(Km, Kb, KbT8, 2048, 1024, blockIdx.x, blockIdx.y, z - 8, ts);
    } else if (z < 24) {
        transcast_body<true, 1>(V, Vb, VbT, 2048, 1024, blockIdx.x, blockIdx.y, z - 16, ts);
    } else {
        if (blockIdx.x < 8 && blockIdx.y < 16)
            transcast_body<false, 1>(W1, nullptr, W1T, 1024, 512, blockIdx.x, blockIdx.y, 0, ts);
    }
}

// ---------------- row softmax over 2048-wide rows ----------------
__global__ __launch_bounds__(256)
void softmax_k(const bf16* __restrict__ S, bf16* __restrict__ A)
{
    const size_t row = blockIdx.x;
    const int t = threadIdx.x;
    const int wid = t >> 6, lane = t & 63;
    __shared__ float r1[4], r2[4];

    bf16x8 v = *(const bf16x8*)(S + row * 2048 + t * 8);
    float f[8];
    float mx = -1e30f;
    #pragma unroll
    for (int i = 0; i < 8; ++i) { f[i] = (float)v[i]; mx = fmaxf(mx, f[i]); }
    #pragma unroll
    for (int o = 32; o; o >>= 1) mx = fmaxf(mx, __shfl_xor(mx, o, 64));
    if (!lane) r1[wid] = mx;
    __syncthreads();
    mx = fmaxf(fmaxf(r1[0], r1[1]), fmaxf(r1[2], r1[3]));

    float sum = 0.f;
    #pragma unroll
    for (int i = 0; i < 8; ++i) { f[i] = __expf(f[i] - mx); sum += f[i]; }
    #pragma unroll
    for (int o = 32; o; o >>= 1) sum += __shfl_xor(sum, o, 64);
    if (!lane) r2[wid] = sum;
    __syncthreads();
    sum = r2[0] + r2[1] + r2[2] + r2[3];

    const float inv = 1.f / sum;
    bf16x8 ov;
    #pragma unroll
    for (int i = 0; i < 8; ++i) ov[i] = (bf16)(f[i] * inv);
    *(bf16x8*)(A + row * 2048 + t * 8) = ov;
}

extern "C" void kernel_launch(void* const* d_in, const int* in_sizes, int n_in,
                              void* d_out, int out_size, void* d_ws, size_t ws_size,
                              hipStream_t stream)
{
    const float* Q  = (const float*)d_in[0];
    const float* Km = (const float*)d_in[1];
    const float* V  = (const float*)d_in[2];
    const float* W1 = (const float*)d_in[3];
    const float* b1 = (const float*)d_in[4];
    const float* W2 = (const float*)d_in[5];
    float* out = (float*)d_out;

    // ---- workspace layout (~236 MB, live-range packed; all launches sequential) ----
    char* ws = (char*)d_ws;
    bf16* Amat = (bf16*)(ws);                            // R1: softmax A (bf16, live to G6)
    bf16* AO   = (bf16*)(ws + 67108864);                 // R2: Kb, then attn_out bf16
    bf16* Kb   = AO;
    unsigned char* KbT8 = (unsigned char*)(ws + 100663296);  // R3: K^T fp8 k-permuted (16.8 MB)
    float* rdSlab = (float*)(ws + 117440512);            // R3 tail: rowdot slabs [4][16384] f32
    bf16* Vb   = (bf16*)(ws + 134217728);                // R4: V bf16 (dead after VW1)
    unsigned char* dS8 = (unsigned char*)(ws + 134217728);   // R4 reuse: dS fp8 k-perm (G6->G7)
    bf16* VbT  = (bf16*)(ws + 167772160);                // R5: V^T bf16 (dead after G3)
    unsigned char* U8 = (unsigned char*)(ws + 167772160);    // R5 reuse: U fp8 = 16*U k-perm
    bf16* Qb   = (bf16*)(ws + 201326592);                // R6: Q bf16 (dead after G1)
    unsigned char* VW18 = (unsigned char*)(ws + 201326592);  // R6 reuse: VW1 fp8 k-perm
    bf16* W1T  = (bf16*)(ws + 234881024);                // R7: W1^T bf16 (1 MB)
    bf16* S    = (bf16*)d_out;                           // S (dead after softmax)

    const long sQK = 2048L * 1024;
    const long sS  = 2048L * 2048;
    const long sVW = 2048L * 512;
    dim3 blk(256), blkG(512);

    // prep: all bf16/fp8 casts / transposes in one launch
    trans_all<<<dim3(16, 32, 25), blk, 0, stream>>>(Q, Km, V, W1, Qb, Kb, KbT8, Vb, VbT, W1T);

    // 1) S = scale * Qb @ Kb^T                               (bf16)
    gemm8p<0, 0><<<dim3(8, 8, 8), blkG, 0, stream>>>(
        Qb, Kb, S, 1024, 1024, 1024, 2048, sQK, sQK, sS, 0.03125f, nullptr, nullptr);

    // 1b) VW18 = fp8(V @ W1)  (writes Qb region — dead after GEMM 1)
    gemm_nc<4, 2><<<dim3(4, 8, 8), blkG, 0, stream>>>(
        Vb, W1T, VW18, 1024, 1024, 1024, 512, sQK, 0, sVW, 1.0f, nullptr, nullptr, nullptr);

    // 2) A = row-softmax(S)
    softmax_k<<<dim3(16384), blk, 0, stream>>>(S, Amat);

    // 3) attn_out = A @ V   (B = V^T; bf16)
    gemm8p<0, 0><<<dim3(4, 8, 8), blkG, 0, stream>>>(
        Amat, VbT, AO, 2048, 2048, 2048, 1024, sS, sQK, sQK, 1.0f, nullptr, nullptr);

    // 4) U8 = fp8(16 * silu'(AO@W1+b1)*w2); rowdot slabs fused (H eliminated)
    gemm_nc<3, 2><<<dim3(4, 64, 1), blkG, 0, stream>>>(
        AO, W1T, U8, 1024, 1024, 1024, 512, 0, 0, 0, 1.0f, b1, W2, rdSlab);

    // 6) dS8 = fp8(64 * A .* (U8@VW18^T / 16 - rowdot))   — fp8 GEMM, K=512
    gemm8p<1, 1><<<dim3(8, 8, 8), blkG, 0, stream>>>(
        U8, VW18, dS8, 512, 512, 512, 2048, 1048576, 1048576, 4194304, 0.0625f, rdSlab, Amat);

    // 7) out = V + attn_out - (eps*scale/64) * dS8 @ K     — fp8 GEMM, K=2048
    gemm8p<2, 1><<<dim3(4, 8, 8), blkG, 0, stream>>>(
        dS8, KbT8, out, 2048, 2048, 2048, 1024, 4194304, 2097152, 2097152,
        0.03f * 0.03125f / 64.f, V, AO);
}